// Round 2
// baseline (2092.614 us; speedup 1.0000x reference)
//
#include <hip/hip_runtime.h>
#include <hip/hip_bf16.h>
#include <cstdint>
#include <cstddef>

#define NPTS 2048
#define P 32
#define KNN_K 15
#define LRELU_NEG 0.2f
#define BN_EPS 1e-5f

__device__ __forceinline__ float lrelu(float x) { return x > 0.f ? x : LRELU_NEG * x; }

// ---------------- KNN: per-cloud pairwise -dist^2, top-15 (incl. self) ----------------
template<int C>
__global__ __launch_bounds__(64) void knn_kernel(const float* __restrict__ xin, int cloudStride,
                                                 unsigned char* __restrict__ idx)
{
    const int n = blockIdx.x, t = threadIdx.x;
    __shared__ float xs[C][P];
    __shared__ float xx[P];
    __shared__ float pd[P][P + 1];
    const float* xp = xin + (size_t)n * cloudStride;
    for (int i = t; i < C * P; i += 64) xs[i / P][i % P] = xp[i];
    __syncthreads();
    if (t < P) { float s = 0.f; for (int c = 0; c < C; ++c) { float v = xs[c][t]; s = fmaf(v, v, s); } xx[t] = s; }
    __syncthreads();
    for (int i = t; i < P * P; i += 64) {
        int p = i >> 5, q = i & 31;
        float d = 0.f;
        for (int c = 0; c < C; ++c) d = fmaf(xs[c][p], xs[c][q], d);
        pd[p][q] = 2.f * d - xx[p] - xx[q];   // diag exactly 0
    }
    __syncthreads();
    if (t < P) {
        for (int j = 0; j < KNN_K; ++j) {
            float best = -INFINITY; int bq = 0;
            for (int q = 0; q < P; ++q) { float v = pd[t][q]; if (v > best) { best = v; bq = q; } }
            idx[(size_t)n * (P * KNN_K) + t * KNN_K + j] = (unsigned char)bq;
            pd[t][bq] = -INFINITY;
        }
    }
}

// ---------------- Wcat^T: wt[c][o2]; o2<O -> W[o2][c] (h); o2>=O -> W[o][C+c]-W[o][c] (g) ----------------
__global__ __launch_bounds__(256) void build_wcat_kernel(const float* __restrict__ W, float* __restrict__ wt,
                                                         int C, int O)
{
    int i = blockIdx.x * 256 + threadIdx.x;
    int tot = C * 2 * O;
    if (i >= tot) return;
    int c = i / (2 * O), o2 = i % (2 * O);
    float v;
    if (o2 < O) v = W[(size_t)o2 * 2 * C + c];
    else { int o = o2 - O; v = W[(size_t)o * 2 * C + C + c] - W[(size_t)o * 2 * C + c]; }
    wt[i] = v;
}

__global__ __launch_bounds__(256) void transpose_w_kernel(const float* __restrict__ W, float* __restrict__ wt,
                                                          int O, int C)   // W[O][C] -> wt[C][O]
{
    int i = blockIdx.x * 256 + threadIdx.x;
    if (i < O * C) { int c = i / O, o = i % O; wt[i] = W[(size_t)o * C + c]; }
}

// ---------------- edge conv: per-cloud g/h GEMM in LDS; OUT=false: BN stats; OUT=true: output ----------------
template<int C, int O, bool OUT>
__global__ __launch_bounds__(256) void edge_pass_kernel(
    const float* __restrict__ xin, int cloudStride,
    const float* __restrict__ wt,                  // [C][2O]
    const unsigned char* __restrict__ idx,         // [N][P][K]
    const float* __restrict__ st,                  // OUT: st[o]=scale, st[1024+o]=shift
    float* __restrict__ xcout,                     // OUT: xc + chBase*P
    float* __restrict__ partS, float* __restrict__ partQ) // stats: [o][2048]
{
    constexpr int O2 = 2 * O;
    constexpr int TPC = (O2 >= 256) ? 1 : (256 / O2);   // thread-groups per column set
    constexpr int CPT = (O2 > 256) ? (O2 / 256) : 1;    // columns per thread
    constexpr int PP = P / TPC;
    const int n = blockIdx.x, t = threadIdx.x;

    __shared__ float xs[C][P];
    __shared__ float gh[P * O2];                   // gemm result; OUT pass reuses as [O][P+1] staging
    __shared__ unsigned char idl[P * KNN_K];
    __shared__ float red[2][256];

    const float* xp = xin + (size_t)n * cloudStride;
    for (int i = t; i < C * P; i += 256) xs[i / P][i % P] = xp[i];
    for (int i = t; i < P * KNN_K; i += 256) idl[i] = idx[(size_t)n * (P * KNN_K) + i];
    __syncthreads();

    // GEMM: gh[p][o2] = sum_c xs[c][p] * wt[c][o2]
    {
        const int col = (O2 >= 256) ? t : (t % O2);
        const int pg  = (O2 >= 256) ? 0 : (t / O2);
        const int p0 = pg * PP;
        float acc[CPT][PP];
        #pragma unroll
        for (int j = 0; j < CPT; ++j)
            #pragma unroll
            for (int p = 0; p < PP; ++p) acc[j][p] = 0.f;
        for (int c = 0; c < C; ++c) {
            float w[CPT];
            #pragma unroll
            for (int j = 0; j < CPT; ++j) w[j] = wt[(size_t)c * O2 + col + j * 256];
            #pragma unroll
            for (int p = 0; p < PP; ++p) {
                float xv = xs[c][p0 + p];
                #pragma unroll
                for (int j = 0; j < CPT; ++j) acc[j][p] = fmaf(w[j], xv, acc[j][p]);
            }
        }
        #pragma unroll
        for (int j = 0; j < CPT; ++j)
            #pragma unroll
            for (int p = 0; p < PP; ++p) gh[(p0 + p) * O2 + col + j * 256] = acc[j][p];
    }
    __syncthreads();

    // combine: y[p][k][o] = gh[idx[p][k]][o] + gh[p][O+o]
    constexpr int TPO = 256 / O;
    constexpr int PPo = P / ((TPO > 0) ? TPO : 1);
    const int o = t % O;
    const int p0c = (t / O) * PPo;

    if constexpr (!OUT) {
        float ssum = 0.f, ssq = 0.f;
        #pragma unroll
        for (int p = 0; p < PPo; ++p) {
            const int pp = p0c + p;
            const float g = gh[pp * O2 + O + o];
            #pragma unroll
            for (int k = 0; k < KNN_K; ++k) {
                const int q = idl[pp * KNN_K + k];
                float yv = gh[q * O2 + o] + g;
                ssum += yv; ssq += yv * yv;
            }
        }
        red[0][t] = ssum; red[1][t] = ssq;
        __syncthreads();
        if (t < O) {
            float S = 0.f, Q = 0.f;
            #pragma unroll
            for (int j = 0; j < TPO; ++j) { S += red[0][t + j * O]; Q += red[1][t + j * O]; }
            partS[(size_t)t * 2048 + n] = S;
            partQ[(size_t)t * 2048 + n] = Q;
        }
    } else {
        const float s = st[o], sh = st[1024 + o];
        float rbuf[PPo];
        #pragma unroll
        for (int p = 0; p < PPo; ++p) {
            const int pp = p0c + p;
            const float g = gh[pp * O2 + O + o];
            float mx = -INFINITY, mn = INFINITY;
            #pragma unroll
            for (int k = 0; k < KNN_K; ++k) {
                const int q = idl[pp * KNN_K + k];
                float yv = gh[q * O2 + o] + g;
                mx = fmaxf(mx, yv); mn = fminf(mn, yv);
            }
            rbuf[p] = lrelu(fmaf(s, (s >= 0.f ? mx : mn), sh));  // lrelu/affine monotone in y
        }
        __syncthreads();   // all gh reads done
        #pragma unroll
        for (int p = 0; p < PPo; ++p) gh[o * (P + 1) + p0c + p] = rbuf[p];
        __syncthreads();
        for (int i = t; i < O * P; i += 256)
            xcout[(size_t)n * (512 * P) + i] = gh[(i / P) * (P + 1) + (i % P)];
    }
}

// ---------------- reduce partials -> scale/shift per channel ----------------
__global__ __launch_bounds__(256) void reduce_stats_kernel(const float* __restrict__ partS,
                                                           const float* __restrict__ partQ,
                                                           const float* __restrict__ gamma,
                                                           const float* __restrict__ beta,
                                                           float* __restrict__ st, int nparts, float inv_count)
{
    const int o = blockIdx.x, t = threadIdx.x;
    __shared__ float rs[256], rq[256];
    float S = 0.f, Q = 0.f;
    for (int i = t; i < nparts; i += 256) { S += partS[(size_t)o * 2048 + i]; Q += partQ[(size_t)o * 2048 + i]; }
    rs[t] = S; rq[t] = Q; __syncthreads();
    for (int w = 128; w > 0; w >>= 1) { if (t < w) { rs[t] += rs[t + w]; rq[t] += rq[t + w]; } __syncthreads(); }
    if (t == 0) {
        float m = rs[0] * inv_count;
        float v = fmaxf(rq[0] * inv_count - m * m, 0.f);
        float s = gamma[o] * rsqrtf(v + BN_EPS);
        st[o] = s;
        st[1024 + o] = fmaf(-m, s, beta[o]);
    }
}

// ---------------- stage 5: y5[n][p][o] = sum_c xc[n][c][p] W5t[c][o]; y5 (bf16) written IN PLACE over xc[n] ----------------
__global__ __launch_bounds__(256) void conv5_kernel(const float* xc, const float* __restrict__ w5t,
                                                    __hip_bfloat16* y5,
                                                    float* __restrict__ partS, float* __restrict__ partQ)
{
    const int n = blockIdx.x, t = threadIdx.x;
    __shared__ float xs[512][P];
    const float* xp = xc + (size_t)n * (512 * P);
    for (int i = t; i < 512 * P; i += 256) xs[i / P][i % P] = xp[i];
    __syncthreads();     // all reads of xc[n] complete before any y5[n] write below
    float acc[4][P];
    #pragma unroll
    for (int j = 0; j < 4; ++j)
        #pragma unroll
        for (int p = 0; p < P; ++p) acc[j][p] = 0.f;
    for (int c = 0; c < 512; ++c) {
        float w[4];
        #pragma unroll
        for (int j = 0; j < 4; ++j) w[j] = w5t[(size_t)c * 1024 + t + j * 256];
        #pragma unroll
        for (int p = 0; p < P; ++p) {
            float xv = xs[c][p];
            #pragma unroll
            for (int j = 0; j < 4; ++j) acc[j][p] = fmaf(w[j], xv, acc[j][p]);
        }
    }
    #pragma unroll
    for (int j = 0; j < 4; ++j) {
        int o = t + j * 256;
        float S = 0.f, Q = 0.f;
        #pragma unroll
        for (int p = 0; p < P; ++p) {
            float v = acc[j][p]; S += v; Q += v * v;
            y5[((size_t)n * P + p) * 1024 + o] = __float2bfloat16(v);
        }
        partS[(size_t)o * 2048 + n] = S;
        partQ[(size_t)o * 2048 + n] = Q;
    }
}

// ---------------- pool: h[n][o] = max_p lrelu(bn(y5)), h[n][1024+o] = mean_p ----------------
__global__ __launch_bounds__(256) void pool5_kernel(const __hip_bfloat16* y5,
                                                    const float* __restrict__ st, float* __restrict__ h)
{
    const int n = blockIdx.x, t = threadIdx.x;
    __shared__ alignas(16) __hip_bfloat16 ls[P][1024];
    const uint4* yp = (const uint4*)(y5 + (size_t)n * (P * 1024));
    uint4* lv = (uint4*)&ls[0][0];
    for (int i = t; i < (P * 1024 * 2) / 16; i += 256) lv[i] = yp[i];
    __syncthreads();
    #pragma unroll
    for (int j = 0; j < 4; ++j) {
        int o = t + j * 256;
        float s = st[o], tt = st[1024 + o];
        float mx = -INFINITY, sm = 0.f;
        #pragma unroll
        for (int p = 0; p < P; ++p) {
            float v = __bfloat162float(ls[p][o]);
            float r = lrelu(fmaf(s, v, tt));
            mx = fmaxf(mx, r); sm += r;
        }
        h[(size_t)n * 2048 + o] = mx;
        h[(size_t)n * 2048 + 1024 + o] = sm * (1.f / 32.f);
    }
}

// ---------------- generic f32 GEMM: C[m][o] = sum_k A[m][k]*B[o][k] (+bias) ----------------
__global__ __launch_bounds__(256) void gemm_nt(const float* __restrict__ A, const float* __restrict__ B,
                                               const float* __restrict__ bias, float* __restrict__ Cc,
                                               int M, int Nn, int Kk)
{
    __shared__ float As[16][64];
    __shared__ float Bs[16][64];
    const int t = threadIdx.x;
    const int m0 = blockIdx.y * 64;
    const int o0 = blockIdx.x * 64;
    const int lm = t % 64;
    const int lk4 = (t / 64) * 4;
    const int tx = t % 16, ty = t / 16;
    float acc[4][4] = {};
    for (int k0 = 0; k0 < Kk; k0 += 16) {
        float4 av4 = *(const float4*)(A + (size_t)(m0 + lm) * Kk + k0 + lk4);
        float4 bv4 = make_float4(0.f, 0.f, 0.f, 0.f);
        if (o0 + lm < Nn) bv4 = *(const float4*)(B + (size_t)(o0 + lm) * Kk + k0 + lk4);
        __syncthreads();
        As[lk4 + 0][lm] = av4.x; As[lk4 + 1][lm] = av4.y; As[lk4 + 2][lm] = av4.z; As[lk4 + 3][lm] = av4.w;
        Bs[lk4 + 0][lm] = bv4.x; Bs[lk4 + 1][lm] = bv4.y; Bs[lk4 + 2][lm] = bv4.z; Bs[lk4 + 3][lm] = bv4.w;
        __syncthreads();
        #pragma unroll
        for (int kk = 0; kk < 16; ++kk) {
            float a[4], b[4];
            *(float4*)a = *(const float4*)&As[kk][ty * 4];
            *(float4*)b = *(const float4*)&Bs[kk][tx * 4];
            #pragma unroll
            for (int i = 0; i < 4; ++i)
                #pragma unroll
                for (int j = 0; j < 4; ++j) acc[i][j] = fmaf(a[i], b[j], acc[i][j]);
        }
    }
    #pragma unroll
    for (int i = 0; i < 4; ++i) {
        int m = m0 + ty * 4 + i;
        #pragma unroll
        for (int j = 0; j < 4; ++j) {
            int o = o0 + tx * 4 + j;
            if (o < Nn) Cc[(size_t)m * Nn + o] = acc[i][j] + (bias ? bias[o] : 0.f);
        }
    }
    (void)M;
}

// ---------------- per-column stats over rows (FC batchnorm, axis 0) ----------------
template<int NCPT>
__global__ __launch_bounds__(256) void colstats_kernel(const float* __restrict__ A, int NC,
                                                       float* __restrict__ partS, float* __restrict__ partQ)
{
    const int b = blockIdx.x, t = threadIdx.x;
    float S[NCPT], Q[NCPT];
    #pragma unroll
    for (int j = 0; j < NCPT; ++j) { S[j] = 0.f; Q[j] = 0.f; }
    for (int r = 0; r < 32; ++r) {
        const float* row = A + (size_t)(b * 32 + r) * NC;
        #pragma unroll
        for (int j = 0; j < NCPT; ++j) { float v = row[t + j * 256]; S[j] += v; Q[j] += v * v; }
    }
    #pragma unroll
    for (int j = 0; j < NCPT; ++j) {
        int o = t + j * 256;
        partS[(size_t)o * 2048 + b] = S[j];
        partQ[(size_t)o * 2048 + b] = Q[j];
    }
}

__global__ __launch_bounds__(256) void bnact_kernel(const float* __restrict__ in, const float* __restrict__ st,
                                                    float* __restrict__ out, int NC, int total)
{
    int i = blockIdx.x * 256 + threadIdx.x;
    if (i < total) {
        int o = i % NC;
        out[i] = lrelu(fmaf(st[o], in[i], st[1024 + o]));
    }
}

__global__ __launch_bounds__(256) void logsoftmax_kernel(float* __restrict__ out)
{
    const int n = blockIdx.x, t = threadIdx.x;
    float* row = out + (size_t)n * 800;
    __shared__ float red[256];
    float v[4];
    float mx = -INFINITY;
    #pragma unroll
    for (int j = 0; j < 4; ++j) {
        int i = t + j * 256;
        v[j] = (i < 800) ? row[i] : -INFINITY;
        mx = fmaxf(mx, v[j]);
    }
    red[t] = mx; __syncthreads();
    for (int w = 128; w > 0; w >>= 1) { if (t < w) red[t] = fmaxf(red[t], red[t + w]); __syncthreads(); }
    const float m = red[0]; __syncthreads();
    float s = 0.f;
    #pragma unroll
    for (int j = 0; j < 4; ++j) { int i = t + j * 256; if (i < 800) s += expf(v[j] - m); }
    red[t] = s; __syncthreads();
    for (int w = 128; w > 0; w >>= 1) { if (t < w) red[t] += red[t + w]; __syncthreads(); }
    const float lg = m + logf(red[0]);
    #pragma unroll
    for (int j = 0; j < 4; ++j) { int i = t + j * 256; if (i < 800) row[i] = v[j] - lg; }
}

extern "C" void kernel_launch(void* const* d_in, const int* in_sizes, int n_in,
                              void* d_out, int out_size, void* d_ws, size_t ws_size,
                              hipStream_t stream)
{
    (void)in_sizes; (void)n_in; (void)out_size; (void)ws_size;
    const float* x   = (const float*)d_in[0];
    const float* W1  = (const float*)d_in[2];
    const float* g1  = (const float*)d_in[3];
    const float* b1  = (const float*)d_in[4];
    const float* W2  = (const float*)d_in[5];
    const float* g2  = (const float*)d_in[6];
    const float* b2  = (const float*)d_in[7];
    const float* W3  = (const float*)d_in[8];
    const float* g3  = (const float*)d_in[9];
    const float* b3  = (const float*)d_in[10];
    const float* W4  = (const float*)d_in[11];
    const float* g4  = (const float*)d_in[12];
    const float* b4  = (const float*)d_in[13];
    const float* W5  = (const float*)d_in[14];
    const float* g5  = (const float*)d_in[15];
    const float* b5  = (const float*)d_in[16];
    const float* Wl1 = (const float*)d_in[17];
    const float* g6  = (const float*)d_in[18];
    const float* b6  = (const float*)d_in[19];
    const float* Wl2 = (const float*)d_in[20];
    const float* bl2 = (const float*)d_in[21];
    const float* g7  = (const float*)d_in[22];
    const float* b7  = (const float*)d_in[23];
    const float* Wl3 = (const float*)d_in[24];
    const float* bl3 = (const float*)d_in[25];

    char* ws = (char*)d_ws;
    size_t off = 0;
    auto alloc = [&](size_t bytes) -> void* {
        void* p = ws + off; off += (bytes + 255) & ~(size_t)255; return p;
    };
    // total ~167 MB
    float*         xc    = (float*)alloc((size_t)NPTS * 512 * P * 4);      // 134.2 MB (y5 bf16 aliases in place)
    unsigned char* idx   = (unsigned char*)alloc((size_t)NPTS * P * KNN_K); // 0.98 MB
    float*         partS = (float*)alloc((size_t)1024 * 2048 * 4);          // 8.4 MB
    float*         partQ = (float*)alloc((size_t)1024 * 2048 * 4);          // 8.4 MB
    float*         st    = (float*)alloc(2048 * 4);
    float*         wt    = (float*)alloc((size_t)512 * 1024 * 4);           // 2.1 MB
    float*         h     = (float*)alloc((size_t)2048 * 2048 * 4);          // 16.8 MB
    float*         h1p   = (float*)alloc((size_t)2048 * 512 * 4);           // 4.2 MB
    __hip_bfloat16* y5 = (__hip_bfloat16*)xc;      // in-place: conv5 block n reads xc[n] to LDS, writes y5[n] over it
    float* h1  = h;                 // h dead after FC1 gemm
    float* h2p = h + 1048576;
    float* h2  = h + 1572864;

    const float inv_edge = 1.f / (float)(NPTS * P * KNN_K);

    // ---- edge block 1: x(C=3) -> O=64 (xc ch 0..63) ----
    knn_kernel<3><<<NPTS, 64, 0, stream>>>(x, 3 * P, idx);
    build_wcat_kernel<<<(3 * 128 + 255) / 256, 256, 0, stream>>>(W1, wt, 3, 64);
    edge_pass_kernel<3, 64, false><<<NPTS, 256, 0, stream>>>(x, 3 * P, wt, idx, nullptr, nullptr, partS, partQ);
    reduce_stats_kernel<<<64, 256, 0, stream>>>(partS, partQ, g1, b1, st, 2048, inv_edge);
    edge_pass_kernel<3, 64, true><<<NPTS, 256, 0, stream>>>(x, 3 * P, wt, idx, st, xc + 0 * P, nullptr, nullptr);

    // ---- edge block 2: xc ch 0..63 -> O=64 (ch 64..127) ----
    knn_kernel<64><<<NPTS, 64, 0, stream>>>(xc, 512 * P, idx);
    build_wcat_kernel<<<(64 * 128 + 255) / 256, 256, 0, stream>>>(W2, wt, 64, 64);
    edge_pass_kernel<64, 64, false><<<NPTS, 256, 0, stream>>>(xc, 512 * P, wt, idx, nullptr, nullptr, partS, partQ);
    reduce_stats_kernel<<<64, 256, 0, stream>>>(partS, partQ, g2, b2, st, 2048, inv_edge);
    edge_pass_kernel<64, 64, true><<<NPTS, 256, 0, stream>>>(xc, 512 * P, wt, idx, st, xc + 64 * P, nullptr, nullptr);

    // ---- edge block 3: xc ch 64..127 -> O=128 (ch 128..255) ----
    knn_kernel<64><<<NPTS, 64, 0, stream>>>(xc + 64 * P, 512 * P, idx);
    build_wcat_kernel<<<(64 * 256 + 255) / 256, 256, 0, stream>>>(W3, wt, 64, 128);
    edge_pass_kernel<64, 128, false><<<NPTS, 256, 0, stream>>>(xc + 64 * P, 512 * P, wt, idx, nullptr, nullptr, partS, partQ);
    reduce_stats_kernel<<<128, 256, 0, stream>>>(partS, partQ, g3, b3, st, 2048, inv_edge);
    edge_pass_kernel<64, 128, true><<<NPTS, 256, 0, stream>>>(xc + 64 * P, 512 * P, wt, idx, st, xc + 128 * P, nullptr, nullptr);

    // ---- edge block 4: xc ch 128..255 -> O=256 (ch 256..511) ----
    knn_kernel<128><<<NPTS, 64, 0, stream>>>(xc + 128 * P, 512 * P, idx);
    build_wcat_kernel<<<(128 * 512 + 255) / 256, 256, 0, stream>>>(W4, wt, 128, 256);
    edge_pass_kernel<128, 256, false><<<NPTS, 256, 0, stream>>>(xc + 128 * P, 512 * P, wt, idx, nullptr, nullptr, partS, partQ);
    reduce_stats_kernel<<<256, 256, 0, stream>>>(partS, partQ, g4, b4, st, 2048, inv_edge);
    edge_pass_kernel<128, 256, true><<<NPTS, 256, 0, stream>>>(xc + 128 * P, 512 * P, wt, idx, st, xc + 256 * P, nullptr, nullptr);

    // ---- stage 5: 512 -> 1024, BN over (n,p), lrelu, max+mean pool over p ----
    transpose_w_kernel<<<(512 * 1024 + 255) / 256, 256, 0, stream>>>(W5, wt, 1024, 512);
    conv5_kernel<<<NPTS, 256, 0, stream>>>(xc, wt, y5, partS, partQ);
    reduce_stats_kernel<<<1024, 256, 0, stream>>>(partS, partQ, g5, b5, st, 2048, 1.f / 65536.f);
    pool5_kernel<<<NPTS, 256, 0, stream>>>(y5, st, h);

    // ---- FC head ----
    gemm_nt<<<dim3(512 / 64, 2048 / 64), 256, 0, stream>>>(h, Wl1, nullptr, h1p, 2048, 512, 2048);
    colstats_kernel<2><<<64, 256, 0, stream>>>(h1p, 512, partS, partQ);
    reduce_stats_kernel<<<512, 256, 0, stream>>>(partS, partQ, g6, b6, st, 64, 1.f / 2048.f);
    bnact_kernel<<<(2048 * 512 + 255) / 256, 256, 0, stream>>>(h1p, st, h1, 512, 2048 * 512);

    gemm_nt<<<dim3(256 / 64, 2048 / 64), 256, 0, stream>>>(h1, Wl2, bl2, h2p, 2048, 256, 512);
    colstats_kernel<1><<<64, 256, 0, stream>>>(h2p, 256, partS, partQ);
    reduce_stats_kernel<<<256, 256, 0, stream>>>(partS, partQ, g7, b7, st, 64, 1.f / 2048.f);
    bnact_kernel<<<(2048 * 256 + 255) / 256, 256, 0, stream>>>(h2p, st, h2, 256, 2048 * 256);

    gemm_nt<<<dim3((800 + 63) / 64, 2048 / 64), 256, 0, stream>>>(h2, Wl3, bl3, (float*)d_out, 2048, 800, 256);
    logsoftmax_kernel<<<NPTS, 256, 0, stream>>>((float*)d_out);
}

// Round 4
// 1674.426 us; speedup vs baseline: 1.2498x; 1.2498x over previous
//
#include <hip/hip_runtime.h>
#include <hip/hip_bf16.h>
#include <cstdint>
#include <cstddef>

#define NPTS 2048
#define P 32
#define KNN_K 15
#define LRELU_NEG 0.2f
#define BN_EPS 1e-5f

__device__ __forceinline__ float lrelu(float x) { return x > 0.f ? x : LRELU_NEG * x; }

__device__ __forceinline__ unsigned short f2bf(float x) {      // RNE f32 -> bf16 bits
    union { float f; unsigned u; } uu; uu.f = x;
    unsigned r = uu.u + 0x7fffu + ((uu.u >> 16) & 1u);
    return (unsigned short)(r >> 16);
}
__device__ __forceinline__ float bf2f(unsigned short b) {
    union { unsigned u; float f; } uu; uu.u = ((unsigned)b) << 16;
    return uu.f;
}

typedef short bf16x8 __attribute__((ext_vector_type(8)));
typedef float f32x4  __attribute__((ext_vector_type(4)));

// ---------------- KNN: per-cloud pairwise -dist^2, top-15 (incl. self) ----------------
template<int C>
__global__ __launch_bounds__(64) void knn_kernel(const float* __restrict__ xin, int cloudStride,
                                                 unsigned char* __restrict__ idx)
{
    const int n = blockIdx.x, t = threadIdx.x;
    __shared__ float xs[C][P];
    __shared__ float xx[P];
    __shared__ float pd[P][P + 1];
    const float* xp = xin + (size_t)n * cloudStride;
    for (int i = t; i < C * P; i += 64) xs[i / P][i % P] = xp[i];
    __syncthreads();
    if (t < P) { float s = 0.f; for (int c = 0; c < C; ++c) { float v = xs[c][t]; s = fmaf(v, v, s); } xx[t] = s; }
    __syncthreads();
    for (int i = t; i < P * P; i += 64) {
        int p = i >> 5, q = i & 31;
        float d = 0.f;
        for (int c = 0; c < C; ++c) d = fmaf(xs[c][p], xs[c][q], d);
        pd[p][q] = 2.f * d - xx[p] - xx[q];   // diag exactly 0
    }
    __syncthreads();
    if (t < P) {
        for (int j = 0; j < KNN_K; ++j) {
            float best = -INFINITY; int bq = 0;
            for (int q = 0; q < P; ++q) { float v = pd[t][q]; if (v > best) { best = v; bq = q; } }
            idx[(size_t)n * (P * KNN_K) + t * KNN_K + j] = (unsigned char)bq;
            pd[t][bq] = -INFINITY;
        }
    }
}

// ---------------- Wcat^T: wt[c][o2]; o2<O -> W[o2][c] (h); o2>=O -> W[o][C+c]-W[o][c] (g) ----------------
__global__ __launch_bounds__(256) void build_wcat_kernel(const float* __restrict__ W, float* __restrict__ wt,
                                                         int C, int O)
{
    int i = blockIdx.x * 256 + threadIdx.x;
    int tot = C * 2 * O;
    if (i >= tot) return;
    int c = i / (2 * O), o2 = i % (2 * O);
    float v;
    if (o2 < O) v = W[(size_t)o2 * 2 * C + c];
    else { int o = o2 - O; v = W[(size_t)o * 2 * C + C + c] - W[(size_t)o * 2 * C + c]; }
    wt[i] = v;
}

// ---------------- edge conv: per-cloud g/h GEMM in LDS; OUT=false: BN stats; OUT=true: output ----------------
template<int C, int O, bool OUT>
__global__ __launch_bounds__(256) void edge_pass_kernel(
    const float* __restrict__ xin, int cloudStride,
    const float* __restrict__ wt,                  // [C][2O]
    const unsigned char* __restrict__ idx,         // [N][P][K]
    const float* __restrict__ st,                  // OUT: st[o]=scale, st[1024+o]=shift
    float* __restrict__ xcout,                     // OUT: xc + chBase*P
    float* __restrict__ partS, float* __restrict__ partQ) // stats: [o][2048]
{
    constexpr int O2 = 2 * O;
    constexpr int TPC = (O2 >= 256) ? 1 : (256 / O2);
    constexpr int CPT = (O2 > 256) ? (O2 / 256) : 1;
    constexpr int PP = P / TPC;
    const int n = blockIdx.x, t = threadIdx.x;

    __shared__ float xs[C][P];
    __shared__ float gh[P * O2];
    __shared__ unsigned char idl[P * KNN_K];
    __shared__ float red[2][256];

    const float* xp = xin + (size_t)n * cloudStride;
    for (int i = t; i < C * P; i += 256) xs[i / P][i % P] = xp[i];
    for (int i = t; i < P * KNN_K; i += 256) idl[i] = idx[(size_t)n * (P * KNN_K) + i];
    __syncthreads();

    // GEMM: gh[p][o2] = sum_c xs[c][p] * wt[c][o2]
    {
        const int col = (O2 >= 256) ? t : (t % O2);
        const int pg  = (O2 >= 256) ? 0 : (t / O2);
        const int p0 = pg * PP;
        float acc[CPT][PP];
        #pragma unroll
        for (int j = 0; j < CPT; ++j)
            #pragma unroll
            for (int p = 0; p < PP; ++p) acc[j][p] = 0.f;
        for (int c = 0; c < C; ++c) {
            float w[CPT];
            #pragma unroll
            for (int j = 0; j < CPT; ++j) w[j] = wt[(size_t)c * O2 + col + j * 256];
            #pragma unroll
            for (int p = 0; p < PP; ++p) {
                float xv = xs[c][p0 + p];
                #pragma unroll
                for (int j = 0; j < CPT; ++j) acc[j][p] = fmaf(w[j], xv, acc[j][p]);
            }
        }
        #pragma unroll
        for (int j = 0; j < CPT; ++j)
            #pragma unroll
            for (int p = 0; p < PP; ++p) gh[(p0 + p) * O2 + col + j * 256] = acc[j][p];
    }
    __syncthreads();

    constexpr int TPO = 256 / O;
    constexpr int PPo = P / ((TPO > 0) ? TPO : 1);
    const int o = t % O;
    const int p0c = (t / O) * PPo;

    if constexpr (!OUT) {
        float ssum = 0.f, ssq = 0.f;
        #pragma unroll
        for (int p = 0; p < PPo; ++p) {
            const int pp = p0c + p;
            const float g = gh[pp * O2 + O + o];
            #pragma unroll
            for (int k = 0; k < KNN_K; ++k) {
                const int q = idl[pp * KNN_K + k];
                float yv = gh[q * O2 + o] + g;
                ssum += yv; ssq += yv * yv;
            }
        }
        red[0][t] = ssum; red[1][t] = ssq;
        __syncthreads();
        if (t < O) {
            float S = 0.f, Q = 0.f;
            #pragma unroll
            for (int j = 0; j < TPO; ++j) { S += red[0][t + j * O]; Q += red[1][t + j * O]; }
            partS[(size_t)t * 2048 + n] = S;
            partQ[(size_t)t * 2048 + n] = Q;
        }
    } else {
        const float s = st[o], sh = st[1024 + o];
        float rbuf[PPo];
        #pragma unroll
        for (int p = 0; p < PPo; ++p) {
            const int pp = p0c + p;
            const float g = gh[pp * O2 + O + o];
            float mx = -INFINITY, mn = INFINITY;
            #pragma unroll
            for (int k = 0; k < KNN_K; ++k) {
                const int q = idl[pp * KNN_K + k];
                float yv = gh[q * O2 + o] + g;
                mx = fmaxf(mx, yv); mn = fminf(mn, yv);
            }
            rbuf[p] = lrelu(fmaf(s, (s >= 0.f ? mx : mn), sh));  // lrelu/affine monotone in y
        }
        __syncthreads();
        #pragma unroll
        for (int p = 0; p < PPo; ++p) gh[o * (P + 1) + p0c + p] = rbuf[p];
        __syncthreads();
        for (int i = t; i < O * P; i += 256)
            xcout[(size_t)n * (512 * P) + i] = gh[(i / P) * (P + 1) + (i % P)];
    }
}

// ---------------- reduce partials -> scale/shift per channel ----------------
__global__ __launch_bounds__(256) void reduce_stats_kernel(const float* __restrict__ partS,
                                                           const float* __restrict__ partQ,
                                                           const float* __restrict__ gamma,
                                                           const float* __restrict__ beta,
                                                           float* __restrict__ st, int nparts, float inv_count)
{
    const int o = blockIdx.x, t = threadIdx.x;
    __shared__ float rs[256], rq[256];
    float S = 0.f, Q = 0.f;
    for (int i = t; i < nparts; i += 256) { S += partS[(size_t)o * 2048 + i]; Q += partQ[(size_t)o * 2048 + i]; }
    rs[t] = S; rq[t] = Q; __syncthreads();
    for (int w = 128; w > 0; w >>= 1) { if (t < w) { rs[t] += rs[t + w]; rq[t] += rq[t + w]; } __syncthreads(); }
    if (t == 0) {
        float m = rs[0] * inv_count;
        float v = fmaxf(rq[0] * inv_count - m * m, 0.f);
        float s = gamma[o] * rsqrtf(v + BN_EPS);
        st[o] = s;
        st[1024 + o] = fmaf(-m, s, beta[o]);
    }
}

// ---------------- pack W5 into MFMA fragment order, bf16 hi/lo ----------------
// layout: wp[((kb*64 + nt)*2 + term)*512 + lane*8 + j]; c = kb*32+(lane>>4)*8+j; o = nt*16+(lane&15)
// total elements: kb(16)*nt(64)*lane(64)*j(8) = 2^19
__global__ __launch_bounds__(256) void pack_w5_kernel(const float* __restrict__ W5, unsigned short* __restrict__ wp)
{
    int i = blockIdx.x * 256 + threadIdx.x;
    if (i >= (1 << 19)) return;
    int j = i & 7, lane = (i >> 3) & 63, nt = (i >> 9) & 63, kb = i >> 15;   // kb 0..15
    int c = kb * 32 + (lane >> 4) * 8 + j;
    int o = nt * 16 + (lane & 15);
    float f = W5[(size_t)o * 512 + c];
    unsigned short hi = f2bf(f);
    unsigned short lo = f2bf(f - bf2f(hi));
    size_t base = (size_t)(kb * 64 + nt) * 2 * 512 + (size_t)lane * 8 + j;
    wp[base] = hi;
    wp[base + 512] = lo;
}

// ---------------- conv5 via MFMA: y[m=(n,p)][o] = sum_c xc[n][c][p] W5[o][c] ----------------
// STATS pass: BN sum/sumsq per o.  !STATS pass: BN+lrelu+max/mean pool over p -> h.
// Block: 512 thr (8 waves), BM=256 rows (8 clouds), BN=256 cols. 3-term bf16 hi/lo GEMM.
template<bool STATS>
__global__ __launch_bounds__(512) void conv5_mfma_kernel(
    const float* __restrict__ xc, const unsigned short* __restrict__ wpack,
    const float* __restrict__ st, float* __restrict__ partS, float* __restrict__ partQ,
    float* __restrict__ h)
{
    const int nb = blockIdx.x;       // 0..3   o-range [nb*256, nb*256+256)
    const int mb = blockIdx.y;       // 0..255 clouds mb*8 .. mb*8+7
    const int t  = threadIdx.x;
    const int w  = t >> 6, l = t & 63;
    const int wm = w >> 2;           // M half (128 rows)
    const int wn = w & 3;            // N quarter (64 cols)
    const int lg = l >> 4, lm = l & 15;

    __shared__ unsigned short Ah[256][40];   // stride 40 (80B): 2-way bank conflict only
    __shared__ unsigned short Al[256][40];

    f32x4 acc[8][4];
    #pragma unroll
    for (int i = 0; i < 8; ++i)
        #pragma unroll
        for (int j2 = 0; j2 < 4; ++j2) acc[i][j2] = (f32x4)0.f;

    const size_t xbase = (size_t)(mb * 8) * (512 * P);

    for (int kb = 0; kb < 16; ++kb) {
        __syncthreads();   // previous-iter LDS reads done before overwrite
        // stage A chunk: 8 clouds x 32 c x 32 p, f32 -> bf16 hi/lo, transposed to [row=(ci,p)][k=c]
        for (int f = t; f < 2048; f += 512) {
            int ci = f >> 8;
            int rem = f & 255;
            int cl = rem >> 3;
            int p4 = rem & 7;
            const float4 v = *(const float4*)(xc + xbase + (size_t)ci * (512 * P)
                                              + (size_t)(kb * 32 + cl) * P + p4 * 4);
            #pragma unroll
            for (int e = 0; e < 4; ++e) {
                float xv = (&v.x)[e];
                unsigned short hi = f2bf(xv);
                unsigned short lo = f2bf(xv - bf2f(hi));
                int r = ci * 32 + p4 * 4 + e;
                Ah[r][cl] = hi;
                Al[r][cl] = lo;
            }
        }
        __syncthreads();

        bf16x8 Bh[4], Bl[4];
        #pragma unroll
        for (int nt = 0; nt < 4; ++nt) {
            int ntg = nb * 16 + wn * 4 + nt;
            const unsigned short* bp = wpack + (size_t)(kb * 64 + ntg) * 2 * 512 + (size_t)l * 8;
            Bh[nt] = *(const bf16x8*)bp;
            Bl[nt] = *(const bf16x8*)(bp + 512);
        }
        #pragma unroll
        for (int mt = 0; mt < 8; ++mt) {
            int row = wm * 128 + mt * 16 + lm;
            bf16x8 ah = *(const bf16x8*)&Ah[row][lg * 8];
            bf16x8 al = *(const bf16x8*)&Al[row][lg * 8];
            #pragma unroll
            for (int nt = 0; nt < 4; ++nt) {
                acc[mt][nt] = __builtin_amdgcn_mfma_f32_16x16x32_bf16(ah, Bl[nt], acc[mt][nt], 0, 0, 0);
                acc[mt][nt] = __builtin_amdgcn_mfma_f32_16x16x32_bf16(al, Bh[nt], acc[mt][nt], 0, 0, 0);
                acc[mt][nt] = __builtin_amdgcn_mfma_f32_16x16x32_bf16(ah, Bh[nt], acc[mt][nt], 0, 0, 0);
            }
        }
    }

    if constexpr (STATS) {
        #pragma unroll
        for (int nt = 0; nt < 4; ++nt) {
            float s = 0.f, q = 0.f;
            #pragma unroll
            for (int mt = 0; mt < 8; ++mt)
                #pragma unroll
                for (int r = 0; r < 4; ++r) { float v = acc[mt][nt][r]; s += v; q = fmaf(v, v, q); }
            s += __shfl_xor(s, 16); q += __shfl_xor(q, 16);
            s += __shfl_xor(s, 32); q += __shfl_xor(q, 32);
            if (l < 16) {
                int o = nb * 256 + wn * 64 + nt * 16 + lm;
                partS[(size_t)o * 2048 + mb * 2 + wm] = s;
                partQ[(size_t)o * 2048 + mb * 2 + wm] = q;
            }
        }
    } else {
        #pragma unroll
        for (int nt = 0; nt < 4; ++nt) {
            int o = nb * 256 + wn * 64 + nt * 16 + lm;
            float sc = st[o], sh = st[1024 + o];
            #pragma unroll
            for (int ci = 0; ci < 4; ++ci) {
                float mx = -INFINITY, sm = 0.f;
                #pragma unroll
                for (int half = 0; half < 2; ++half) {
                    int mt = ci * 2 + half;
                    #pragma unroll
                    for (int r = 0; r < 4; ++r) {
                        float v = lrelu(fmaf(sc, acc[mt][nt][r], sh));
                        mx = fmaxf(mx, v); sm += v;
                    }
                }
                mx = fmaxf(mx, __shfl_xor(mx, 16)); sm += __shfl_xor(sm, 16);
                mx = fmaxf(mx, __shfl_xor(mx, 32)); sm += __shfl_xor(sm, 32);
                if (l < 16) {
                    int n = mb * 8 + wm * 4 + ci;
                    h[(size_t)n * 2048 + o] = mx;
                    h[(size_t)n * 2048 + 1024 + o] = sm * (1.f / 32.f);
                }
            }
        }
    }
}

// ---------------- generic f32 GEMM: C[m][o] = sum_k A[m][k]*B[o][k] (+bias) ----------------
__global__ __launch_bounds__(256) void gemm_nt(const float* __restrict__ A, const float* __restrict__ B,
                                               const float* __restrict__ bias, float* __restrict__ Cc,
                                               int M, int Nn, int Kk)
{
    __shared__ float As[16][64];
    __shared__ float Bs[16][64];
    const int t = threadIdx.x;
    const int m0 = blockIdx.y * 64;
    const int o0 = blockIdx.x * 64;
    const int lm = t % 64;
    const int lk4 = (t / 64) * 4;
    const int tx = t % 16, ty = t / 16;
    float acc[4][4] = {};
    for (int k0 = 0; k0 < Kk; k0 += 16) {
        float4 av4 = *(const float4*)(A + (size_t)(m0 + lm) * Kk + k0 + lk4);
        float4 bv4 = make_float4(0.f, 0.f, 0.f, 0.f);
        if (o0 + lm < Nn) bv4 = *(const float4*)(B + (size_t)(o0 + lm) * Kk + k0 + lk4);
        __syncthreads();
        As[lk4 + 0][lm] = av4.x; As[lk4 + 1][lm] = av4.y; As[lk4 + 2][lm] = av4.z; As[lk4 + 3][lm] = av4.w;
        Bs[lk4 + 0][lm] = bv4.x; Bs[lk4 + 1][lm] = bv4.y; Bs[lk4 + 2][lm] = bv4.z; Bs[lk4 + 3][lm] = bv4.w;
        __syncthreads();
        #pragma unroll
        for (int kk = 0; kk < 16; ++kk) {
            float a[4], b[4];
            *(float4*)a = *(const float4*)&As[kk][ty * 4];
            *(float4*)b = *(const float4*)&Bs[kk][tx * 4];
            #pragma unroll
            for (int i = 0; i < 4; ++i)
                #pragma unroll
                for (int j = 0; j < 4; ++j) acc[i][j] = fmaf(a[i], b[j], acc[i][j]);
        }
    }
    #pragma unroll
    for (int i = 0; i < 4; ++i) {
        int m = m0 + ty * 4 + i;
        #pragma unroll
        for (int j = 0; j < 4; ++j) {
            int o = o0 + tx * 4 + j;
            if (o < Nn) Cc[(size_t)m * Nn + o] = acc[i][j] + (bias ? bias[o] : 0.f);
        }
    }
    (void)M;
}

// ---------------- per-column stats over rows (FC batchnorm, axis 0) ----------------
template<int NCPT>
__global__ __launch_bounds__(256) void colstats_kernel(const float* __restrict__ A, int NC,
                                                       float* __restrict__ partS, float* __restrict__ partQ)
{
    const int b = blockIdx.x, t = threadIdx.x;
    float S[NCPT], Q[NCPT];
    #pragma unroll
    for (int j = 0; j < NCPT; ++j) { S[j] = 0.f; Q[j] = 0.f; }
    for (int r = 0; r < 32; ++r) {
        const float* row = A + (size_t)(b * 32 + r) * NC;
        #pragma unroll
        for (int j = 0; j < NCPT; ++j) { float v = row[t + j * 256]; S[j] += v; Q[j] += v * v; }
    }
    #pragma unroll
    for (int j = 0; j < NCPT; ++j) {
        int o = t + j * 256;
        partS[(size_t)o * 2048 + b] = S[j];
        partQ[(size_t)o * 2048 + b] = Q[j];
    }
}

__global__ __launch_bounds__(256) void bnact_kernel(const float* __restrict__ in, const float* __restrict__ st,
                                                    float* __restrict__ out, int NC, int total)
{
    int i = blockIdx.x * 256 + threadIdx.x;
    if (i < total) {
        int o = i % NC;
        out[i] = lrelu(fmaf(st[o], in[i], st[1024 + o]));
    }
}

__global__ __launch_bounds__(256) void logsoftmax_kernel(float* __restrict__ out)
{
    const int n = blockIdx.x, t = threadIdx.x;
    float* row = out + (size_t)n * 800;
    __shared__ float red[256];
    float v[4];
    float mx = -INFINITY;
    #pragma unroll
    for (int j = 0; j < 4; ++j) {
        int i = t + j * 256;
        v[j] = (i < 800) ? row[i] : -INFINITY;
        mx = fmaxf(mx, v[j]);
    }
    red[t] = mx; __syncthreads();
    for (int w = 128; w > 0; w >>= 1) { if (t < w) red[t] = fmaxf(red[t], red[t + w]); __syncthreads(); }
    const float m = red[0]; __syncthreads();
    float s = 0.f;
    #pragma unroll
    for (int j = 0; j < 4; ++j) { int i = t + j * 256; if (i < 800) s += expf(v[j] - m); }
    red[t] = s; __syncthreads();
    for (int w = 128; w > 0; w >>= 1) { if (t < w) red[t] += red[t + w]; __syncthreads(); }
    const float lg = m + logf(red[0]);
    #pragma unroll
    for (int j = 0; j < 4; ++j) { int i = t + j * 256; if (i < 800) row[i] = v[j] - lg; }
}

extern "C" void kernel_launch(void* const* d_in, const int* in_sizes, int n_in,
                              void* d_out, int out_size, void* d_ws, size_t ws_size,
                              hipStream_t stream)
{
    (void)in_sizes; (void)n_in; (void)out_size; (void)ws_size;
    const float* x   = (const float*)d_in[0];
    const float* W1  = (const float*)d_in[2];
    const float* g1  = (const float*)d_in[3];
    const float* b1  = (const float*)d_in[4];
    const float* W2  = (const float*)d_in[5];
    const float* g2  = (const float*)d_in[6];
    const float* b2  = (const float*)d_in[7];
    const float* W3  = (const float*)d_in[8];
    const float* g3  = (const float*)d_in[9];
    const float* b3  = (const float*)d_in[10];
    const float* W4  = (const float*)d_in[11];
    const float* g4  = (const float*)d_in[12];
    const float* b4  = (const float*)d_in[13];
    const float* W5  = (const float*)d_in[14];
    const float* g5  = (const float*)d_in[15];
    const float* b5  = (const float*)d_in[16];
    const float* Wl1 = (const float*)d_in[17];
    const float* g6  = (const float*)d_in[18];
    const float* b6  = (const float*)d_in[19];
    const float* Wl2 = (const float*)d_in[20];
    const float* bl2 = (const float*)d_in[21];
    const float* g7  = (const float*)d_in[22];
    const float* b7  = (const float*)d_in[23];
    const float* Wl3 = (const float*)d_in[24];
    const float* bl3 = (const float*)d_in[25];

    char* ws = (char*)d_ws;
    size_t off = 0;
    auto alloc = [&](size_t bytes) -> void* {
        void* p = ws + off; off += (bytes + 255) & ~(size_t)255; return p;
    };
    float*         xc    = (float*)alloc((size_t)NPTS * 512 * P * 4);       // 134.2 MB
    unsigned char* idx   = (unsigned char*)alloc((size_t)NPTS * P * KNN_K); // 0.98 MB
    float*         partS = (float*)alloc((size_t)1024 * 2048 * 4);          // 8.4 MB
    float*         partQ = (float*)alloc((size_t)1024 * 2048 * 4);          // 8.4 MB
    float*         st    = (float*)alloc(2048 * 4);
    float*         wt    = (float*)alloc((size_t)512 * 1024 * 4);           // 2 MB (also holds W5 pack)
    float*         h     = (float*)alloc((size_t)2048 * 2048 * 4);          // 16.8 MB
    float*         h1p   = (float*)alloc((size_t)2048 * 512 * 4);           // 4.2 MB
    float* h1  = h;                 // h dead after FC1 gemm
    float* h2p = h + 1048576;
    float* h2  = h + 1572864;

    const float inv_edge = 1.f / (float)(NPTS * P * KNN_K);

    // ---- edge block 1: x(C=3) -> O=64 (xc ch 0..63) ----
    knn_kernel<3><<<NPTS, 64, 0, stream>>>(x, 3 * P, idx);
    build_wcat_kernel<<<(3 * 128 + 255) / 256, 256, 0, stream>>>(W1, wt, 3, 64);
    edge_pass_kernel<3, 64, false><<<NPTS, 256, 0, stream>>>(x, 3 * P, wt, idx, nullptr, nullptr, partS, partQ);
    reduce_stats_kernel<<<64, 256, 0, stream>>>(partS, partQ, g1, b1, st, 2048, inv_edge);
    edge_pass_kernel<3, 64, true><<<NPTS, 256, 0, stream>>>(x, 3 * P, wt, idx, st, xc + 0 * P, nullptr, nullptr);

    // ---- edge block 2: xc ch 0..63 -> O=64 (ch 64..127) ----
    knn_kernel<64><<<NPTS, 64, 0, stream>>>(xc, 512 * P, idx);
    build_wcat_kernel<<<(64 * 128 + 255) / 256, 256, 0, stream>>>(W2, wt, 64, 64);
    edge_pass_kernel<64, 64, false><<<NPTS, 256, 0, stream>>>(xc, 512 * P, wt, idx, nullptr, nullptr, partS, partQ);
    reduce_stats_kernel<<<64, 256, 0, stream>>>(partS, partQ, g2, b2, st, 2048, inv_edge);
    edge_pass_kernel<64, 64, true><<<NPTS, 256, 0, stream>>>(xc, 512 * P, wt, idx, st, xc + 64 * P, nullptr, nullptr);

    // ---- edge block 3: xc ch 64..127 -> O=128 (ch 128..255) ----
    knn_kernel<64><<<NPTS, 64, 0, stream>>>(xc + 64 * P, 512 * P, idx);
    build_wcat_kernel<<<(64 * 256 + 255) / 256, 256, 0, stream>>>(W3, wt, 64, 128);
    edge_pass_kernel<64, 128, false><<<NPTS, 256, 0, stream>>>(xc + 64 * P, 512 * P, wt, idx, nullptr, nullptr, partS, partQ);
    reduce_stats_kernel<<<128, 256, 0, stream>>>(partS, partQ, g3, b3, st, 2048, inv_edge);
    edge_pass_kernel<64, 128, true><<<NPTS, 256, 0, stream>>>(xc + 64 * P, 512 * P, wt, idx, st, xc + 128 * P, nullptr, nullptr);

    // ---- edge block 4: xc ch 128..255 -> O=256 (ch 256..511) ----
    knn_kernel<128><<<NPTS, 64, 0, stream>>>(xc + 128 * P, 512 * P, idx);
    build_wcat_kernel<<<(128 * 512 + 255) / 256, 256, 0, stream>>>(W4, wt, 128, 256);
    edge_pass_kernel<128, 256, false><<<NPTS, 256, 0, stream>>>(xc + 128 * P, 512 * P, wt, idx, nullptr, nullptr, partS, partQ);
    reduce_stats_kernel<<<256, 256, 0, stream>>>(partS, partQ, g4, b4, st, 2048, inv_edge);
    edge_pass_kernel<128, 256, true><<<NPTS, 256, 0, stream>>>(xc + 128 * P, 512 * P, wt, idx, st, xc + 256 * P, nullptr, nullptr);

    // ---- stage 5 via MFMA: 512 -> 1024, BN over (n,p), lrelu, max+mean pool over p ----
    pack_w5_kernel<<<2048, 256, 0, stream>>>(W5, (unsigned short*)wt);
    conv5_mfma_kernel<true><<<dim3(4, 256), 512, 0, stream>>>(xc, (const unsigned short*)wt, nullptr, partS, partQ, nullptr);
    reduce_stats_kernel<<<1024, 256, 0, stream>>>(partS, partQ, g5, b5, st, 512, 1.f / 65536.f);
    conv5_mfma_kernel<false><<<dim3(4, 256), 512, 0, stream>>>(xc, (const unsigned short*)wt, st, nullptr, nullptr, h);

    // ---- FC head ----
    gemm_nt<<<dim3(512 / 64, 2048 / 64), 256, 0, stream>>>(h, Wl1, nullptr, h1p, 2048, 512, 2048);
    colstats_kernel<2><<<64, 256, 0, stream>>>(h1p, 512, partS, partQ);
    reduce_stats_kernel<<<512, 256, 0, stream>>>(partS, partQ, g6, b6, st, 64, 1.f / 2048.f);
    bnact_kernel<<<(2048 * 512 + 255) / 256, 256, 0, stream>>>(h1p, st, h1, 512, 2048 * 512);

    gemm_nt<<<dim3(256 / 64, 2048 / 64), 256, 0, stream>>>(h1, Wl2, bl2, h2p, 2048, 256, 512);
    colstats_kernel<1><<<64, 256, 0, stream>>>(h2p, 256, partS, partQ);
    reduce_stats_kernel<<<256, 256, 0, stream>>>(partS, partQ, g7, b7, st, 64, 1.f / 2048.f);
    bnact_kernel<<<(2048 * 256 + 255) / 256, 256, 0, stream>>>(h2p, st, h2, 256, 2048 * 256);

    gemm_nt<<<dim3((800 + 63) / 64, 2048 / 64), 256, 0, stream>>>(h2, Wl3, bl3, (float*)d_out, 2048, 800, 256);
    logsoftmax_kernel<<<NPTS, 256, 0, stream>>>((float*)d_out);
}

// Round 5
// 1423.420 us; speedup vs baseline: 1.4701x; 1.1763x over previous
//
#include <hip/hip_runtime.h>
#include <hip/hip_bf16.h>
#include <cstdint>
#include <cstddef>

#define NPTS 2048
#define P 32
#define KNN_K 15
#define LRELU_NEG 0.2f
#define BN_EPS 1e-5f

__device__ __forceinline__ float lrelu(float x) { return x > 0.f ? x : LRELU_NEG * x; }

__device__ __forceinline__ unsigned short f2bf(float x) {      // RNE f32 -> bf16 bits
    union { float f; unsigned u; } uu; uu.f = x;
    unsigned r = uu.u + 0x7fffu + ((uu.u >> 16) & 1u);
    return (unsigned short)(r >> 16);
}
__device__ __forceinline__ float bf2f(unsigned short b) {
    union { unsigned u; float f; } uu; uu.u = ((unsigned)b) << 16;
    return uu.f;
}

typedef short bf16x8 __attribute__((ext_vector_type(8)));
typedef float f32x4  __attribute__((ext_vector_type(4)));

// ---------------- KNN: per-cloud pairwise -dist^2, top-15 (incl. self) ----------------
template<int C>
__global__ __launch_bounds__(64) void knn_kernel(const float* __restrict__ xin, int cloudStride,
                                                 unsigned char* __restrict__ idx)
{
    const int n = blockIdx.x, t = threadIdx.x;
    __shared__ float xs[C][P];
    __shared__ float xx[P];
    __shared__ float pd[P][P + 1];
    const float* xp = xin + (size_t)n * cloudStride;
    for (int i = t; i < C * P; i += 64) xs[i / P][i % P] = xp[i];
    __syncthreads();
    if (t < P) { float s = 0.f; for (int c = 0; c < C; ++c) { float v = xs[c][t]; s = fmaf(v, v, s); } xx[t] = s; }
    __syncthreads();
    for (int i = t; i < P * P; i += 64) {
        int p = i >> 5, q = i & 31;
        float d = 0.f;
        for (int c = 0; c < C; ++c) d = fmaf(xs[c][p], xs[c][q], d);
        pd[p][q] = 2.f * d - xx[p] - xx[q];   // diag exactly 0
    }
    __syncthreads();
    if (t < P) {
        for (int j = 0; j < KNN_K; ++j) {
            float best = -INFINITY; int bq = 0;
            for (int q = 0; q < P; ++q) { float v = pd[t][q]; if (v > best) { best = v; bq = q; } }
            idx[(size_t)n * (P * KNN_K) + t * KNN_K + j] = (unsigned char)bq;
            pd[t][bq] = -INFINITY;
        }
    }
}

// ---------------- Wcat^T, chunked column order ----------------
// column col in [0,2O): chunk = col/O2C, cl = col%O2C (O2C = 2O/NCHUNK, OC = O/NCHUNK)
//   cl <  OC: h-term of output o = chunk*OC+cl        -> W[o][c]
//   cl >= OC: g-term of output o = chunk*OC+cl-OC     -> W[o][C+c]-W[o][c]
__global__ __launch_bounds__(256) void build_wcat_kernel(const float* __restrict__ W, float* __restrict__ wt,
                                                         int C, int O, int NCHUNK)
{
    int i = blockIdx.x * 256 + threadIdx.x;
    int tot = C * 2 * O;
    if (i >= tot) return;
    int c = i / (2 * O), col = i % (2 * O);
    int O2C = 2 * O / NCHUNK, OC = O / NCHUNK;
    int chunk = col / O2C, cl = col % O2C;
    float v;
    if (cl < OC) { int o = chunk * OC + cl; v = W[(size_t)o * 2 * C + c]; }
    else { int o = chunk * OC + cl - OC; v = W[(size_t)o * 2 * C + C + c] - W[(size_t)o * 2 * C + c]; }
    wt[i] = v;
}

// ---------------- edge conv: per-cloud g/h GEMM in LDS, O-chunked for occupancy ----------------
// OUT=false: BN stats; OUT=true: normalize+lrelu+max -> xc
template<int C, int O, int NCHUNK, bool OUT>
__global__ __launch_bounds__(256) void edge_pass_kernel(
    const float* __restrict__ xin, int cloudStride,
    const float* __restrict__ wt,                  // [C][2O] chunk-ordered
    const unsigned char* __restrict__ idx,         // [N][P][K]
    const float* __restrict__ st,                  // OUT: st[o]=scale, st[1024+o]=shift
    float* __restrict__ xcout,                     // OUT: xc + chBase*P
    float* __restrict__ partS, float* __restrict__ partQ) // stats: [o][2048]
{
    constexpr int TOTC = 2 * O;
    constexpr int O2C = TOTC / NCHUNK;             // LDS cols per chunk
    constexpr int OC  = O / NCHUNK;                // outputs per chunk
    constexpr int TPC = (O2C >= 256) ? 1 : (256 / O2C);
    constexpr int CPT = (O2C > 256) ? (O2C / 256) : 1;
    constexpr int PP  = P / TPC;
    constexpr int TPO = 256 / OC;
    constexpr int PPo = P / TPO;
    const int n = blockIdx.x, t = threadIdx.x;

    __shared__ float xs[C][P];
    __shared__ float gh[P * O2C];
    __shared__ unsigned char idl[P * KNN_K];
    __shared__ float red[2][256];

    const float* xp = xin + (size_t)n * cloudStride;
    for (int i = t; i < C * P; i += 256) xs[i / P][i % P] = xp[i];
    for (int i = t; i < P * KNN_K; i += 256) idl[i] = idx[(size_t)n * (P * KNN_K) + i];

    const int col = (O2C >= 256) ? t : (t % O2C);
    const int p0  = ((O2C >= 256) ? 0 : (t / O2C)) * PP;
    const int o   = t % OC;
    const int p0c = (t / OC) * PPo;

    for (int chunk = 0; chunk < NCHUNK; ++chunk) {
        __syncthreads();   // xs/idl ready (chunk 0); prev chunk's gh/red reads done (chunk>0)

        // GEMM: gh[p][cl] = sum_c xs[c][p] * wt[c][chunk*O2C + cl]
        {
            float acc[CPT][PP];
            #pragma unroll
            for (int j = 0; j < CPT; ++j)
                #pragma unroll
                for (int p = 0; p < PP; ++p) acc[j][p] = 0.f;
            for (int c = 0; c < C; ++c) {
                float w[CPT];
                #pragma unroll
                for (int j = 0; j < CPT; ++j) w[j] = wt[(size_t)c * TOTC + chunk * O2C + col + j * 256];
                #pragma unroll
                for (int p = 0; p < PP; ++p) {
                    float xv = xs[c][p0 + p];
                    #pragma unroll
                    for (int j = 0; j < CPT; ++j) acc[j][p] = fmaf(w[j], xv, acc[j][p]);
                }
            }
            #pragma unroll
            for (int j = 0; j < CPT; ++j)
                #pragma unroll
                for (int p = 0; p < PP; ++p) gh[(p0 + p) * O2C + col + j * 256] = acc[j][p];
        }
        __syncthreads();

        // combine: y[p][k][o] = gh[idx[p][k]][o] + gh[p][OC+o]
        if constexpr (!OUT) {
            float ssum = 0.f, ssq = 0.f;
            #pragma unroll
            for (int p = 0; p < PPo; ++p) {
                const int pp = p0c + p;
                const float g = gh[pp * O2C + OC + o];
                #pragma unroll
                for (int k = 0; k < KNN_K; ++k) {
                    const int q = idl[pp * KNN_K + k];
                    float yv = gh[q * O2C + o] + g;
                    ssum += yv; ssq += yv * yv;
                }
            }
            red[0][t] = ssum; red[1][t] = ssq;
            __syncthreads();
            if (t < OC) {
                float S = 0.f, Q = 0.f;
                #pragma unroll
                for (int j = 0; j < TPO; ++j) { S += red[0][t + j * OC]; Q += red[1][t + j * OC]; }
                partS[(size_t)(chunk * OC + t) * 2048 + n] = S;
                partQ[(size_t)(chunk * OC + t) * 2048 + n] = Q;
            }
        } else {
            const float s = st[chunk * OC + o], sh = st[1024 + chunk * OC + o];
            float rbuf[PPo];
            #pragma unroll
            for (int p = 0; p < PPo; ++p) {
                const int pp = p0c + p;
                const float g = gh[pp * O2C + OC + o];
                float mx = -INFINITY, mn = INFINITY;
                #pragma unroll
                for (int k = 0; k < KNN_K; ++k) {
                    const int q = idl[pp * KNN_K + k];
                    float yv = gh[q * O2C + o] + g;
                    mx = fmaxf(mx, yv); mn = fminf(mn, yv);
                }
                rbuf[p] = lrelu(fmaf(s, (s >= 0.f ? mx : mn), sh));  // lrelu/affine monotone in y
            }
            __syncthreads();   // all gh reads done
            #pragma unroll
            for (int p = 0; p < PPo; ++p) gh[o * (P + 1) + p0c + p] = rbuf[p];
            __syncthreads();
            for (int i = t; i < OC * P; i += 256)
                xcout[(size_t)n * (512 * P) + chunk * OC * P + i] = gh[(i / P) * (P + 1) + (i % P)];
        }
    }
}

// ---------------- reduce partials -> scale/shift per channel ----------------
__global__ __launch_bounds__(256) void reduce_stats_kernel(const float* __restrict__ partS,
                                                           const float* __restrict__ partQ,
                                                           const float* __restrict__ gamma,
                                                           const float* __restrict__ beta,
                                                           float* __restrict__ st, int nparts, float inv_count)
{
    const int o = blockIdx.x, t = threadIdx.x;
    __shared__ float rs[256], rq[256];
    float S = 0.f, Q = 0.f;
    for (int i = t; i < nparts; i += 256) { S += partS[(size_t)o * 2048 + i]; Q += partQ[(size_t)o * 2048 + i]; }
    rs[t] = S; rq[t] = Q; __syncthreads();
    for (int w = 128; w > 0; w >>= 1) { if (t < w) { rs[t] += rs[t + w]; rq[t] += rq[t + w]; } __syncthreads(); }
    if (t == 0) {
        float m = rs[0] * inv_count;
        float v = fmaxf(rq[0] * inv_count - m * m, 0.f);
        float s = gamma[o] * rsqrtf(v + BN_EPS);
        st[o] = s;
        st[1024 + o] = fmaf(-m, s, beta[o]);
    }
}

// ---------------- pack W5 into MFMA fragment order, bf16 hi/lo ----------------
// layout: wp[((kb*64 + nt)*2 + term)*512 + lane*8 + j]; c = kb*32+(lane>>4)*8+j; o = nt*16+(lane&15)
// total elements: kb(16)*nt(64)*lane(64)*j(8) = 2^19
__global__ __launch_bounds__(256) void pack_w5_kernel(const float* __restrict__ W5, unsigned short* __restrict__ wp)
{
    int i = blockIdx.x * 256 + threadIdx.x;
    if (i >= (1 << 19)) return;
    int j = i & 7, lane = (i >> 3) & 63, nt = (i >> 9) & 63, kb = i >> 15;   // kb 0..15
    int c = kb * 32 + (lane >> 4) * 8 + j;
    int o = nt * 16 + (lane & 15);
    float f = W5[(size_t)o * 512 + c];
    unsigned short hi = f2bf(f);
    unsigned short lo = f2bf(f - bf2f(hi));
    size_t base = (size_t)(kb * 64 + nt) * 2 * 512 + (size_t)lane * 8 + j;
    wp[base] = hi;
    wp[base + 512] = lo;
}

// ---------------- conv5 via MFMA: y[m=(n,p)][o] = sum_c xc[n][c][p] W5[o][c] ----------------
// STATS pass: BN sum/sumsq per o.  !STATS pass: BN+lrelu+max/mean pool over p -> h.
// Block: 512 thr (8 waves), BM=256 rows (8 clouds), BN=256 cols. 3-term bf16 hi/lo GEMM.
template<bool STATS>
__global__ __launch_bounds__(512) void conv5_mfma_kernel(
    const float* __restrict__ xc, const unsigned short* __restrict__ wpack,
    const float* __restrict__ st, float* __restrict__ partS, float* __restrict__ partQ,
    float* __restrict__ h)
{
    const int nb = blockIdx.x;       // 0..3   o-range [nb*256, nb*256+256)
    const int mb = blockIdx.y;       // 0..255 clouds mb*8 .. mb*8+7
    const int t  = threadIdx.x;
    const int w  = t >> 6, l = t & 63;
    const int wm = w >> 2;           // M half (128 rows)
    const int wn = w & 3;            // N quarter (64 cols)
    const int lg = l >> 4, lm = l & 15;

    __shared__ unsigned short Ah[256][40];   // stride 40 (80B): 2-way bank conflict only
    __shared__ unsigned short Al[256][40];

    f32x4 acc[8][4];
    #pragma unroll
    for (int i = 0; i < 8; ++i)
        #pragma unroll
        for (int j2 = 0; j2 < 4; ++j2) acc[i][j2] = (f32x4)0.f;

    const size_t xbase = (size_t)(mb * 8) * (512 * P);

    for (int kb = 0; kb < 16; ++kb) {
        __syncthreads();   // previous-iter LDS reads done before overwrite
        // stage A chunk: 8 clouds x 32 c x 32 p, f32 -> bf16 hi/lo, transposed to [row=(ci,p)][k=c]
        for (int f = t; f < 2048; f += 512) {
            int ci = f >> 8;
            int rem = f & 255;
            int cl = rem >> 3;
            int p4 = rem & 7;
            const float4 v = *(const float4*)(xc + xbase + (size_t)ci * (512 * P)
                                              + (size_t)(kb * 32 + cl) * P + p4 * 4);
            #pragma unroll
            for (int e = 0; e < 4; ++e) {
                float xv = (&v.x)[e];
                unsigned short hi = f2bf(xv);
                unsigned short lo = f2bf(xv - bf2f(hi));
                int r = ci * 32 + p4 * 4 + e;
                Ah[r][cl] = hi;
                Al[r][cl] = lo;
            }
        }
        __syncthreads();

        bf16x8 Bh[4], Bl[4];
        #pragma unroll
        for (int nt = 0; nt < 4; ++nt) {
            int ntg = nb * 16 + wn * 4 + nt;
            const unsigned short* bp = wpack + (size_t)(kb * 64 + ntg) * 2 * 512 + (size_t)l * 8;
            Bh[nt] = *(const bf16x8*)bp;
            Bl[nt] = *(const bf16x8*)(bp + 512);
        }
        #pragma unroll
        for (int mt = 0; mt < 8; ++mt) {
            int row = wm * 128 + mt * 16 + lm;
            bf16x8 ah = *(const bf16x8*)&Ah[row][lg * 8];
            bf16x8 al = *(const bf16x8*)&Al[row][lg * 8];
            #pragma unroll
            for (int nt = 0; nt < 4; ++nt) {
                acc[mt][nt] = __builtin_amdgcn_mfma_f32_16x16x32_bf16(ah, Bl[nt], acc[mt][nt], 0, 0, 0);
                acc[mt][nt] = __builtin_amdgcn_mfma_f32_16x16x32_bf16(al, Bh[nt], acc[mt][nt], 0, 0, 0);
                acc[mt][nt] = __builtin_amdgcn_mfma_f32_16x16x32_bf16(ah, Bh[nt], acc[mt][nt], 0, 0, 0);
            }
        }
    }

    if constexpr (STATS) {
        #pragma unroll
        for (int nt = 0; nt < 4; ++nt) {
            float s = 0.f, q = 0.f;
            #pragma unroll
            for (int mt = 0; mt < 8; ++mt)
                #pragma unroll
                for (int r = 0; r < 4; ++r) { float v = acc[mt][nt][r]; s += v; q = fmaf(v, v, q); }
            s += __shfl_xor(s, 16); q += __shfl_xor(q, 16);
            s += __shfl_xor(s, 32); q += __shfl_xor(q, 32);
            if (l < 16) {
                int o = nb * 256 + wn * 64 + nt * 16 + lm;
                partS[(size_t)o * 2048 + mb * 2 + wm] = s;
                partQ[(size_t)o * 2048 + mb * 2 + wm] = q;
            }
        }
    } else {
        #pragma unroll
        for (int nt = 0; nt < 4; ++nt) {
            int o = nb * 256 + wn * 64 + nt * 16 + lm;
            float sc = st[o], sh = st[1024 + o];
            #pragma unroll
            for (int ci = 0; ci < 4; ++ci) {
                float mx = -INFINITY, sm = 0.f;
                #pragma unroll
                for (int half = 0; half < 2; ++half) {
                    int mt = ci * 2 + half;
                    #pragma unroll
                    for (int r = 0; r < 4; ++r) {
                        float v = lrelu(fmaf(sc, acc[mt][nt][r], sh));
                        mx = fmaxf(mx, v); sm += v;
                    }
                }
                mx = fmaxf(mx, __shfl_xor(mx, 16)); sm += __shfl_xor(sm, 16);
                mx = fmaxf(mx, __shfl_xor(mx, 32)); sm += __shfl_xor(sm, 32);
                if (l < 16) {
                    int n = mb * 8 + wm * 4 + ci;
                    h[(size_t)n * 2048 + o] = mx;
                    h[(size_t)n * 2048 + 1024 + o] = sm * (1.f / 32.f);
                }
            }
        }
    }
}

// ---------------- generic f32 GEMM: C[m][o] = sum_k A[m][k]*B[o][k] (+bias) ----------------
__global__ __launch_bounds__(256) void gemm_nt(const float* __restrict__ A, const float* __restrict__ B,
                                               const float* __restrict__ bias, float* __restrict__ Cc,
                                               int M, int Nn, int Kk)
{
    __shared__ float As[16][64];
    __shared__ float Bs[16][64];
    const int t = threadIdx.x;
    const int m0 = blockIdx.y * 64;
    const int o0 = blockIdx.x * 64;
    const int lm = t % 64;
    const int lk4 = (t / 64) * 4;
    const int tx = t % 16, ty = t / 16;
    float acc[4][4] = {};
    for (int k0 = 0; k0 < Kk; k0 += 16) {
        float4 av4 = *(const float4*)(A + (size_t)(m0 + lm) * Kk + k0 + lk4);
        float4 bv4 = make_float4(0.f, 0.f, 0.f, 0.f);
        if (o0 + lm < Nn) bv4 = *(const float4*)(B + (size_t)(o0 + lm) * Kk + k0 + lk4);
        __syncthreads();
        As[lk4 + 0][lm] = av4.x; As[lk4 + 1][lm] = av4.y; As[lk4 + 2][lm] = av4.z; As[lk4 + 3][lm] = av4.w;
        Bs[lk4 + 0][lm] = bv4.x; Bs[lk4 + 1][lm] = bv4.y; Bs[lk4 + 2][lm] = bv4.z; Bs[lk4 + 3][lm] = bv4.w;
        __syncthreads();
        #pragma unroll
        for (int kk = 0; kk < 16; ++kk) {
            float a[4], b[4];
            *(float4*)a = *(const float4*)&As[kk][ty * 4];
            *(float4*)b = *(const float4*)&Bs[kk][tx * 4];
            #pragma unroll
            for (int i = 0; i < 4; ++i)
                #pragma unroll
                for (int j = 0; j < 4; ++j) acc[i][j] = fmaf(a[i], b[j], acc[i][j]);
        }
    }
    #pragma unroll
    for (int i = 0; i < 4; ++i) {
        int m = m0 + ty * 4 + i;
        #pragma unroll
        for (int j = 0; j < 4; ++j) {
            int o = o0 + tx * 4 + j;
            if (o < Nn) Cc[(size_t)m * Nn + o] = acc[i][j] + (bias ? bias[o] : 0.f);
        }
    }
    (void)M;
}

// ---------------- per-column stats over rows (FC batchnorm, axis 0) ----------------
template<int NCPT>
__global__ __launch_bounds__(256) void colstats_kernel(const float* __restrict__ A, int NC,
                                                       float* __restrict__ partS, float* __restrict__ partQ)
{
    const int b = blockIdx.x, t = threadIdx.x;
    float S[NCPT], Q[NCPT];
    #pragma unroll
    for (int j = 0; j < NCPT; ++j) { S[j] = 0.f; Q[j] = 0.f; }
    for (int r = 0; r < 32; ++r) {
        const float* row = A + (size_t)(b * 32 + r) * NC;
        #pragma unroll
        for (int j = 0; j < NCPT; ++j) { float v = row[t + j * 256]; S[j] += v; Q[j] += v * v; }
    }
    #pragma unroll
    for (int j = 0; j < NCPT; ++j) {
        int o = t + j * 256;
        partS[(size_t)o * 2048 + b] = S[j];
        partQ[(size_t)o * 2048 + b] = Q[j];
    }
}

__global__ __launch_bounds__(256) void bnact_kernel(const float* __restrict__ in, const float* __restrict__ st,
                                                    float* __restrict__ out, int NC, int total)
{
    int i = blockIdx.x * 256 + threadIdx.x;
    if (i < total) {
        int o = i % NC;
        out[i] = lrelu(fmaf(st[o], in[i], st[1024 + o]));
    }
}

__global__ __launch_bounds__(256) void logsoftmax_kernel(float* __restrict__ out)
{
    const int n = blockIdx.x, t = threadIdx.x;
    float* row = out + (size_t)n * 800;
    __shared__ float red[256];
    float v[4];
    float mx = -INFINITY;
    #pragma unroll
    for (int j = 0; j < 4; ++j) {
        int i = t + j * 256;
        v[j] = (i < 800) ? row[i] : -INFINITY;
        mx = fmaxf(mx, v[j]);
    }
    red[t] = mx; __syncthreads();
    for (int w = 128; w > 0; w >>= 1) { if (t < w) red[t] = fmaxf(red[t], red[t + w]); __syncthreads(); }
    const float m = red[0]; __syncthreads();
    float s = 0.f;
    #pragma unroll
    for (int j = 0; j < 4; ++j) { int i = t + j * 256; if (i < 800) s += expf(v[j] - m); }
    red[t] = s; __syncthreads();
    for (int w = 128; w > 0; w >>= 1) { if (t < w) red[t] += red[t + w]; __syncthreads(); }
    const float lg = m + logf(red[0]);
    #pragma unroll
    for (int j = 0; j < 4; ++j) { int i = t + j * 256; if (i < 800) row[i] = v[j] - lg; }
}

extern "C" void kernel_launch(void* const* d_in, const int* in_sizes, int n_in,
                              void* d_out, int out_size, void* d_ws, size_t ws_size,
                              hipStream_t stream)
{
    (void)in_sizes; (void)n_in; (void)out_size; (void)ws_size;
    const float* x   = (const float*)d_in[0];
    const float* W1  = (const float*)d_in[2];
    const float* g1  = (const float*)d_in[3];
    const float* b1  = (const float*)d_in[4];
    const float* W2  = (const float*)d_in[5];
    const float* g2  = (const float*)d_in[6];
    const float* b2  = (const float*)d_in[7];
    const float* W3  = (const float*)d_in[8];
    const float* g3  = (const float*)d_in[9];
    const float* b3  = (const float*)d_in[10];
    const float* W4  = (const float*)d_in[11];
    const float* g4  = (const float*)d_in[12];
    const float* b4  = (const float*)d_in[13];
    const float* W5  = (const float*)d_in[14];
    const float* g5  = (const float*)d_in[15];
    const float* b5  = (const float*)d_in[16];
    const float* Wl1 = (const float*)d_in[17];
    const float* g6  = (const float*)d_in[18];
    const float* b6  = (const float*)d_in[19];
    const float* Wl2 = (const float*)d_in[20];
    const float* bl2 = (const float*)d_in[21];
    const float* g7  = (const float*)d_in[22];
    const float* b7  = (const float*)d_in[23];
    const float* Wl3 = (const float*)d_in[24];
    const float* bl3 = (const float*)d_in[25];

    char* ws = (char*)d_ws;
    size_t off = 0;
    auto alloc = [&](size_t bytes) -> void* {
        void* p = ws + off; off += (bytes + 255) & ~(size_t)255; return p;
    };
    float*         xc    = (float*)alloc((size_t)NPTS * 512 * P * 4);       // 134.2 MB
    unsigned char* idx   = (unsigned char*)alloc((size_t)NPTS * P * KNN_K); // 0.98 MB
    float*         partS = (float*)alloc((size_t)1024 * 2048 * 4);          // 8.4 MB
    float*         partQ = (float*)alloc((size_t)1024 * 2048 * 4);          // 8.4 MB
    float*         st    = (float*)alloc(2048 * 4);
    float*         wt    = (float*)alloc((size_t)512 * 1024 * 4);           // 2 MB (also holds W5 pack)
    float*         h     = (float*)alloc((size_t)2048 * 2048 * 4);          // 16.8 MB
    float*         h1p   = (float*)alloc((size_t)2048 * 512 * 4);           // 4.2 MB
    float* h1  = h;                 // h dead after FC1 gemm
    float* h2p = h + 1048576;
    float* h2  = h + 1572864;

    const float inv_edge = 1.f / (float)(NPTS * P * KNN_K);

    // ---- edge block 1: x(C=3) -> O=64 (xc ch 0..63) ----
    knn_kernel<3><<<NPTS, 64, 0, stream>>>(x, 3 * P, idx);
    build_wcat_kernel<<<(3 * 128 + 255) / 256, 256, 0, stream>>>(W1, wt, 3, 64, 1);
    edge_pass_kernel<3, 64, 1, false><<<NPTS, 256, 0, stream>>>(x, 3 * P, wt, idx, nullptr, nullptr, partS, partQ);
    reduce_stats_kernel<<<64, 256, 0, stream>>>(partS, partQ, g1, b1, st, 2048, inv_edge);
    edge_pass_kernel<3, 64, 1, true><<<NPTS, 256, 0, stream>>>(x, 3 * P, wt, idx, st, xc + 0 * P, nullptr, nullptr);

    // ---- edge block 2: xc ch 0..63 -> O=64 (ch 64..127) ----
    knn_kernel<64><<<NPTS, 64, 0, stream>>>(xc, 512 * P, idx);
    build_wcat_kernel<<<(64 * 128 + 255) / 256, 256, 0, stream>>>(W2, wt, 64, 64, 1);
    edge_pass_kernel<64, 64, 1, false><<<NPTS, 256, 0, stream>>>(xc, 512 * P, wt, idx, nullptr, nullptr, partS, partQ);
    reduce_stats_kernel<<<64, 256, 0, stream>>>(partS, partQ, g2, b2, st, 2048, inv_edge);
    edge_pass_kernel<64, 64, 1, true><<<NPTS, 256, 0, stream>>>(xc, 512 * P, wt, idx, st, xc + 64 * P, nullptr, nullptr);

    // ---- edge block 3: xc ch 64..127 -> O=128 (ch 128..255), 2 chunks ----
    knn_kernel<64><<<NPTS, 64, 0, stream>>>(xc + 64 * P, 512 * P, idx);
    build_wcat_kernel<<<(64 * 256 + 255) / 256, 256, 0, stream>>>(W3, wt, 64, 128, 2);
    edge_pass_kernel<64, 128, 2, false><<<NPTS, 256, 0, stream>>>(xc + 64 * P, 512 * P, wt, idx, nullptr, nullptr, partS, partQ);
    reduce_stats_kernel<<<128, 256, 0, stream>>>(partS, partQ, g3, b3, st, 2048, inv_edge);
    edge_pass_kernel<64, 128, 2, true><<<NPTS, 256, 0, stream>>>(xc + 64 * P, 512 * P, wt, idx, st, xc + 128 * P, nullptr, nullptr);

    // ---- edge block 4: xc ch 128..255 -> O=256 (ch 256..511), 2 chunks ----
    knn_kernel<128><<<NPTS, 64, 0, stream>>>(xc + 128 * P, 512 * P, idx);
    build_wcat_kernel<<<(128 * 512 + 255) / 256, 256, 0, stream>>>(W4, wt, 128, 256, 2);
    edge_pass_kernel<128, 256, 2, false><<<NPTS, 256, 0, stream>>>(xc + 128 * P, 512 * P, wt, idx, nullptr, nullptr, partS, partQ);
    reduce_stats_kernel<<<256, 256, 0, stream>>>(partS, partQ, g4, b4, st, 2048, inv_edge);
    edge_pass_kernel<128, 256, 2, true><<<NPTS, 256, 0, stream>>>(xc + 128 * P, 512 * P, wt, idx, st, xc + 256 * P, nullptr, nullptr);

    // ---- stage 5 via MFMA: 512 -> 1024, BN over (n,p), lrelu, max+mean pool over p ----
    pack_w5_kernel<<<2048, 256, 0, stream>>>(W5, (unsigned short*)wt);
    conv5_mfma_kernel<true><<<dim3(4, 256), 512, 0, stream>>>(xc, (const unsigned short*)wt, nullptr, partS, partQ, nullptr);
    reduce_stats_kernel<<<1024, 256, 0, stream>>>(partS, partQ, g5, b5, st, 512, 1.f / 65536.f);
    conv5_mfma_kernel<false><<<dim3(4, 256), 512, 0, stream>>>(xc, (const unsigned short*)wt, st, nullptr, nullptr, h);

    // ---- FC head ----
    gemm_nt<<<dim3(512 / 64, 2048 / 64), 256, 0, stream>>>(h, Wl1, nullptr, h1p, 2048, 512, 2048);
    colstats_kernel<2><<<64, 256, 0, stream>>>(h1p, 512, partS, partQ);
    reduce_stats_kernel<<<512, 256, 0, stream>>>(partS, partQ, g6, b6, st, 64, 1.f / 2048.f);
    bnact_kernel<<<(2048 * 512 + 255) / 256, 256, 0, stream>>>(h1p, st, h1, 512, 2048 * 512);

    gemm_nt<<<dim3(256 / 64, 2048 / 64), 256, 0, stream>>>(h1, Wl2, bl2, h2p, 2048, 256, 512);
    colstats_kernel<1><<<64, 256, 0, stream>>>(h2p, 256, partS, partQ);
    reduce_stats_kernel<<<256, 256, 0, stream>>>(partS, partQ, g7, b7, st, 64, 1.f / 2048.f);
    bnact_kernel<<<(2048 * 256 + 255) / 256, 256, 0, stream>>>(h2p, st, h2, 256, 2048 * 256);

    gemm_nt<<<dim3((800 + 63) / 64, 2048 / 64), 256, 0, stream>>>(h2, Wl3, bl3, (float*)d_out, 2048, 800, 256);
    logsoftmax_kernel<<<NPTS, 256, 0, stream>>>((float*)d_out);
}

// Round 6
// 1189.286 us; speedup vs baseline: 1.7596x; 1.1969x over previous
//
#include <hip/hip_runtime.h>
#include <hip/hip_bf16.h>
#include <cstdint>
#include <cstddef>

#define NPTS 2048
#define P 32
#define KNN_K 15
#define LRELU_NEG 0.2f
#define BN_EPS 1e-5f

__device__ __forceinline__ float lrelu(float x) { return x > 0.f ? x : LRELU_NEG * x; }

__device__ __forceinline__ unsigned short f2bf(float x) {      // RNE f32 -> bf16 bits
    union { float f; unsigned u; } uu; uu.f = x;
    unsigned r = uu.u + 0x7fffu + ((uu.u >> 16) & 1u);
    return (unsigned short)(r >> 16);
}
__device__ __forceinline__ float bf2f(unsigned short b) {
    union { unsigned u; float f; } uu; uu.u = ((unsigned)b) << 16;
    return uu.f;
}

typedef short bf16x8 __attribute__((ext_vector_type(8)));
typedef float f32x4  __attribute__((ext_vector_type(4)));

// ---------------- KNN: per-cloud pairwise -dist^2, top-15 (incl. self) ----------------
template<int C>
__global__ __launch_bounds__(64) void knn_kernel(const float* __restrict__ xin, int cloudStride,
                                                 unsigned char* __restrict__ idx)
{
    const int n = blockIdx.x, t = threadIdx.x;
    __shared__ float xs[C][P];
    __shared__ float xx[P];
    __shared__ float pd[P][P + 1];
    const float* xp = xin + (size_t)n * cloudStride;
    for (int i = t; i < C * P; i += 64) xs[i / P][i % P] = xp[i];
    __syncthreads();
    if (t < P) { float s = 0.f; for (int c = 0; c < C; ++c) { float v = xs[c][t]; s = fmaf(v, v, s); } xx[t] = s; }
    __syncthreads();
    for (int i = t; i < P * P; i += 64) {
        int p = i >> 5, q = i & 31;
        float d = 0.f;
        for (int c = 0; c < C; ++c) d = fmaf(xs[c][p], xs[c][q], d);
        pd[p][q] = 2.f * d - xx[p] - xx[q];   // diag exactly 0
    }
    __syncthreads();
    if (t < P) {
        for (int j = 0; j < KNN_K; ++j) {
            float best = -INFINITY; int bq = 0;
            for (int q = 0; q < P; ++q) { float v = pd[t][q]; if (v > best) { best = v; bq = q; } }
            idx[(size_t)n * (P * KNN_K) + t * KNN_K + j] = (unsigned char)bq;
            pd[t][bq] = -INFINITY;
        }
    }
}

// ---------------- Wcat^T, chunked column order ----------------
__global__ __launch_bounds__(256) void build_wcat_kernel(const float* __restrict__ W, float* __restrict__ wt,
                                                         int C, int O, int NCHUNK)
{
    int i = blockIdx.x * 256 + threadIdx.x;
    int tot = C * 2 * O;
    if (i >= tot) return;
    int c = i / (2 * O), col = i % (2 * O);
    int O2C = 2 * O / NCHUNK, OC = O / NCHUNK;
    int chunk = col / O2C, cl = col % O2C;
    float v;
    if (cl < OC) { int o = chunk * OC + cl; v = W[(size_t)o * 2 * C + c]; }
    else { int o = chunk * OC + cl - OC; v = W[(size_t)o * 2 * C + C + c] - W[(size_t)o * 2 * C + c]; }
    wt[i] = v;
}

// ---------------- edge conv: per-cloud g/h GEMM in LDS, O-chunked for occupancy ----------------
template<int C, int O, int NCHUNK, bool OUT>
__global__ __launch_bounds__(256) void edge_pass_kernel(
    const float* __restrict__ xin, int cloudStride,
    const float* __restrict__ wt,
    const unsigned char* __restrict__ idx,
    const float* __restrict__ st,
    float* __restrict__ xcout,
    float* __restrict__ partS, float* __restrict__ partQ)
{
    constexpr int TOTC = 2 * O;
    constexpr int O2C = TOTC / NCHUNK;
    constexpr int OC  = O / NCHUNK;
    constexpr int TPC = (O2C >= 256) ? 1 : (256 / O2C);
    constexpr int CPT = (O2C > 256) ? (O2C / 256) : 1;
    constexpr int PP  = P / TPC;
    constexpr int TPO = 256 / OC;
    constexpr int PPo = P / TPO;
    const int n = blockIdx.x, t = threadIdx.x;

    __shared__ float xs[C][P];
    __shared__ float gh[P * O2C];
    __shared__ unsigned char idl[P * KNN_K];
    __shared__ float red[2][256];

    const float* xp = xin + (size_t)n * cloudStride;
    for (int i = t; i < C * P; i += 256) xs[i / P][i % P] = xp[i];
    for (int i = t; i < P * KNN_K; i += 256) idl[i] = idx[(size_t)n * (P * KNN_K) + i];

    const int col = (O2C >= 256) ? t : (t % O2C);
    const int p0  = ((O2C >= 256) ? 0 : (t / O2C)) * PP;
    const int o   = t % OC;
    const int p0c = (t / OC) * PPo;

    for (int chunk = 0; chunk < NCHUNK; ++chunk) {
        __syncthreads();

        {
            float acc[CPT][PP];
            #pragma unroll
            for (int j = 0; j < CPT; ++j)
                #pragma unroll
                for (int p = 0; p < PP; ++p) acc[j][p] = 0.f;
            for (int c = 0; c < C; ++c) {
                float w[CPT];
                #pragma unroll
                for (int j = 0; j < CPT; ++j) w[j] = wt[(size_t)c * TOTC + chunk * O2C + col + j * 256];
                #pragma unroll
                for (int p = 0; p < PP; ++p) {
                    float xv = xs[c][p0 + p];
                    #pragma unroll
                    for (int j = 0; j < CPT; ++j) acc[j][p] = fmaf(w[j], xv, acc[j][p]);
                }
            }
            #pragma unroll
            for (int j = 0; j < CPT; ++j)
                #pragma unroll
                for (int p = 0; p < PP; ++p) gh[(p0 + p) * O2C + col + j * 256] = acc[j][p];
        }
        __syncthreads();

        if constexpr (!OUT) {
            float ssum = 0.f, ssq = 0.f;
            #pragma unroll
            for (int p = 0; p < PPo; ++p) {
                const int pp = p0c + p;
                const float g = gh[pp * O2C + OC + o];
                #pragma unroll
                for (int k = 0; k < KNN_K; ++k) {
                    const int q = idl[pp * KNN_K + k];
                    float yv = gh[q * O2C + o] + g;
                    ssum += yv; ssq += yv * yv;
                }
            }
            red[0][t] = ssum; red[1][t] = ssq;
            __syncthreads();
            if (t < OC) {
                float S = 0.f, Q = 0.f;
                #pragma unroll
                for (int j = 0; j < TPO; ++j) { S += red[0][t + j * OC]; Q += red[1][t + j * OC]; }
                partS[(size_t)(chunk * OC + t) * 2048 + n] = S;
                partQ[(size_t)(chunk * OC + t) * 2048 + n] = Q;
            }
        } else {
            const float s = st[chunk * OC + o], sh = st[1024 + chunk * OC + o];
            float rbuf[PPo];
            #pragma unroll
            for (int p = 0; p < PPo; ++p) {
                const int pp = p0c + p;
                const float g = gh[pp * O2C + OC + o];
                float mx = -INFINITY, mn = INFINITY;
                #pragma unroll
                for (int k = 0; k < KNN_K; ++k) {
                    const int q = idl[pp * KNN_K + k];
                    float yv = gh[q * O2C + o] + g;
                    mx = fmaxf(mx, yv); mn = fminf(mn, yv);
                }
                rbuf[p] = lrelu(fmaf(s, (s >= 0.f ? mx : mn), sh));
            }
            __syncthreads();
            #pragma unroll
            for (int p = 0; p < PPo; ++p) gh[o * (P + 1) + p0c + p] = rbuf[p];
            __syncthreads();
            for (int i = t; i < OC * P; i += 256)
                xcout[(size_t)n * (512 * P) + chunk * OC * P + i] = gh[(i / P) * (P + 1) + (i % P)];
        }
    }
}

// ---------------- reduce partials -> scale/shift per channel ----------------
__global__ __launch_bounds__(256) void reduce_stats_kernel(const float* __restrict__ partS,
                                                           const float* __restrict__ partQ,
                                                           const float* __restrict__ gamma,
                                                           const float* __restrict__ beta,
                                                           float* __restrict__ st, int nparts, float inv_count)
{
    const int o = blockIdx.x, t = threadIdx.x;
    __shared__ float rs[256], rq[256];
    float S = 0.f, Q = 0.f;
    for (int i = t; i < nparts; i += 256) { S += partS[(size_t)o * 2048 + i]; Q += partQ[(size_t)o * 2048 + i]; }
    rs[t] = S; rq[t] = Q; __syncthreads();
    for (int w = 128; w > 0; w >>= 1) { if (t < w) { rs[t] += rs[t + w]; rq[t] += rq[t + w]; } __syncthreads(); }
    if (t == 0) {
        float m = rs[0] * inv_count;
        float v = fmaxf(rq[0] * inv_count - m * m, 0.f);
        float s = gamma[o] * rsqrtf(v + BN_EPS);
        st[o] = s;
        st[1024 + o] = fmaf(-m, s, beta[o]);
    }
}

// ---------------- pack W5 into MFMA fragment order, bf16 hi/lo ----------------
// wp[((kb*64 + ntg)*2 + term)*512 + lane*8 + j]; c = kb*32+(lane>>4)*8+j; o = ntg*16+(lane&15)
__global__ __launch_bounds__(256) void pack_w5_kernel(const float* __restrict__ W5, unsigned short* __restrict__ wp)
{
    int i = blockIdx.x * 256 + threadIdx.x;
    if (i >= (1 << 19)) return;
    int j = i & 7, lane = (i >> 3) & 63, nt = (i >> 9) & 63, kb = i >> 15;
    int c = kb * 32 + (lane >> 4) * 8 + j;
    int o = nt * 16 + (lane & 15);
    float f = W5[(size_t)o * 512 + c];
    unsigned short hi = f2bf(f);
    unsigned short lo = f2bf(f - bf2f(hi));
    size_t base = (size_t)(kb * 64 + nt) * 2 * 512 + (size_t)lane * 8 + j;
    wp[base] = hi;
    wp[base + 512] = lo;
}

// ---------------- conv5 single pass: GEMM + BN partials + y5 (bf16, frag-order) IN PLACE over xc ----------------
// Block: 512 thr (8 waves, 1M x 8N), BM=64 rows (2 clouds), BN=1024 cols. 3-term bf16 hi/lo.
// y5 layout (uint2 units): [b][w][nt][mt][lane] — coalesced 8B/lane stores; aliases xc (block b owns bytes
// [b*131072, (b+1)*131072) which is exactly clouds 2b,2b+1's xc region; all xc reads done before epilogue).
__global__ __launch_bounds__(512) void conv5_store_kernel(
    const float* xc, const unsigned short* __restrict__ wpack,
    unsigned short* y5,
    float* __restrict__ partS, float* __restrict__ partQ)
{
    const int b = blockIdx.x;        // cloud pair
    const int t = threadIdx.x;
    const int w = t >> 6, l = t & 63;
    const int lg = l >> 4, lm = l & 15;

    __shared__ unsigned short Ah[64][40];   // [row=(cloud,p)][k] stride 40 shorts (80B, 16B-aligned)
    __shared__ unsigned short Al[64][40];

    f32x4 acc[4][8];
    #pragma unroll
    for (int mt = 0; mt < 4; ++mt)
        #pragma unroll
        for (int nt = 0; nt < 8; ++nt) acc[mt][nt] = (f32x4)0.f;

    const float* xbase = xc + (size_t)(b * 2) * (512 * P);

    // staging roles: first 256 threads; each handles (cloud, c-pair, p-quad)
    const int sp4    = t & 7;
    const int schalf = (t >> 3) & 15;
    const int scloud = (t >> 7) & 1;
    const bool sact  = t < 256;

    for (int kb = 0; kb < 16; ++kb) {
        __syncthreads();   // prev iter LDS reads done
        if (sact) {
            const float* src = xbase + (size_t)scloud * (512 * P)
                             + (size_t)(kb * 32 + 2 * schalf) * P + sp4 * 4;
            const float4 v0 = *(const float4*)src;
            const float4 v1 = *(const float4*)(src + P);
            const int r0 = scloud * 32 + sp4 * 4;
            #pragma unroll
            for (int e = 0; e < 4; ++e) {
                float a0 = (&v0.x)[e], a1 = (&v1.x)[e];
                unsigned short h0 = f2bf(a0), h1 = f2bf(a1);
                unsigned short l0 = f2bf(a0 - bf2f(h0)), l1 = f2bf(a1 - bf2f(h1));
                *(unsigned*)&Ah[r0 + e][2 * schalf] = (unsigned)h0 | ((unsigned)h1 << 16);
                *(unsigned*)&Al[r0 + e][2 * schalf] = (unsigned)l0 | ((unsigned)l1 << 16);
            }
        }
        __syncthreads();

        bf16x8 a_h[4], a_l[4];
        #pragma unroll
        for (int mt = 0; mt < 4; ++mt) {
            int row = mt * 16 + lm;
            a_h[mt] = *(const bf16x8*)&Ah[row][lg * 8];
            a_l[mt] = *(const bf16x8*)&Al[row][lg * 8];
        }
        #pragma unroll
        for (int nt = 0; nt < 8; ++nt) {
            const int ntg = w * 8 + nt;
            const unsigned short* bp = wpack + (size_t)(kb * 64 + ntg) * 2 * 512 + (size_t)l * 8;
            bf16x8 Bh = *(const bf16x8*)bp;
            bf16x8 Bl = *(const bf16x8*)(bp + 512);
            #pragma unroll
            for (int mt = 0; mt < 4; ++mt) {
                acc[mt][nt] = __builtin_amdgcn_mfma_f32_16x16x32_bf16(a_h[mt], Bl, acc[mt][nt], 0, 0, 0);
                acc[mt][nt] = __builtin_amdgcn_mfma_f32_16x16x32_bf16(a_l[mt], Bh, acc[mt][nt], 0, 0, 0);
                acc[mt][nt] = __builtin_amdgcn_mfma_f32_16x16x32_bf16(a_h[mt], Bh, acc[mt][nt], 0, 0, 0);
            }
        }
    }
    __syncthreads();   // all xc reads (global+LDS path) complete before in-place overwrite

    #pragma unroll
    for (int nt = 0; nt < 8; ++nt) {
        float s = 0.f, q = 0.f;
        #pragma unroll
        for (int mt = 0; mt < 4; ++mt)
            #pragma unroll
            for (int r = 0; r < 4; ++r) { float v = acc[mt][nt][r]; s += v; q = fmaf(v, v, q); }
        s += __shfl_xor(s, 16); q += __shfl_xor(q, 16);
        s += __shfl_xor(s, 32); q += __shfl_xor(q, 32);
        if (l < 16) {
            int o = w * 128 + nt * 16 + lm;
            partS[(size_t)o * 2048 + b] = s;
            partQ[(size_t)o * 2048 + b] = q;
        }
        #pragma unroll
        for (int mt = 0; mt < 4; ++mt) {
            unsigned p0 = (unsigned)f2bf(acc[mt][nt][0]) | ((unsigned)f2bf(acc[mt][nt][1]) << 16);
            unsigned p1 = (unsigned)f2bf(acc[mt][nt][2]) | ((unsigned)f2bf(acc[mt][nt][3]) << 16);
            size_t off = ((((size_t)b * 8 + w) * 8 + nt) * 4 + mt) * 64 + l;
            ((uint2*)y5)[off] = make_uint2(p0, p1);
        }
    }
}

// ---------------- conv5 finish: read y5 frag-order, BN+lrelu+max/mean pool over p -> h ----------------
__global__ __launch_bounds__(512) void conv5_finish_kernel(
    const unsigned short* __restrict__ y5, const float* __restrict__ st, float* __restrict__ h)
{
    const int b = blockIdx.x, t = threadIdx.x;
    const int w = t >> 6, l = t & 63, lm = l & 15;
    #pragma unroll
    for (int nt = 0; nt < 8; ++nt) {
        const int o = w * 128 + nt * 16 + lm;
        const float sc = st[o], sh = st[1024 + o];
        #pragma unroll
        for (int cloud = 0; cloud < 2; ++cloud) {
            float mx = -INFINITY, sm = 0.f;
            #pragma unroll
            for (int half = 0; half < 2; ++half) {
                const int mt = cloud * 2 + half;
                uint2 pk = ((const uint2*)y5)[((((size_t)b * 8 + w) * 8 + nt) * 4 + mt) * 64 + l];
                #pragma unroll
                for (int r = 0; r < 4; ++r) {
                    unsigned word = (r < 2) ? pk.x : pk.y;
                    unsigned short bits = (unsigned short)((r & 1) ? (word >> 16) : (word & 0xffff));
                    float v = lrelu(fmaf(sc, bf2f(bits), sh));
                    mx = fmaxf(mx, v); sm += v;
                }
            }
            mx = fmaxf(mx, __shfl_xor(mx, 16)); sm += __shfl_xor(sm, 16);
            mx = fmaxf(mx, __shfl_xor(mx, 32)); sm += __shfl_xor(sm, 32);
            if (l < 16) {
                const int n = b * 2 + cloud;
                h[(size_t)n * 2048 + o] = mx;
                h[(size_t)n * 2048 + 1024 + o] = sm * (1.f / 32.f);
            }
        }
    }
}

// ---------------- generic f32 GEMM: C[m][o] = sum_k A[m][k]*B[o][k] (+bias) ----------------
__global__ __launch_bounds__(256) void gemm_nt(const float* __restrict__ A, const float* __restrict__ B,
                                               const float* __restrict__ bias, float* __restrict__ Cc,
                                               int M, int Nn, int Kk)
{
    __shared__ float As[16][64];
    __shared__ float Bs[16][64];
    const int t = threadIdx.x;
    const int m0 = blockIdx.y * 64;
    const int o0 = blockIdx.x * 64;
    const int lm = t % 64;
    const int lk4 = (t / 64) * 4;
    const int tx = t % 16, ty = t / 16;
    float acc[4][4] = {};
    for (int k0 = 0; k0 < Kk; k0 += 16) {
        float4 av4 = *(const float4*)(A + (size_t)(m0 + lm) * Kk + k0 + lk4);
        float4 bv4 = make_float4(0.f, 0.f, 0.f, 0.f);
        if (o0 + lm < Nn) bv4 = *(const float4*)(B + (size_t)(o0 + lm) * Kk + k0 + lk4);
        __syncthreads();
        As[lk4 + 0][lm] = av4.x; As[lk4 + 1][lm] = av4.y; As[lk4 + 2][lm] = av4.z; As[lk4 + 3][lm] = av4.w;
        Bs[lk4 + 0][lm] = bv4.x; Bs[lk4 + 1][lm] = bv4.y; Bs[lk4 + 2][lm] = bv4.z; Bs[lk4 + 3][lm] = bv4.w;
        __syncthreads();
        #pragma unroll
        for (int kk = 0; kk < 16; ++kk) {
            float a[4], b[4];
            *(float4*)a = *(const float4*)&As[kk][ty * 4];
            *(float4*)b = *(const float4*)&Bs[kk][tx * 4];
            #pragma unroll
            for (int i = 0; i < 4; ++i)
                #pragma unroll
                for (int j = 0; j < 4; ++j) acc[i][j] = fmaf(a[i], b[j], acc[i][j]);
        }
    }
    #pragma unroll
    for (int i = 0; i < 4; ++i) {
        int m = m0 + ty * 4 + i;
        #pragma unroll
        for (int j = 0; j < 4; ++j) {
            int o = o0 + tx * 4 + j;
            if (o < Nn) Cc[(size_t)m * Nn + o] = acc[i][j] + (bias ? bias[o] : 0.f);
        }
    }
    (void)M;
}

// ---------------- per-column stats over rows (FC batchnorm, axis 0) ----------------
template<int NCPT>
__global__ __launch_bounds__(256) void colstats_kernel(const float* __restrict__ A, int NC,
                                                       float* __restrict__ partS, float* __restrict__ partQ)
{
    const int b = blockIdx.x, t = threadIdx.x;
    float S[NCPT], Q[NCPT];
    #pragma unroll
    for (int j = 0; j < NCPT; ++j) { S[j] = 0.f; Q[j] = 0.f; }
    for (int r = 0; r < 32; ++r) {
        const float* row = A + (size_t)(b * 32 + r) * NC;
        #pragma unroll
        for (int j = 0; j < NCPT; ++j) { float v = row[t + j * 256]; S[j] += v; Q[j] += v * v; }
    }
    #pragma unroll
    for (int j = 0; j < NCPT; ++j) {
        int o = t + j * 256;
        partS[(size_t)o * 2048 + b] = S[j];
        partQ[(size_t)o * 2048 + b] = Q[j];
    }
}

__global__ __launch_bounds__(256) void bnact_kernel(const float* __restrict__ in, const float* __restrict__ st,
                                                    float* __restrict__ out, int NC, int total)
{
    int i = blockIdx.x * 256 + threadIdx.x;
    if (i < total) {
        int o = i % NC;
        out[i] = lrelu(fmaf(st[o], in[i], st[1024 + o]));
    }
}

__global__ __launch_bounds__(256) void logsoftmax_kernel(float* __restrict__ out)
{
    const int n = blockIdx.x, t = threadIdx.x;
    float* row = out + (size_t)n * 800;
    __shared__ float red[256];
    float v[4];
    float mx = -INFINITY;
    #pragma unroll
    for (int j = 0; j < 4; ++j) {
        int i = t + j * 256;
        v[j] = (i < 800) ? row[i] : -INFINITY;
        mx = fmaxf(mx, v[j]);
    }
    red[t] = mx; __syncthreads();
    for (int w = 128; w > 0; w >>= 1) { if (t < w) red[t] = fmaxf(red[t], red[t + w]); __syncthreads(); }
    const float m = red[0]; __syncthreads();
    float s = 0.f;
    #pragma unroll
    for (int j = 0; j < 4; ++j) { int i = t + j * 256; if (i < 800) s += expf(v[j] - m); }
    red[t] = s; __syncthreads();
    for (int w = 128; w > 0; w >>= 1) { if (t < w) red[t] += red[t + w]; __syncthreads(); }
    const float lg = m + logf(red[0]);
    #pragma unroll
    for (int j = 0; j < 4; ++j) { int i = t + j * 256; if (i < 800) row[i] = v[j] - lg; }
}

extern "C" void kernel_launch(void* const* d_in, const int* in_sizes, int n_in,
                              void* d_out, int out_size, void* d_ws, size_t ws_size,
                              hipStream_t stream)
{
    (void)in_sizes; (void)n_in; (void)out_size; (void)ws_size;
    const float* x   = (const float*)d_in[0];
    const float* W1  = (const float*)d_in[2];
    const float* g1  = (const float*)d_in[3];
    const float* b1  = (const float*)d_in[4];
    const float* W2  = (const float*)d_in[5];
    const float* g2  = (const float*)d_in[6];
    const float* b2  = (const float*)d_in[7];
    const float* W3  = (const float*)d_in[8];
    const float* g3  = (const float*)d_in[9];
    const float* b3  = (const float*)d_in[10];
    const float* W4  = (const float*)d_in[11];
    const float* g4  = (const float*)d_in[12];
    const float* b4  = (const float*)d_in[13];
    const float* W5  = (const float*)d_in[14];
    const float* g5  = (const float*)d_in[15];
    const float* b5  = (const float*)d_in[16];
    const float* Wl1 = (const float*)d_in[17];
    const float* g6  = (const float*)d_in[18];
    const float* b6  = (const float*)d_in[19];
    const float* Wl2 = (const float*)d_in[20];
    const float* bl2 = (const float*)d_in[21];
    const float* g7  = (const float*)d_in[22];
    const float* b7  = (const float*)d_in[23];
    const float* Wl3 = (const float*)d_in[24];
    const float* bl3 = (const float*)d_in[25];

    char* ws = (char*)d_ws;
    size_t off = 0;
    auto alloc = [&](size_t bytes) -> void* {
        void* p = ws + off; off += (bytes + 255) & ~(size_t)255; return p;
    };
    float*         xc    = (float*)alloc((size_t)NPTS * 512 * P * 4);       // 134.2 MB (y5 bf16 aliases in place)
    unsigned char* idx   = (unsigned char*)alloc((size_t)NPTS * P * KNN_K); // 0.98 MB
    float*         partS = (float*)alloc((size_t)1024 * 2048 * 4);          // 8.4 MB
    float*         partQ = (float*)alloc((size_t)1024 * 2048 * 4);          // 8.4 MB
    float*         st    = (float*)alloc(2048 * 4);
    float*         wt    = (float*)alloc((size_t)512 * 1024 * 4);           // 2 MB (also holds W5 pack)
    float*         h     = (float*)alloc((size_t)2048 * 2048 * 4);          // 16.8 MB
    float*         h1p   = (float*)alloc((size_t)2048 * 512 * 4);           // 4.2 MB
    unsigned short* y5 = (unsigned short*)xc;   // in-place: block b reads clouds 2b,2b+1 then overwrites them
    float* h1  = h;
    float* h2p = h + 1048576;
    float* h2  = h + 1572864;

    const float inv_edge = 1.f / (float)(NPTS * P * KNN_K);

    // ---- edge block 1: x(C=3) -> O=64 (xc ch 0..63) ----
    knn_kernel<3><<<NPTS, 64, 0, stream>>>(x, 3 * P, idx);
    build_wcat_kernel<<<(3 * 128 + 255) / 256, 256, 0, stream>>>(W1, wt, 3, 64, 1);
    edge_pass_kernel<3, 64, 1, false><<<NPTS, 256, 0, stream>>>(x, 3 * P, wt, idx, nullptr, nullptr, partS, partQ);
    reduce_stats_kernel<<<64, 256, 0, stream>>>(partS, partQ, g1, b1, st, 2048, inv_edge);
    edge_pass_kernel<3, 64, 1, true><<<NPTS, 256, 0, stream>>>(x, 3 * P, wt, idx, st, xc + 0 * P, nullptr, nullptr);

    // ---- edge block 2: xc ch 0..63 -> O=64 (ch 64..127) ----
    knn_kernel<64><<<NPTS, 64, 0, stream>>>(xc, 512 * P, idx);
    build_wcat_kernel<<<(64 * 128 + 255) / 256, 256, 0, stream>>>(W2, wt, 64, 64, 1);
    edge_pass_kernel<64, 64, 1, false><<<NPTS, 256, 0, stream>>>(xc, 512 * P, wt, idx, nullptr, nullptr, partS, partQ);
    reduce_stats_kernel<<<64, 256, 0, stream>>>(partS, partQ, g2, b2, st, 2048, inv_edge);
    edge_pass_kernel<64, 64, 1, true><<<NPTS, 256, 0, stream>>>(xc, 512 * P, wt, idx, st, xc + 64 * P, nullptr, nullptr);

    // ---- edge block 3: xc ch 64..127 -> O=128 (ch 128..255), 2 chunks ----
    knn_kernel<64><<<NPTS, 64, 0, stream>>>(xc + 64 * P, 512 * P, idx);
    build_wcat_kernel<<<(64 * 256 + 255) / 256, 256, 0, stream>>>(W3, wt, 64, 128, 2);
    edge_pass_kernel<64, 128, 2, false><<<NPTS, 256, 0, stream>>>(xc + 64 * P, 512 * P, wt, idx, nullptr, nullptr, partS, partQ);
    reduce_stats_kernel<<<128, 256, 0, stream>>>(partS, partQ, g3, b3, st, 2048, inv_edge);
    edge_pass_kernel<64, 128, 2, true><<<NPTS, 256, 0, stream>>>(xc + 64 * P, 512 * P, wt, idx, st, xc + 128 * P, nullptr, nullptr);

    // ---- edge block 4: xc ch 128..255 -> O=256 (ch 256..511), 2 chunks ----
    knn_kernel<128><<<NPTS, 64, 0, stream>>>(xc + 128 * P, 512 * P, idx);
    build_wcat_kernel<<<(128 * 512 + 255) / 256, 256, 0, stream>>>(W4, wt, 128, 256, 2);
    edge_pass_kernel<128, 256, 2, false><<<NPTS, 256, 0, stream>>>(xc + 128 * P, 512 * P, wt, idx, nullptr, nullptr, partS, partQ);
    reduce_stats_kernel<<<256, 256, 0, stream>>>(partS, partQ, g4, b4, st, 2048, inv_edge);
    edge_pass_kernel<128, 256, 2, true><<<NPTS, 256, 0, stream>>>(xc + 128 * P, 512 * P, wt, idx, st, xc + 256 * P, nullptr, nullptr);

    // ---- stage 5 via MFMA, single GEMM pass: stats partials + y5 in place; then BN+pool ----
    pack_w5_kernel<<<2048, 256, 0, stream>>>(W5, (unsigned short*)wt);
    conv5_store_kernel<<<1024, 512, 0, stream>>>(xc, (const unsigned short*)wt, y5, partS, partQ);
    reduce_stats_kernel<<<1024, 256, 0, stream>>>(partS, partQ, g5, b5, st, 1024, 1.f / 65536.f);
    conv5_finish_kernel<<<1024, 512, 0, stream>>>(y5, st, h);

    // ---- FC head ----
    gemm_nt<<<dim3(512 / 64, 2048 / 64), 256, 0, stream>>>(h, Wl1, nullptr, h1p, 2048, 512, 2048);
    colstats_kernel<2><<<64, 256, 0, stream>>>(h1p, 512, partS, partQ);
    reduce_stats_kernel<<<512, 256, 0, stream>>>(partS, partQ, g6, b6, st, 64, 1.f / 2048.f);
    bnact_kernel<<<(2048 * 512 + 255) / 256, 256, 0, stream>>>(h1p, st, h1, 512, 2048 * 512);

    gemm_nt<<<dim3(256 / 64, 2048 / 64), 256, 0, stream>>>(h1, Wl2, bl2, h2p, 2048, 256, 512);
    colstats_kernel<1><<<64, 256, 0, stream>>>(h2p, 256, partS, partQ);
    reduce_stats_kernel<<<256, 256, 0, stream>>>(partS, partQ, g7, b7, st, 64, 1.f / 2048.f);
    bnact_kernel<<<(2048 * 256 + 255) / 256, 256, 0, stream>>>(h2p, st, h2, 256, 2048 * 256);

    gemm_nt<<<dim3((800 + 63) / 64, 2048 / 64), 256, 0, stream>>>(h2, Wl3, bl3, (float*)d_out, 2048, 800, 256);
    logsoftmax_kernel<<<NPTS, 256, 0, stream>>>((float*)d_out);
}

// Round 7
// 946.671 us; speedup vs baseline: 2.2105x; 1.2563x over previous
//
#include <hip/hip_runtime.h>
#include <hip/hip_bf16.h>
#include <cstdint>
#include <cstddef>

#define NPTS 2048
#define P 32
#define KNN_K 15
#define LRELU_NEG 0.2f
#define BN_EPS 1e-5f

__device__ __forceinline__ float lrelu(float x) { return x > 0.f ? x : LRELU_NEG * x; }

__device__ __forceinline__ unsigned short f2bf(float x) {      // RNE f32 -> bf16 bits
    union { float f; unsigned u; } uu; uu.f = x;
    unsigned r = uu.u + 0x7fffu + ((uu.u >> 16) & 1u);
    return (unsigned short)(r >> 16);
}
__device__ __forceinline__ float bf2f(unsigned short b) {
    union { unsigned u; float f; } uu; uu.u = ((unsigned)b) << 16;
    return uu.f;
}

typedef short bf16x8 __attribute__((ext_vector_type(8)));
typedef float f32x4  __attribute__((ext_vector_type(4)));

// ---------------- KNN: per-cloud pairwise -dist^2, top-15 (incl. self) ----------------
template<int C>
__global__ __launch_bounds__(64) void knn_kernel(const float* __restrict__ xin, int cloudStride,
                                                 unsigned char* __restrict__ idx)
{
    const int n = blockIdx.x, t = threadIdx.x;
    __shared__ float xs[C][P];
    __shared__ float xx[P];
    __shared__ float pd[P][P + 1];
    const float* xp = xin + (size_t)n * cloudStride;
    for (int i = t; i < C * P; i += 64) xs[i / P][i % P] = xp[i];
    __syncthreads();
    if (t < P) { float s = 0.f; for (int c = 0; c < C; ++c) { float v = xs[c][t]; s = fmaf(v, v, s); } xx[t] = s; }
    __syncthreads();
    for (int i = t; i < P * P; i += 64) {
        int p = i >> 5, q = i & 31;
        float d = 0.f;
        for (int c = 0; c < C; ++c) d = fmaf(xs[c][p], xs[c][q], d);
        pd[p][q] = 2.f * d - xx[p] - xx[q];   // diag exactly 0
    }
    __syncthreads();
    if (t < P) {
        for (int j = 0; j < KNN_K; ++j) {
            float best = -INFINITY; int bq = 0;
            for (int q = 0; q < P; ++q) { float v = pd[t][q]; if (v > best) { best = v; bq = q; } }
            idx[(size_t)n * (P * KNN_K) + t * KNN_K + j] = (unsigned char)bq;
            pd[t][bq] = -INFINITY;
        }
    }
}

// ---------------- Wcat^T, chunked column order (f32 scratch; consumed by pack / block-1 kernel) ----------------
__global__ __launch_bounds__(256) void build_wcat_kernel(const float* __restrict__ W, float* __restrict__ wt,
                                                         int C, int O, int NCHUNK)
{
    int i = blockIdx.x * 256 + threadIdx.x;
    int tot = C * 2 * O;
    if (i >= tot) return;
    int c = i / (2 * O), col = i % (2 * O);
    int O2C = 2 * O / NCHUNK, OC = O / NCHUNK;
    int chunk = col / O2C, cl = col % O2C;
    float v;
    if (cl < OC) { int o = chunk * OC + cl; v = W[(size_t)o * 2 * C + c]; }
    else { int o = chunk * OC + cl - OC; v = W[(size_t)o * 2 * C + C + c] - W[(size_t)o * 2 * C + c]; }
    wt[i] = v;
}

// ---------------- pack wt [C][TOTC] f32 -> bf16 hi/lo MFMA frag order ----------------
// wpk[((kb*NTT + ntg)*2 + term)*512 + lane*8 + j]; k = kb*32+(lane>>4)*8+j; col = ntg*16+(lane&15)
__global__ __launch_bounds__(256) void pack_wcat_kernel(const float* __restrict__ wt,
                                                        unsigned short* __restrict__ wpk,
                                                        int C, int TOTC)
{
    int NTT = TOTC / 16;
    int total = C * TOTC;
    int i = blockIdx.x * 256 + threadIdx.x;
    if (i >= total) return;
    int j = i & 7, lane = (i >> 3) & 63;
    int rest = i >> 9;                 // kb*NTT + ntg
    int ntg = rest % NTT, kb = rest / NTT;
    int k = kb * 32 + (lane >> 4) * 8 + j;
    int col = ntg * 16 + (lane & 15);
    float f = wt[(size_t)k * TOTC + col];
    unsigned short hi = f2bf(f);
    unsigned short lo = f2bf(f - bf2f(hi));
    size_t base = (size_t)rest * 1024 + (size_t)lane * 8 + j;
    wpk[base] = hi;
    wpk[base + 512] = lo;
}

// ---------------- edge conv (f32 VALU path, block 1 only: C=3) ----------------
template<int C, int O, int NCHUNK, bool OUT>
__global__ __launch_bounds__(256) void edge_pass_kernel(
    const float* __restrict__ xin, int cloudStride,
    const float* __restrict__ wt,
    const unsigned char* __restrict__ idx,
    const float* __restrict__ st,
    float* __restrict__ xcout,
    float* __restrict__ partS, float* __restrict__ partQ)
{
    constexpr int TOTC = 2 * O;
    constexpr int O2C = TOTC / NCHUNK;
    constexpr int OC  = O / NCHUNK;
    constexpr int TPC = (O2C >= 256) ? 1 : (256 / O2C);
    constexpr int CPT = (O2C > 256) ? (O2C / 256) : 1;
    constexpr int PP  = P / TPC;
    constexpr int TPO = 256 / OC;
    constexpr int PPo = P / TPO;
    const int n = blockIdx.x, t = threadIdx.x;

    __shared__ float xs[C][P];
    __shared__ float gh[P * O2C];
    __shared__ unsigned char idl[P * KNN_K];
    __shared__ float red[2][256];

    const float* xp = xin + (size_t)n * cloudStride;
    for (int i = t; i < C * P; i += 256) xs[i / P][i % P] = xp[i];
    for (int i = t; i < P * KNN_K; i += 256) idl[i] = idx[(size_t)n * (P * KNN_K) + i];

    const int col = (O2C >= 256) ? t : (t % O2C);
    const int p0  = ((O2C >= 256) ? 0 : (t / O2C)) * PP;
    const int o   = t % OC;
    const int p0c = (t / OC) * PPo;

    for (int chunk = 0; chunk < NCHUNK; ++chunk) {
        __syncthreads();
        {
            float acc[CPT][PP];
            #pragma unroll
            for (int j = 0; j < CPT; ++j)
                #pragma unroll
                for (int p = 0; p < PP; ++p) acc[j][p] = 0.f;
            for (int c = 0; c < C; ++c) {
                float w[CPT];
                #pragma unroll
                for (int j = 0; j < CPT; ++j) w[j] = wt[(size_t)c * TOTC + chunk * O2C + col + j * 256];
                #pragma unroll
                for (int p = 0; p < PP; ++p) {
                    float xv = xs[c][p0 + p];
                    #pragma unroll
                    for (int j = 0; j < CPT; ++j) acc[j][p] = fmaf(w[j], xv, acc[j][p]);
                }
            }
            #pragma unroll
            for (int j = 0; j < CPT; ++j)
                #pragma unroll
                for (int p = 0; p < PP; ++p) gh[(p0 + p) * O2C + col + j * 256] = acc[j][p];
        }
        __syncthreads();

        if constexpr (!OUT) {
            float ssum = 0.f, ssq = 0.f;
            #pragma unroll
            for (int p = 0; p < PPo; ++p) {
                const int pp = p0c + p;
                const float g = gh[pp * O2C + OC + o];
                #pragma unroll
                for (int k = 0; k < KNN_K; ++k) {
                    const int q = idl[pp * KNN_K + k];
                    float yv = gh[q * O2C + o] + g;
                    ssum += yv; ssq += yv * yv;
                }
            }
            red[0][t] = ssum; red[1][t] = ssq;
            __syncthreads();
            if (t < OC) {
                float S = 0.f, Q = 0.f;
                #pragma unroll
                for (int j = 0; j < TPO; ++j) { S += red[0][t + j * OC]; Q += red[1][t + j * OC]; }
                partS[(size_t)(chunk * OC + t) * 2048 + n] = S;
                partQ[(size_t)(chunk * OC + t) * 2048 + n] = Q;
            }
        } else {
            const float s = st[chunk * OC + o], sh = st[1024 + chunk * OC + o];
            float rbuf[PPo];
            #pragma unroll
            for (int p = 0; p < PPo; ++p) {
                const int pp = p0c + p;
                const float g = gh[pp * O2C + OC + o];
                float mx = -INFINITY, mn = INFINITY;
                #pragma unroll
                for (int k = 0; k < KNN_K; ++k) {
                    const int q = idl[pp * KNN_K + k];
                    float yv = gh[q * O2C + o] + g;
                    mx = fmaxf(mx, yv); mn = fminf(mn, yv);
                }
                rbuf[p] = lrelu(fmaf(s, (s >= 0.f ? mx : mn), sh));
            }
            __syncthreads();
            #pragma unroll
            for (int p = 0; p < PPo; ++p) gh[o * (P + 1) + p0c + p] = rbuf[p];
            __syncthreads();
            for (int i = t; i < OC * P; i += 256)
                xcout[(size_t)n * (512 * P) + chunk * OC * P + i] = gh[(i / P) * (P + 1) + (i % P)];
        }
    }
}

// ---------------- edge conv via MFMA (blocks 2-4: C in {64,128}) ----------------
// Per cloud: x -> LDS bf16 hi/lo; per 256-col chunk: 3-term MFMA -> gh; gather/combine as before.
template<int C, int O, bool OUT>
__global__ __launch_bounds__(256) void edge_mfma_kernel(
    const float* __restrict__ xin, int cloudStride,
    const unsigned short* __restrict__ wpk,        // frag-order packed wcat, chunk-ordered cols
    const unsigned char* __restrict__ idx,
    const float* __restrict__ st,
    float* __restrict__ xcout,
    float* __restrict__ partS, float* __restrict__ partQ)
{
    constexpr int TOTC  = 2 * O;
    constexpr int O2C   = (TOTC > 256) ? 256 : TOTC;
    constexpr int NCHUNK= TOTC / O2C;
    constexpr int OC    = O2C / 2;
    constexpr int NTW   = O2C / 64;      // 16-col groups per wave
    constexpr int KB    = C / 32;
    constexpr int NTT   = TOTC / 16;
    constexpr int AS    = C + 8;         // A stride (shorts): byte stride mult of 16
    constexpr int GHS   = O2C + 4;       // gh stride (floats)
    constexpr int TPO   = 256 / OC;
    constexpr int PPo   = P / TPO;

    const int n = blockIdx.x, t = threadIdx.x;
    const int w = t >> 6, l = t & 63;
    const int lg = l >> 4, lm = l & 15;

    __shared__ unsigned short Ah[P * AS];
    __shared__ unsigned short Al[P * AS];
    __shared__ float gh[P * GHS];
    __shared__ unsigned char idl[P * KNN_K];

    // stage x (f32 [C][P]) -> Ah/Al [p][c] bf16 hi/lo
    const float* xp = xin + (size_t)n * cloudStride;
    for (int i = t; i < C * P; i += 256) {
        int c = i / P, p = i % P;
        float v = xp[i];
        unsigned short hi = f2bf(v);
        Ah[p * AS + c] = hi;
        Al[p * AS + c] = f2bf(v - bf2f(hi));
    }
    for (int i = t; i < P * KNN_K; i += 256) idl[i] = idx[(size_t)n * (P * KNN_K) + i];
    __syncthreads();

    const int o = t % OC;
    const int p0c = (t / OC) * PPo;

    for (int chunk = 0; chunk < NCHUNK; ++chunk) {
        f32x4 acc[2][NTW];
        #pragma unroll
        for (int mt = 0; mt < 2; ++mt)
            #pragma unroll
            for (int nt = 0; nt < NTW; ++nt) acc[mt][nt] = (f32x4)0.f;

        #pragma unroll
        for (int kb = 0; kb < KB; ++kb) {
            bf16x8 a_h[2], a_l[2];
            #pragma unroll
            for (int mt = 0; mt < 2; ++mt) {
                int row = mt * 16 + lm;
                a_h[mt] = *(const bf16x8*)&Ah[row * AS + kb * 32 + lg * 8];
                a_l[mt] = *(const bf16x8*)&Al[row * AS + kb * 32 + lg * 8];
            }
            #pragma unroll
            for (int nt = 0; nt < NTW; ++nt) {
                int ntg = chunk * (O2C / 16) + w * NTW + nt;
                const unsigned short* bp = wpk + (size_t)(kb * NTT + ntg) * 1024 + (size_t)l * 8;
                bf16x8 Bh = *(const bf16x8*)bp;
                bf16x8 Bl = *(const bf16x8*)(bp + 512);
                #pragma unroll
                for (int mt = 0; mt < 2; ++mt) {
                    acc[mt][nt] = __builtin_amdgcn_mfma_f32_16x16x32_bf16(a_h[mt], Bl, acc[mt][nt], 0, 0, 0);
                    acc[mt][nt] = __builtin_amdgcn_mfma_f32_16x16x32_bf16(a_l[mt], Bh, acc[mt][nt], 0, 0, 0);
                    acc[mt][nt] = __builtin_amdgcn_mfma_f32_16x16x32_bf16(a_h[mt], Bh, acc[mt][nt], 0, 0, 0);
                }
            }
        }
        __syncthreads();   // prev chunk's gh consumers done (chunk 0: after stage barrier, harmless)
        // scatter C frags: row = mt*16 + lg*4 + r, col = (w*NTW+nt)*16 + lm  [m89 mapping]
        #pragma unroll
        for (int mt = 0; mt < 2; ++mt)
            #pragma unroll
            for (int nt = 0; nt < NTW; ++nt) {
                int colb = (w * NTW + nt) * 16 + lm;
                #pragma unroll
                for (int r = 0; r < 4; ++r)
                    gh[(mt * 16 + lg * 4 + r) * GHS + colb] = acc[mt][nt][r];
            }
        __syncthreads();

        if constexpr (!OUT) {
            float ssum = 0.f, ssq = 0.f;
            #pragma unroll
            for (int p = 0; p < PPo; ++p) {
                const int pp = p0c + p;
                const float g = gh[pp * GHS + OC + o];
                #pragma unroll
                for (int k = 0; k < KNN_K; ++k) {
                    const int q = idl[pp * KNN_K + k];
                    float yv = gh[q * GHS + o] + g;
                    ssum += yv; ssq += yv * yv;
                }
            }
            __syncthreads();           // all gh gather reads done; alias reduction scratch onto gh
            gh[t] = ssum; gh[256 + t] = ssq;
            __syncthreads();
            if (t < OC) {
                float S = 0.f, Q = 0.f;
                #pragma unroll
                for (int j = 0; j < TPO; ++j) { S += gh[t + j * OC]; Q += gh[256 + t + j * OC]; }
                partS[(size_t)(chunk * OC + t) * 2048 + n] = S;
                partQ[(size_t)(chunk * OC + t) * 2048 + n] = Q;
            }
        } else {
            const float s = st[chunk * OC + o], sh = st[1024 + chunk * OC + o];
            float rbuf[PPo];
            #pragma unroll
            for (int p = 0; p < PPo; ++p) {
                const int pp = p0c + p;
                const float g = gh[pp * GHS + OC + o];
                float mx = -INFINITY, mn = INFINITY;
                #pragma unroll
                for (int k = 0; k < KNN_K; ++k) {
                    const int q = idl[pp * KNN_K + k];
                    float yv = gh[q * GHS + o] + g;
                    mx = fmaxf(mx, yv); mn = fminf(mn, yv);
                }
                rbuf[p] = lrelu(fmaf(s, (s >= 0.f ? mx : mn), sh));   // lrelu/affine monotone in y
            }
            __syncthreads();           // all gh reads done
            #pragma unroll
            for (int p = 0; p < PPo; ++p) gh[o * (P + 1) + p0c + p] = rbuf[p];
            __syncthreads();
            for (int i = t; i < OC * P; i += 256)
                xcout[(size_t)n * (512 * P) + chunk * OC * P + i] = gh[(i / P) * (P + 1) + (i % P)];
        }
    }
}

// ---------------- reduce partials -> scale/shift per channel ----------------
__global__ __launch_bounds__(256) void reduce_stats_kernel(const float* __restrict__ partS,
                                                           const float* __restrict__ partQ,
                                                           const float* __restrict__ gamma,
                                                           const float* __restrict__ beta,
                                                           float* __restrict__ st, int nparts, float inv_count)
{
    const int o = blockIdx.x, t = threadIdx.x;
    __shared__ float rs[256], rq[256];
    float S = 0.f, Q = 0.f;
    for (int i = t; i < nparts; i += 256) { S += partS[(size_t)o * 2048 + i]; Q += partQ[(size_t)o * 2048 + i]; }
    rs[t] = S; rq[t] = Q; __syncthreads();
    for (int w = 128; w > 0; w >>= 1) { if (t < w) { rs[t] += rs[t + w]; rq[t] += rq[t + w]; } __syncthreads(); }
    if (t == 0) {
        float m = rs[0] * inv_count;
        float v = fmaxf(rq[0] * inv_count - m * m, 0.f);
        float s = gamma[o] * rsqrtf(v + BN_EPS);
        st[o] = s;
        st[1024 + o] = fmaf(-m, s, beta[o]);
    }
}

// ---------------- pack W5 into MFMA fragment order, bf16 hi/lo ----------------
__global__ __launch_bounds__(256) void pack_w5_kernel(const float* __restrict__ W5, unsigned short* __restrict__ wp)
{
    int i = blockIdx.x * 256 + threadIdx.x;
    if (i >= (1 << 19)) return;
    int j = i & 7, lane = (i >> 3) & 63, nt = (i >> 9) & 63, kb = i >> 15;
    int c = kb * 32 + (lane >> 4) * 8 + j;
    int o = nt * 16 + (lane & 15);
    float f = W5[(size_t)o * 512 + c];
    unsigned short hi = f2bf(f);
    unsigned short lo = f2bf(f - bf2f(hi));
    size_t base = (size_t)(kb * 64 + nt) * 2 * 512 + (size_t)lane * 8 + j;
    wp[base] = hi;
    wp[base + 512] = lo;
}

// ---------------- conv5 single pass, double-buffered staging ----------------
__global__ __launch_bounds__(512) void conv5_store_kernel(
    const float* xc, const unsigned short* __restrict__ wpack,
    unsigned short* y5,
    float* __restrict__ partS, float* __restrict__ partQ)
{
    const int b = blockIdx.x;
    const int t = threadIdx.x;
    const int w = t >> 6, l = t & 63;
    const int lg = l >> 4, lm = l & 15;

    __shared__ unsigned short Ah[2][64][40];
    __shared__ unsigned short Al[2][64][40];

    f32x4 acc[4][8];
    #pragma unroll
    for (int mt = 0; mt < 4; ++mt)
        #pragma unroll
        for (int nt = 0; nt < 8; ++nt) acc[mt][nt] = (f32x4)0.f;

    const float* xbase = xc + (size_t)(b * 2) * (512 * P);

    const int sp4    = t & 7;
    const int schalf = (t >> 3) & 15;
    const int scloud = (t >> 7) & 1;
    const bool sact  = t < 256;

    auto stage = [&](int kb, int buf) {
        if (sact) {
            const float* src = xbase + (size_t)scloud * (512 * P)
                             + (size_t)(kb * 32 + 2 * schalf) * P + sp4 * 4;
            const float4 v0 = *(const float4*)src;
            const float4 v1 = *(const float4*)(src + P);
            const int r0 = scloud * 32 + sp4 * 4;
            #pragma unroll
            for (int e = 0; e < 4; ++e) {
                float a0 = (&v0.x)[e], a1 = (&v1.x)[e];
                unsigned short h0 = f2bf(a0), h1 = f2bf(a1);
                unsigned short l0 = f2bf(a0 - bf2f(h0)), l1 = f2bf(a1 - bf2f(h1));
                *(unsigned*)&Ah[buf][r0 + e][2 * schalf] = (unsigned)h0 | ((unsigned)h1 << 16);
                *(unsigned*)&Al[buf][r0 + e][2 * schalf] = (unsigned)l0 | ((unsigned)l1 << 16);
            }
        }
    };

    stage(0, 0);
    int cur = 0;
    for (int kb = 0; kb < 16; ++kb) {
        __syncthreads();                 // buf[cur] staged (and prev-iter reads of buf[cur^1] done)
        if (kb + 1 < 16) stage(kb + 1, cur ^ 1);   // prefetch overlaps MFMA below

        bf16x8 a_h[4], a_l[4];
        #pragma unroll
        for (int mt = 0; mt < 4; ++mt) {
            int row = mt * 16 + lm;
            a_h[mt] = *(const bf16x8*)&Ah[cur][row][lg * 8];
            a_l[mt] = *(const bf16x8*)&Al[cur][row][lg * 8];
        }
        #pragma unroll
        for (int nt = 0; nt < 8; ++nt) {
            const int ntg = w * 8 + nt;
            const unsigned short* bp = wpack + (size_t)(kb * 64 + ntg) * 2 * 512 + (size_t)l * 8;
            bf16x8 Bh = *(const bf16x8*)bp;
            bf16x8 Bl = *(const bf16x8*)(bp + 512);
            #pragma unroll
            for (int mt = 0; mt < 4; ++mt) {
                acc[mt][nt] = __builtin_amdgcn_mfma_f32_16x16x32_bf16(a_h[mt], Bl, acc[mt][nt], 0, 0, 0);
                acc[mt][nt] = __builtin_amdgcn_mfma_f32_16x16x32_bf16(a_l[mt], Bh, acc[mt][nt], 0, 0, 0);
                acc[mt][nt] = __builtin_amdgcn_mfma_f32_16x16x32_bf16(a_h[mt], Bh, acc[mt][nt], 0, 0, 0);
            }
        }
        cur ^= 1;
    }
    __syncthreads();   // all xc reads complete before in-place overwrite

    #pragma unroll
    for (int nt = 0; nt < 8; ++nt) {
        float s = 0.f, q = 0.f;
        #pragma unroll
        for (int mt = 0; mt < 4; ++mt)
            #pragma unroll
            for (int r = 0; r < 4; ++r) { float v = acc[mt][nt][r]; s += v; q = fmaf(v, v, q); }
        s += __shfl_xor(s, 16); q += __shfl_xor(q, 16);
        s += __shfl_xor(s, 32); q += __shfl_xor(q, 32);
        if (l < 16) {
            int o = w * 128 + nt * 16 + lm;
            partS[(size_t)o * 2048 + b] = s;
            partQ[(size_t)o * 2048 + b] = q;
        }
        #pragma unroll
        for (int mt = 0; mt < 4; ++mt) {
            unsigned p0 = (unsigned)f2bf(acc[mt][nt][0]) | ((unsigned)f2bf(acc[mt][nt][1]) << 16);
            unsigned p1 = (unsigned)f2bf(acc[mt][nt][2]) | ((unsigned)f2bf(acc[mt][nt][3]) << 16);
            size_t off = ((((size_t)b * 8 + w) * 8 + nt) * 4 + mt) * 64 + l;
            ((uint2*)y5)[off] = make_uint2(p0, p1);
        }
    }
}

// ---------------- conv5 finish: read y5 frag-order, BN+lrelu+max/mean pool over p -> h ----------------
__global__ __launch_bounds__(512) void conv5_finish_kernel(
    const unsigned short* __restrict__ y5, const float* __restrict__ st, float* __restrict__ h)
{
    const int b = blockIdx.x, t = threadIdx.x;
    const int w = t >> 6, l = t & 63, lm = l & 15;
    #pragma unroll
    for (int nt = 0; nt < 8; ++nt) {
        const int o = w * 128 + nt * 16 + lm;
        const float sc = st[o], sh = st[1024 + o];
        #pragma unroll
        for (int cloud = 0; cloud < 2; ++cloud) {
            float mx = -INFINITY, sm = 0.f;
            #pragma unroll
            for (int half = 0; half < 2; ++half) {
                const int mt = cloud * 2 + half;
                uint2 pk = ((const uint2*)y5)[((((size_t)b * 8 + w) * 8 + nt) * 4 + mt) * 64 + l];
                #pragma unroll
                for (int r = 0; r < 4; ++r) {
                    unsigned word = (r < 2) ? pk.x : pk.y;
                    unsigned short bits = (unsigned short)((r & 1) ? (word >> 16) : (word & 0xffff));
                    float v = lrelu(fmaf(sc, bf2f(bits), sh));
                    mx = fmaxf(mx, v); sm += v;
                }
            }
            mx = fmaxf(mx, __shfl_xor(mx, 16)); sm += __shfl_xor(sm, 16);
            mx = fmaxf(mx, __shfl_xor(mx, 32)); sm += __shfl_xor(sm, 32);
            if (l < 16) {
                const int n = b * 2 + cloud;
                h[(size_t)n * 2048 + o] = mx;
                h[(size_t)n * 2048 + 1024 + o] = sm * (1.f / 32.f);
            }
        }
    }
}

// ---------------- generic f32 GEMM: C[m][o] = sum_k A[m][k]*B[o][k] (+bias) ----------------
__global__ __launch_bounds__(256) void gemm_nt(const float* __restrict__ A, const float* __restrict__ B,
                                               const float* __restrict__ bias, float* __restrict__ Cc,
                                               int M, int Nn, int Kk)
{
    __shared__ float As[16][64];
    __shared__ float Bs[16][64];
    const int t = threadIdx.x;
    const int m0 = blockIdx.y * 64;
    const int o0 = blockIdx.x * 64;
    const int lm = t % 64;
    const int lk4 = (t / 64) * 4;
    const int tx = t % 16, ty = t / 16;
    float acc[4][4] = {};
    for (int k0 = 0; k0 < Kk; k0 += 16) {
        float4 av4 = *(const float4*)(A + (size_t)(m0 + lm) * Kk + k0 + lk4);
        float4 bv4 = make_float4(0.f, 0.f, 0.f, 0.f);
        if (o0 + lm < Nn) bv4 = *(const float4*)(B + (size_t)(o0 + lm) * Kk + k0 + lk4);
        __syncthreads();
        As[lk4 + 0][lm] = av4.x; As[lk4 + 1][lm] = av4.y; As[lk4 + 2][lm] = av4.z; As[lk4 + 3][lm] = av4.w;
        Bs[lk4 + 0][lm] = bv4.x; Bs[lk4 + 1][lm] = bv4.y; Bs[lk4 + 2][lm] = bv4.z; Bs[lk4 + 3][lm] = bv4.w;
        __syncthreads();
        #pragma unroll
        for (int kk = 0; kk < 16; ++kk) {
            float a[4], b[4];
            *(float4*)a = *(const float4*)&As[kk][ty * 4];
            *(float4*)b = *(const float4*)&Bs[kk][tx * 4];
            #pragma unroll
            for (int i = 0; i < 4; ++i)
                #pragma unroll
                for (int j = 0; j < 4; ++j) acc[i][j] = fmaf(a[i], b[j], acc[i][j]);
        }
    }
    #pragma unroll
    for (int i = 0; i < 4; ++i) {
        int m = m0 + ty * 4 + i;
        #pragma unroll
        for (int j = 0; j < 4; ++j) {
            int o = o0 + tx * 4 + j;
            if (o < Nn) Cc[(size_t)m * Nn + o] = acc[i][j] + (bias ? bias[o] : 0.f);
        }
    }
    (void)M;
}

// ---------------- per-column stats over rows (FC batchnorm, axis 0) ----------------
template<int NCPT>
__global__ __launch_bounds__(256) void colstats_kernel(const float* __restrict__ A, int NC,
                                                       float* __restrict__ partS, float* __restrict__ partQ)
{
    const int b = blockIdx.x, t = threadIdx.x;
    float S[NCPT], Q[NCPT];
    #pragma unroll
    for (int j = 0; j < NCPT; ++j) { S[j] = 0.f; Q[j] = 0.f; }
    for (int r = 0; r < 32; ++r) {
        const float* row = A + (size_t)(b * 32 + r) * NC;
        #pragma unroll
        for (int j = 0; j < NCPT; ++j) { float v = row[t + j * 256]; S[j] += v; Q[j] += v * v; }
    }
    #pragma unroll
    for (int j = 0; j < NCPT; ++j) {
        int o = t + j * 256;
        partS[(size_t)o * 2048 + b] = S[j];
        partQ[(size_t)o * 2048 + b] = Q[j];
    }
}

__global__ __launch_bounds__(256) void bnact_kernel(const float* __restrict__ in, const float* __restrict__ st,
                                                    float* __restrict__ out, int NC, int total)
{
    int i = blockIdx.x * 256 + threadIdx.x;
    if (i < total) {
        int o = i % NC;
        out[i] = lrelu(fmaf(st[o], in[i], st[1024 + o]));
    }
}

__global__ __launch_bounds__(256) void logsoftmax_kernel(float* __restrict__ out)
{
    const int n = blockIdx.x, t = threadIdx.x;
    float* row = out + (size_t)n * 800;
    __shared__ float red[256];
    float v[4];
    float mx = -INFINITY;
    #pragma unroll
    for (int j = 0; j < 4; ++j) {
        int i = t + j * 256;
        v[j] = (i < 800) ? row[i] : -INFINITY;
        mx = fmaxf(mx, v[j]);
    }
    red[t] = mx; __syncthreads();
    for (int w = 128; w > 0; w >>= 1) { if (t < w) red[t] = fmaxf(red[t], red[t + w]); __syncthreads(); }
    const float m = red[0]; __syncthreads();
    float s = 0.f;
    #pragma unroll
    for (int j = 0; j < 4; ++j) { int i = t + j * 256; if (i < 800) s += expf(v[j] - m); }
    red[t] = s; __syncthreads();
    for (int w = 128; w > 0; w >>= 1) { if (t < w) red[t] += red[t + w]; __syncthreads(); }
    const float lg = m + logf(red[0]);
    #pragma unroll
    for (int j = 0; j < 4; ++j) { int i = t + j * 256; if (i < 800) row[i] = v[j] - lg; }
}

extern "C" void kernel_launch(void* const* d_in, const int* in_sizes, int n_in,
                              void* d_out, int out_size, void* d_ws, size_t ws_size,
                              hipStream_t stream)
{
    (void)in_sizes; (void)n_in; (void)out_size; (void)ws_size;
    const float* x   = (const float*)d_in[0];
    const float* W1  = (const float*)d_in[2];
    const float* g1  = (const float*)d_in[3];
    const float* b1  = (const float*)d_in[4];
    const float* W2  = (const float*)d_in[5];
    const float* g2  = (const float*)d_in[6];
    const float* b2  = (const float*)d_in[7];
    const float* W3  = (const float*)d_in[8];
    const float* g3  = (const float*)d_in[9];
    const float* b3  = (const float*)d_in[10];
    const float* W4  = (const float*)d_in[11];
    const float* g4  = (const float*)d_in[12];
    const float* b4  = (const float*)d_in[13];
    const float* W5  = (const float*)d_in[14];
    const float* g5  = (const float*)d_in[15];
    const float* b5  = (const float*)d_in[16];
    const float* Wl1 = (const float*)d_in[17];
    const float* g6  = (const float*)d_in[18];
    const float* b6  = (const float*)d_in[19];
    const float* Wl2 = (const float*)d_in[20];
    const float* bl2 = (const float*)d_in[21];
    const float* g7  = (const float*)d_in[22];
    const float* b7  = (const float*)d_in[23];
    const float* Wl3 = (const float*)d_in[24];
    const float* bl3 = (const float*)d_in[25];

    char* ws = (char*)d_ws;
    size_t off = 0;
    auto alloc = [&](size_t bytes) -> void* {
        void* p = ws + off; off += (bytes + 255) & ~(size_t)255; return p;
    };
    float*          xc    = (float*)alloc((size_t)NPTS * 512 * P * 4);       // 134.2 MB
    unsigned char*  idx   = (unsigned char*)alloc((size_t)NPTS * P * KNN_K); // 0.98 MB
    float*          partS = (float*)alloc((size_t)1024 * 2048 * 4);          // 8.4 MB
    float*          partQ = (float*)alloc((size_t)1024 * 2048 * 4);          // 8.4 MB
    float*          st    = (float*)alloc(2048 * 4);
    float*          wt    = (float*)alloc((size_t)512 * 1024 * 4);           // 2 MB (f32 wcat / W5 pack)
    unsigned short* wpk   = (unsigned short*)alloc((size_t)128 * 512 * 2 * 2); // 256 KB edge bf16 pack
    float*          h     = (float*)alloc((size_t)2048 * 2048 * 4);          // 16.8 MB
    float*          h1p   = (float*)alloc((size_t)2048 * 512 * 4);           // 4.2 MB
    unsigned short* y5 = (unsigned short*)xc;   // in-place
    float* h1  = h;
    float* h2p = h + 1048576;
    float* h2  = h + 1572864;

    const float inv_edge = 1.f / (float)(NPTS * P * KNN_K);

    // ---- edge block 1: x(C=3) -> O=64 (xc ch 0..63), f32 path ----
    knn_kernel<3><<<NPTS, 64, 0, stream>>>(x, 3 * P, idx);
    build_wcat_kernel<<<(3 * 128 + 255) / 256, 256, 0, stream>>>(W1, wt, 3, 64, 1);
    edge_pass_kernel<3, 64, 1, false><<<NPTS, 256, 0, stream>>>(x, 3 * P, wt, idx, nullptr, nullptr, partS, partQ);
    reduce_stats_kernel<<<64, 256, 0, stream>>>(partS, partQ, g1, b1, st, 2048, inv_edge);
    edge_pass_kernel<3, 64, 1, true><<<NPTS, 256, 0, stream>>>(x, 3 * P, wt, idx, st, xc + 0 * P, nullptr, nullptr);

    // ---- edge block 2: xc ch 0..63 -> O=64 (ch 64..127), MFMA ----
    knn_kernel<64><<<NPTS, 64, 0, stream>>>(xc, 512 * P, idx);
    build_wcat_kernel<<<(64 * 128 + 255) / 256, 256, 0, stream>>>(W2, wt, 64, 64, 1);
    pack_wcat_kernel<<<(64 * 128 + 255) / 256, 256, 0, stream>>>(wt, wpk, 64, 128);
    edge_mfma_kernel<64, 64, false><<<NPTS, 256, 0, stream>>>(xc, 512 * P, wpk, idx, nullptr, nullptr, partS, partQ);
    reduce_stats_kernel<<<64, 256, 0, stream>>>(partS, partQ, g2, b2, st, 2048, inv_edge);
    edge_mfma_kernel<64, 64, true><<<NPTS, 256, 0, stream>>>(xc, 512 * P, wpk, idx, st, xc + 64 * P, nullptr, nullptr);

    // ---- edge block 3: xc ch 64..127 -> O=128 (ch 128..255), MFMA ----
    knn_kernel<64><<<NPTS, 64, 0, stream>>>(xc + 64 * P, 512 * P, idx);
    build_wcat_kernel<<<(64 * 256 + 255) / 256, 256, 0, stream>>>(W3, wt, 64, 128, 1);
    pack_wcat_kernel<<<(64 * 256 + 255) / 256, 256, 0, stream>>>(wt, wpk, 64, 256);
    edge_mfma_kernel<64, 128, false><<<NPTS, 256, 0, stream>>>(xc + 64 * P, 512 * P, wpk, idx, nullptr, nullptr, partS, partQ);
    reduce_stats_kernel<<<128, 256, 0, stream>>>(partS, partQ, g3, b3, st, 2048, inv_edge);
    edge_mfma_kernel<64, 128, true><<<NPTS, 256, 0, stream>>>(xc + 64 * P, 512 * P, wpk, idx, st, xc + 128 * P, nullptr, nullptr);

    // ---- edge block 4: xc ch 128..255 -> O=256 (ch 256..511), MFMA, 2 chunks ----
    knn_kernel<128><<<NPTS, 64, 0, stream>>>(xc + 128 * P, 512 * P, idx);
    build_wcat_kernel<<<(128 * 512 + 255) / 256, 256, 0, stream>>>(W4, wt, 128, 256, 2);
    pack_wcat_kernel<<<(128 * 512 + 255) / 256, 256, 0, stream>>>(wt, wpk, 128, 512);
    edge_mfma_kernel<128, 256, false><<<NPTS, 256, 0, stream>>>(xc + 128 * P, 512 * P, wpk, idx, nullptr, nullptr, partS, partQ);
    reduce_stats_kernel<<<256, 256, 0, stream>>>(partS, partQ, g4, b4, st, 2048, inv_edge);
    edge_mfma_kernel<128, 256, true><<<NPTS, 256, 0, stream>>>(xc + 128 * P, 512 * P, wpk, idx, st, xc + 256 * P, nullptr, nullptr);

    // ---- stage 5 via MFMA, single GEMM pass (dbuf staging): stats + y5 in place; then BN+pool ----
    pack_w5_kernel<<<2048, 256, 0, stream>>>(W5, (unsigned short*)wt);
    conv5_store_kernel<<<1024, 512, 0, stream>>>(xc, (const unsigned short*)wt, y5, partS, partQ);
    reduce_stats_kernel<<<1024, 256, 0, stream>>>(partS, partQ, g5, b5, st, 1024, 1.f / 65536.f);
    conv5_finish_kernel<<<1024, 512, 0, stream>>>(y5, st, h);

    // ---- FC head ----
    gemm_nt<<<dim3(512 / 64, 2048 / 64), 256, 0, stream>>>(h, Wl1, nullptr, h1p, 2048, 512, 2048);
    colstats_kernel<2><<<64, 256, 0, stream>>>(h1p, 512, partS, partQ);
    reduce_stats_kernel<<<512, 256, 0, stream>>>(partS, partQ, g6, b6, st, 64, 1.f / 2048.f);
    bnact_kernel<<<(2048 * 512 + 255) / 256, 256, 0, stream>>>(h1p, st, h1, 512, 2048 * 512);

    gemm_nt<<<dim3(256 / 64, 2048 / 64), 256, 0, stream>>>(h1, Wl2, bl2, h2p, 2048, 256, 512);
    colstats_kernel<1><<<64, 256, 0, stream>>>(h2p, 256, partS, partQ);
    reduce_stats_kernel<<<256, 256, 0, stream>>>(partS, partQ, g7, b7, st, 64, 1.f / 2048.f);
    bnact_kernel<<<(2048 * 256 + 255) / 256, 256, 0, stream>>>(h2p, st, h2, 256, 2048 * 256);

    gemm_nt<<<dim3((800 + 63) / 64, 2048 / 64), 256, 0, stream>>>(h2, Wl3, bl3, (float*)d_out, 2048, 800, 256);
    logsoftmax_kernel<<<NPTS, 256, 0, stream>>>((float*)d_out);
}

// Round 8
// 851.086 us; speedup vs baseline: 2.4588x; 1.1123x over previous
//
#include <hip/hip_runtime.h>
#include <hip/hip_bf16.h>
#include <cstdint>
#include <cstddef>

#define NPTS 2048
#define P 32
#define KNN_K 15
#define LRELU_NEG 0.2f
#define BN_EPS 1e-5f

__device__ __forceinline__ float lrelu(float x) { return x > 0.f ? x : LRELU_NEG * x; }

__device__ __forceinline__ unsigned short f2bf(float x) {      // RNE f32 -> bf16 bits
    union { float f; unsigned u; } uu; uu.f = x;
    unsigned r = uu.u + 0x7fffu + ((uu.u >> 16) & 1u);
    return (unsigned short)(r >> 16);
}
__device__ __forceinline__ float bf2f(unsigned short b) {
    union { unsigned u; float f; } uu; uu.u = ((unsigned)b) << 16;
    return uu.f;
}

typedef short bf16x8 __attribute__((ext_vector_type(8)));
typedef float f32x4  __attribute__((ext_vector_type(4)));

// ---------------- KNN: per-cloud pairwise -dist^2, top-15 (incl. self) ----------------
template<int C>
__global__ __launch_bounds__(64) void knn_kernel(const float* __restrict__ xin, int cloudStride,
                                                 unsigned char* __restrict__ idx)
{
    const int n = blockIdx.x, t = threadIdx.x;
    __shared__ float xs[C][P];
    __shared__ float xx[P];
    __shared__ float pd[P][P + 1];
    const float* xp = xin + (size_t)n * cloudStride;
    for (int i = t; i < C * P; i += 64) xs[i / P][i % P] = xp[i];
    __syncthreads();
    if (t < P) { float s = 0.f; for (int c = 0; c < C; ++c) { float v = xs[c][t]; s = fmaf(v, v, s); } xx[t] = s; }
    __syncthreads();
    for (int i = t; i < P * P; i += 64) {
        int p = i >> 5, q = i & 31;
        float d = 0.f;
        for (int c = 0; c < C; ++c) d = fmaf(xs[c][p], xs[c][q], d);
        pd[p][q] = 2.f * d - xx[p] - xx[q];   // diag exactly 0
    }
    __syncthreads();
    if (t < P) {
        for (int j = 0; j < KNN_K; ++j) {
            float best = -INFINITY; int bq = 0;
            for (int q = 0; q < P; ++q) { float v = pd[t][q]; if (v > best) { best = v; bq = q; } }
            idx[(size_t)n * (P * KNN_K) + t * KNN_K + j] = (unsigned char)bq;
            pd[t][bq] = -INFINITY;
        }
    }
}

// ---------------- Wcat^T f32 (block-1 path only) ----------------
__global__ __launch_bounds__(256) void build_wcat_kernel(const float* __restrict__ W, float* __restrict__ wt,
                                                         int C, int O, int NCHUNK)
{
    int i = blockIdx.x * 256 + threadIdx.x;
    int tot = C * 2 * O;
    if (i >= tot) return;
    int c = i / (2 * O), col = i % (2 * O);
    int O2C = 2 * O / NCHUNK, OC = O / NCHUNK;
    int chunk = col / O2C, cl = col % O2C;
    float v;
    if (cl < OC) { int o = chunk * OC + cl; v = W[(size_t)o * 2 * C + c]; }
    else { int o = chunk * OC + cl - OC; v = W[(size_t)o * 2 * C + C + c] - W[(size_t)o * 2 * C + c]; }
    wt[i] = v;
}

// ---------------- direct pack: W (edge, 2C cols) -> bf16 hi/lo MFMA frag order, chunk-ordered ----------------
// wpk[(kb*NTT+ntg)*1024 + term*512 + lane*8 + j]; k = kb*32+(lane>>4)*8+j; col = ntg*16+(lane&15)
__global__ __launch_bounds__(256) void pack_wcat_direct(const float* __restrict__ W,
                                                        unsigned short* __restrict__ wpk,
                                                        int C, int O, int NCHUNK)
{
    const int TOTC = 2 * O, NTT = TOTC / 16;
    const int O2C = TOTC / NCHUNK, OC = O / NCHUNK;
    int i = blockIdx.x * 256 + threadIdx.x;
    if (i >= C * TOTC) return;
    int j = i & 7, lane = (i >> 3) & 63, rest = i >> 9;
    int ntg = rest % NTT, kb = rest / NTT;
    int k = kb * 32 + (lane >> 4) * 8 + j;
    int col = ntg * 16 + (lane & 15);
    int chunk = col / O2C, cl = col % O2C;
    float v;
    if (cl < OC) { int o = chunk * OC + cl; v = W[(size_t)o * 2 * C + k]; }
    else         { int o = chunk * OC + cl - OC; v = W[(size_t)o * 2 * C + C + k] - W[(size_t)o * 2 * C + k]; }
    unsigned short hi = f2bf(v);
    wpk[(size_t)rest * 1024 + lane * 8 + j] = hi;
    wpk[(size_t)rest * 1024 + 512 + lane * 8 + j] = f2bf(v - bf2f(hi));
}

// ---------------- pack FC weight W[N][K] -> bf16 hi/lo frag order (N padded to NTT*16) ----------------
__global__ __launch_bounds__(256) void pack_wfc_kernel(const float* __restrict__ W,
                                                       unsigned short* __restrict__ wpk,
                                                       int Kk, int Nn, int NTT)
{
    int i = blockIdx.x * 256 + threadIdx.x;
    if (i >= NTT * 16 * Kk) return;
    int j = i & 7, lane = (i >> 3) & 63, rest = i >> 9;
    int ntg = rest % NTT, kb = rest / NTT;
    int k = kb * 32 + (lane >> 4) * 8 + j;
    int col = ntg * 16 + (lane & 15);
    float v = (col < Nn) ? W[(size_t)col * Kk + k] : 0.f;
    unsigned short hi = f2bf(v);
    wpk[(size_t)rest * 1024 + lane * 8 + j] = hi;
    wpk[(size_t)rest * 1024 + 512 + lane * 8 + j] = f2bf(v - bf2f(hi));
}

// ---------------- edge conv (f32 VALU path, block 1 only: C=3) ----------------
template<int C, int O, int NCHUNK, bool OUT>
__global__ __launch_bounds__(256) void edge_pass_kernel(
    const float* __restrict__ xin, int cloudStride,
    const float* __restrict__ wt,
    const unsigned char* __restrict__ idx,
    const float* __restrict__ st,
    float* __restrict__ xcout,
    float* __restrict__ partS, float* __restrict__ partQ)
{
    constexpr int TOTC = 2 * O;
    constexpr int O2C = TOTC / NCHUNK;
    constexpr int OC  = O / NCHUNK;
    constexpr int TPC = (O2C >= 256) ? 1 : (256 / O2C);
    constexpr int CPT = (O2C > 256) ? (O2C / 256) : 1;
    constexpr int PP  = P / TPC;
    constexpr int TPO = 256 / OC;
    constexpr int PPo = P / TPO;
    const int n = blockIdx.x, t = threadIdx.x;

    __shared__ float xs[C][P];
    __shared__ float gh[P * O2C];
    __shared__ unsigned char idl[P * KNN_K];
    __shared__ float red[2][256];

    const float* xp = xin + (size_t)n * cloudStride;
    for (int i = t; i < C * P; i += 256) xs[i / P][i % P] = xp[i];
    for (int i = t; i < P * KNN_K; i += 256) idl[i] = idx[(size_t)n * (P * KNN_K) + i];

    const int col = (O2C >= 256) ? t : (t % O2C);
    const int p0  = ((O2C >= 256) ? 0 : (t / O2C)) * PP;
    const int o   = t % OC;
    const int p0c = (t / OC) * PPo;

    for (int chunk = 0; chunk < NCHUNK; ++chunk) {
        __syncthreads();
        {
            float acc[CPT][PP];
            #pragma unroll
            for (int j = 0; j < CPT; ++j)
                #pragma unroll
                for (int p = 0; p < PP; ++p) acc[j][p] = 0.f;
            for (int c = 0; c < C; ++c) {
                float w[CPT];
                #pragma unroll
                for (int j = 0; j < CPT; ++j) w[j] = wt[(size_t)c * TOTC + chunk * O2C + col + j * 256];
                #pragma unroll
                for (int p = 0; p < PP; ++p) {
                    float xv = xs[c][p0 + p];
                    #pragma unroll
                    for (int j = 0; j < CPT; ++j) acc[j][p] = fmaf(w[j], xv, acc[j][p]);
                }
            }
            #pragma unroll
            for (int j = 0; j < CPT; ++j)
                #pragma unroll
                for (int p = 0; p < PP; ++p) gh[(p0 + p) * O2C + col + j * 256] = acc[j][p];
        }
        __syncthreads();

        if constexpr (!OUT) {
            float ssum = 0.f, ssq = 0.f;
            #pragma unroll
            for (int p = 0; p < PPo; ++p) {
                const int pp = p0c + p;
                const float g = gh[pp * O2C + OC + o];
                #pragma unroll
                for (int k = 0; k < KNN_K; ++k) {
                    const int q = idl[pp * KNN_K + k];
                    float yv = gh[q * O2C + o] + g;
                    ssum += yv; ssq += yv * yv;
                }
            }
            red[0][t] = ssum; red[1][t] = ssq;
            __syncthreads();
            if (t < OC) {
                float S = 0.f, Q = 0.f;
                #pragma unroll
                for (int j = 0; j < TPO; ++j) { S += red[0][t + j * OC]; Q += red[1][t + j * OC]; }
                partS[(size_t)(chunk * OC + t) * 2048 + n] = S;
                partQ[(size_t)(chunk * OC + t) * 2048 + n] = Q;
            }
        } else {
            const float s = st[chunk * OC + o], sh = st[1024 + chunk * OC + o];
            float rbuf[PPo];
            #pragma unroll
            for (int p = 0; p < PPo; ++p) {
                const int pp = p0c + p;
                const float g = gh[pp * O2C + OC + o];
                float mx = -INFINITY, mn = INFINITY;
                #pragma unroll
                for (int k = 0; k < KNN_K; ++k) {
                    const int q = idl[pp * KNN_K + k];
                    float yv = gh[q * O2C + o] + g;
                    mx = fmaxf(mx, yv); mn = fminf(mn, yv);
                }
                rbuf[p] = lrelu(fmaf(s, (s >= 0.f ? mx : mn), sh));
            }
            __syncthreads();
            #pragma unroll
            for (int p = 0; p < PPo; ++p) gh[o * (P + 1) + p0c + p] = rbuf[p];
            __syncthreads();
            for (int i = t; i < OC * P; i += 256)
                xcout[(size_t)n * (512 * P) + chunk * OC * P + i] = gh[(i / P) * (P + 1) + (i % P)];
        }
    }
}

// ---------------- edge conv via MFMA (blocks 2-4: C in {64,128}) ----------------
template<int C, int O, bool OUT>
__global__ __launch_bounds__(256) void edge_mfma_kernel(
    const float* __restrict__ xin, int cloudStride,
    const unsigned short* __restrict__ wpk,
    const unsigned char* __restrict__ idx,
    const float* __restrict__ st,
    float* __restrict__ xcout,
    float* __restrict__ partS, float* __restrict__ partQ)
{
    constexpr int TOTC  = 2 * O;
    constexpr int O2C   = (TOTC > 256) ? 256 : TOTC;
    constexpr int NCHUNK= TOTC / O2C;
    constexpr int OC    = O2C / 2;
    constexpr int NTW   = O2C / 64;
    constexpr int KB    = C / 32;
    constexpr int NTT   = TOTC / 16;
    constexpr int AS    = C + 8;
    constexpr int GHS   = O2C + 4;
    constexpr int TPO   = 256 / OC;
    constexpr int PPo   = P / TPO;

    const int n = blockIdx.x, t = threadIdx.x;
    const int w = t >> 6, l = t & 63;
    const int lg = l >> 4, lm = l & 15;

    __shared__ unsigned short Ah[P * AS];
    __shared__ unsigned short Al[P * AS];
    __shared__ float gh[P * GHS];
    __shared__ unsigned char idl[P * KNN_K];

    const float* xp = xin + (size_t)n * cloudStride;
    for (int i = t; i < C * P; i += 256) {
        int c = i / P, p = i % P;
        float v = xp[i];
        unsigned short hi = f2bf(v);
        Ah[p * AS + c] = hi;
        Al[p * AS + c] = f2bf(v - bf2f(hi));
    }
    for (int i = t; i < P * KNN_K; i += 256) idl[i] = idx[(size_t)n * (P * KNN_K) + i];
    __syncthreads();

    const int o = t % OC;
    const int p0c = (t / OC) * PPo;

    for (int chunk = 0; chunk < NCHUNK; ++chunk) {
        f32x4 acc[2][NTW];
        #pragma unroll
        for (int mt = 0; mt < 2; ++mt)
            #pragma unroll
            for (int nt = 0; nt < NTW; ++nt) acc[mt][nt] = (f32x4)0.f;

        #pragma unroll
        for (int kb = 0; kb < KB; ++kb) {
            bf16x8 a_h[2], a_l[2];
            #pragma unroll
            for (int mt = 0; mt < 2; ++mt) {
                int row = mt * 16 + lm;
                a_h[mt] = *(const bf16x8*)&Ah[row * AS + kb * 32 + lg * 8];
                a_l[mt] = *(const bf16x8*)&Al[row * AS + kb * 32 + lg * 8];
            }
            #pragma unroll
            for (int nt = 0; nt < NTW; ++nt) {
                int ntg = chunk * (O2C / 16) + w * NTW + nt;
                const unsigned short* bp = wpk + (size_t)(kb * NTT + ntg) * 1024 + (size_t)l * 8;
                bf16x8 Bh = *(const bf16x8*)bp;
                bf16x8 Bl = *(const bf16x8*)(bp + 512);
                #pragma unroll
                for (int mt = 0; mt < 2; ++mt) {
                    acc[mt][nt] = __builtin_amdgcn_mfma_f32_16x16x32_bf16(a_h[mt], Bl, acc[mt][nt], 0, 0, 0);
                    acc[mt][nt] = __builtin_amdgcn_mfma_f32_16x16x32_bf16(a_l[mt], Bh, acc[mt][nt], 0, 0, 0);
                    acc[mt][nt] = __builtin_amdgcn_mfma_f32_16x16x32_bf16(a_h[mt], Bh, acc[mt][nt], 0, 0, 0);
                }
            }
        }
        __syncthreads();
        #pragma unroll
        for (int mt = 0; mt < 2; ++mt)
            #pragma unroll
            for (int nt = 0; nt < NTW; ++nt) {
                int colb = (w * NTW + nt) * 16 + lm;
                #pragma unroll
                for (int r = 0; r < 4; ++r)
                    gh[(mt * 16 + lg * 4 + r) * GHS + colb] = acc[mt][nt][r];
            }
        __syncthreads();

        if constexpr (!OUT) {
            float ssum = 0.f, ssq = 0.f;
            #pragma unroll
            for (int p = 0; p < PPo; ++p) {
                const int pp = p0c + p;
                const float g = gh[pp * GHS + OC + o];
                #pragma unroll
                for (int k = 0; k < KNN_K; ++k) {
                    const int q = idl[pp * KNN_K + k];
                    float yv = gh[q * GHS + o] + g;
                    ssum += yv; ssq += yv * yv;
                }
            }
            __syncthreads();
            gh[t] = ssum; gh[256 + t] = ssq;
            __syncthreads();
            if (t < OC) {
                float S = 0.f, Q = 0.f;
                #pragma unroll
                for (int j = 0; j < TPO; ++j) { S += gh[t + j * OC]; Q += gh[256 + t + j * OC]; }
                partS[(size_t)(chunk * OC + t) * 2048 + n] = S;
                partQ[(size_t)(chunk * OC + t) * 2048 + n] = Q;
            }
        } else {
            const float s = st[chunk * OC + o], sh = st[1024 + chunk * OC + o];
            float rbuf[PPo];
            #pragma unroll
            for (int p = 0; p < PPo; ++p) {
                const int pp = p0c + p;
                const float g = gh[pp * GHS + OC + o];
                float mx = -INFINITY, mn = INFINITY;
                #pragma unroll
                for (int k = 0; k < KNN_K; ++k) {
                    const int q = idl[pp * KNN_K + k];
                    float yv = gh[q * GHS + o] + g;
                    mx = fmaxf(mx, yv); mn = fminf(mn, yv);
                }
                rbuf[p] = lrelu(fmaf(s, (s >= 0.f ? mx : mn), sh));
            }
            __syncthreads();
            #pragma unroll
            for (int p = 0; p < PPo; ++p) gh[o * (P + 1) + p0c + p] = rbuf[p];
            __syncthreads();
            for (int i = t; i < OC * P; i += 256)
                xcout[(size_t)n * (512 * P) + chunk * OC * P + i] = gh[(i / P) * (P + 1) + (i % P)];
        }
    }
}

// ---------------- reduce partials -> scale/shift per channel ----------------
__global__ __launch_bounds__(256) void reduce_stats_kernel(const float* __restrict__ partS,
                                                           const float* __restrict__ partQ,
                                                           const float* __restrict__ gamma,
                                                           const float* __restrict__ beta,
                                                           float* __restrict__ st, int nparts, float inv_count)
{
    const int o = blockIdx.x, t = threadIdx.x;
    __shared__ float rs[256], rq[256];
    float S = 0.f, Q = 0.f;
    for (int i = t; i < nparts; i += 256) { S += partS[(size_t)o * 2048 + i]; Q += partQ[(size_t)o * 2048 + i]; }
    rs[t] = S; rq[t] = Q; __syncthreads();
    for (int w = 128; w > 0; w >>= 1) { if (t < w) { rs[t] += rs[t + w]; rq[t] += rq[t + w]; } __syncthreads(); }
    if (t == 0) {
        float m = rs[0] * inv_count;
        float v = fmaxf(rq[0] * inv_count - m * m, 0.f);
        float s = gamma[o] * rsqrtf(v + BN_EPS);
        st[o] = s;
        st[1024 + o] = fmaf(-m, s, beta[o]);
    }
}

// ---------------- pack W5 into MFMA fragment order, bf16 hi/lo ----------------
__global__ __launch_bounds__(256) void pack_w5_kernel(const float* __restrict__ W5, unsigned short* __restrict__ wp)
{
    int i = blockIdx.x * 256 + threadIdx.x;
    if (i >= (1 << 19)) return;
    int j = i & 7, lane = (i >> 3) & 63, nt = (i >> 9) & 63, kb = i >> 15;
    int c = kb * 32 + (lane >> 4) * 8 + j;
    int o = nt * 16 + (lane & 15);
    float f = W5[(size_t)o * 512 + c];
    unsigned short hi = f2bf(f);
    unsigned short lo = f2bf(f - bf2f(hi));
    size_t base = (size_t)(kb * 64 + nt) * 2 * 512 + (size_t)lane * 8 + j;
    wp[base] = hi;
    wp[base + 512] = lo;
}

// ---------------- conv5 single pass, double-buffered staging ----------------
__global__ __launch_bounds__(512) void conv5_store_kernel(
    const float* xc, const unsigned short* __restrict__ wpack,
    unsigned short* y5,
    float* __restrict__ partS, float* __restrict__ partQ)
{
    const int b = blockIdx.x;
    const int t = threadIdx.x;
    const int w = t >> 6, l = t & 63;
    const int lg = l >> 4, lm = l & 15;

    __shared__ unsigned short Ah[2][64][40];
    __shared__ unsigned short Al[2][64][40];

    f32x4 acc[4][8];
    #pragma unroll
    for (int mt = 0; mt < 4; ++mt)
        #pragma unroll
        for (int nt = 0; nt < 8; ++nt) acc[mt][nt] = (f32x4)0.f;

    const float* xbase = xc + (size_t)(b * 2) * (512 * P);

    const int sp4    = t & 7;
    const int schalf = (t >> 3) & 15;
    const int scloud = (t >> 7) & 1;
    const bool sact  = t < 256;

    auto stage = [&](int kb, int buf) {
        if (sact) {
            const float* src = xbase + (size_t)scloud * (512 * P)
                             + (size_t)(kb * 32 + 2 * schalf) * P + sp4 * 4;
            const float4 v0 = *(const float4*)src;
            const float4 v1 = *(const float4*)(src + P);
            const int r0 = scloud * 32 + sp4 * 4;
            #pragma unroll
            for (int e = 0; e < 4; ++e) {
                float a0 = (&v0.x)[e], a1 = (&v1.x)[e];
                unsigned short h0 = f2bf(a0), h1 = f2bf(a1);
                unsigned short l0 = f2bf(a0 - bf2f(h0)), l1 = f2bf(a1 - bf2f(h1));
                *(unsigned*)&Ah[buf][r0 + e][2 * schalf] = (unsigned)h0 | ((unsigned)h1 << 16);
                *(unsigned*)&Al[buf][r0 + e][2 * schalf] = (unsigned)l0 | ((unsigned)l1 << 16);
            }
        }
    };

    stage(0, 0);
    int cur = 0;
    for (int kb = 0; kb < 16; ++kb) {
        __syncthreads();
        if (kb + 1 < 16) stage(kb + 1, cur ^ 1);

        bf16x8 a_h[4], a_l[4];
        #pragma unroll
        for (int mt = 0; mt < 4; ++mt) {
            int row = mt * 16 + lm;
            a_h[mt] = *(const bf16x8*)&Ah[cur][row][lg * 8];
            a_l[mt] = *(const bf16x8*)&Al[cur][row][lg * 8];
        }
        #pragma unroll
        for (int nt = 0; nt < 8; ++nt) {
            const int ntg = w * 8 + nt;
            const unsigned short* bp = wpack + (size_t)(kb * 64 + ntg) * 2 * 512 + (size_t)l * 8;
            bf16x8 Bh = *(const bf16x8*)bp;
            bf16x8 Bl = *(const bf16x8*)(bp + 512);
            #pragma unroll
            for (int mt = 0; mt < 4; ++mt) {
                acc[mt][nt] = __builtin_amdgcn_mfma_f32_16x16x32_bf16(a_h[mt], Bl, acc[mt][nt], 0, 0, 0);
                acc[mt][nt] = __builtin_amdgcn_mfma_f32_16x16x32_bf16(a_l[mt], Bh, acc[mt][nt], 0, 0, 0);
                acc[mt][nt] = __builtin_amdgcn_mfma_f32_16x16x32_bf16(a_h[mt], Bh, acc[mt][nt], 0, 0, 0);
            }
        }
        cur ^= 1;
    }
    __syncthreads();

    #pragma unroll
    for (int nt = 0; nt < 8; ++nt) {
        float s = 0.f, q = 0.f;
        #pragma unroll
        for (int mt = 0; mt < 4; ++mt)
            #pragma unroll
            for (int r = 0; r < 4; ++r) { float v = acc[mt][nt][r]; s += v; q = fmaf(v, v, q); }
        s += __shfl_xor(s, 16); q += __shfl_xor(q, 16);
        s += __shfl_xor(s, 32); q += __shfl_xor(q, 32);
        if (l < 16) {
            int o = w * 128 + nt * 16 + lm;
            partS[(size_t)o * 2048 + b] = s;
            partQ[(size_t)o * 2048 + b] = q;
        }
        #pragma unroll
        for (int mt = 0; mt < 4; ++mt) {
            unsigned p0 = (unsigned)f2bf(acc[mt][nt][0]) | ((unsigned)f2bf(acc[mt][nt][1]) << 16);
            unsigned p1 = (unsigned)f2bf(acc[mt][nt][2]) | ((unsigned)f2bf(acc[mt][nt][3]) << 16);
            size_t off = ((((size_t)b * 8 + w) * 8 + nt) * 4 + mt) * 64 + l;
            ((uint2*)y5)[off] = make_uint2(p0, p1);
        }
    }
}

// ---------------- conv5 finish: read y5 frag-order, BN+lrelu+max/mean pool over p -> h ----------------
__global__ __launch_bounds__(512) void conv5_finish_kernel(
    const unsigned short* __restrict__ y5, const float* __restrict__ st, float* __restrict__ h)
{
    const int b = blockIdx.x, t = threadIdx.x;
    const int w = t >> 6, l = t & 63, lm = l & 15;
    #pragma unroll
    for (int nt = 0; nt < 8; ++nt) {
        const int o = w * 128 + nt * 16 + lm;
        const float sc = st[o], sh = st[1024 + o];
        #pragma unroll
        for (int cloud = 0; cloud < 2; ++cloud) {
            float mx = -INFINITY, sm = 0.f;
            #pragma unroll
            for (int half = 0; half < 2; ++half) {
                const int mt = cloud * 2 + half;
                uint2 pk = ((const uint2*)y5)[((((size_t)b * 8 + w) * 8 + nt) * 4 + mt) * 64 + l];
                #pragma unroll
                for (int r = 0; r < 4; ++r) {
                    unsigned word = (r < 2) ? pk.x : pk.y;
                    unsigned short bits = (unsigned short)((r & 1) ? (word >> 16) : (word & 0xffff));
                    float v = lrelu(fmaf(sc, bf2f(bits), sh));
                    mx = fmaxf(mx, v); sm += v;
                }
            }
            mx = fmaxf(mx, __shfl_xor(mx, 16)); sm += __shfl_xor(sm, 16);
            mx = fmaxf(mx, __shfl_xor(mx, 32)); sm += __shfl_xor(sm, 32);
            if (l < 16) {
                const int n = b * 2 + cloud;
                h[(size_t)n * 2048 + o] = mx;
                h[(size_t)n * 2048 + 1024 + o] = sm * (1.f / 32.f);
            }
        }
    }
}

// ---------------- FC GEMM via MFMA: C[m][col] = A[m][:] . W[col][:] (+bias) ----------------
// BM=64, BN=64, 256 thr (4 waves, 1 ntg each). BNIN: apply lrelu(st*k+sh) to A during staging.
// STATS: fused per-column partial sum/sumsq over the block's 64 rows -> partS/partQ[col][blockIdx.y].
template<bool BNIN, bool STATS>
__global__ __launch_bounds__(256) void gemm_mfma_nt(
    const float* __restrict__ A, const unsigned short* __restrict__ wpk,
    const float* __restrict__ stbn, const float* __restrict__ bias,
    float* __restrict__ Cc, float* __restrict__ partS, float* __restrict__ partQ,
    int Nn, int NTT, int Kk)
{
    const int o0 = blockIdx.x * 64;
    const int m0 = blockIdx.y * 64;
    const int t = threadIdx.x;
    const int w = t >> 6, l = t & 63;
    const int lg = l >> 4, lm = l & 15;

    __shared__ unsigned short Ah[2][64][40];
    __shared__ unsigned short Al[2][64][40];

    f32x4 acc[4];
    #pragma unroll
    for (int mt = 0; mt < 4; ++mt) acc[mt] = (f32x4)0.f;

    const int srow = t >> 3;        // 0..31 (handles rows srow, srow+32)
    const int sk4  = (t & 7) * 4;   // k offset within 32-chunk

    auto stage = [&](int kb, int buf) {
        const float* src = A + (size_t)(m0 + srow) * Kk + kb * 32 + sk4;
        float4 v0 = *(const float4*)src;
        float4 v1 = *(const float4*)(src + (size_t)32 * Kk);
        if (BNIN) {
            const float4 s4 = *(const float4*)(stbn + kb * 32 + sk4);
            const float4 t4 = *(const float4*)(stbn + 1024 + kb * 32 + sk4);
            #pragma unroll
            for (int e = 0; e < 4; ++e) {
                (&v0.x)[e] = lrelu(fmaf((&s4.x)[e], (&v0.x)[e], (&t4.x)[e]));
                (&v1.x)[e] = lrelu(fmaf((&s4.x)[e], (&v1.x)[e], (&t4.x)[e]));
            }
        }
        #pragma unroll
        for (int e = 0; e < 4; e += 2) {
            float a0 = (&v0.x)[e], a1 = (&v0.x)[e + 1];
            unsigned short h0 = f2bf(a0), h1 = f2bf(a1);
            *(unsigned*)&Ah[buf][srow][sk4 + e] = (unsigned)h0 | ((unsigned)h1 << 16);
            *(unsigned*)&Al[buf][srow][sk4 + e] =
                (unsigned)f2bf(a0 - bf2f(h0)) | ((unsigned)f2bf(a1 - bf2f(h1)) << 16);
            float b0 = (&v1.x)[e], b1 = (&v1.x)[e + 1];
            unsigned short g0 = f2bf(b0), g1 = f2bf(b1);
            *(unsigned*)&Ah[buf][srow + 32][sk4 + e] = (unsigned)g0 | ((unsigned)g1 << 16);
            *(unsigned*)&Al[buf][srow + 32][sk4 + e] =
                (unsigned)f2bf(b0 - bf2f(g0)) | ((unsigned)f2bf(b1 - bf2f(g1)) << 16);
        }
    };

    const int KB = Kk >> 5;
    stage(0, 0);
    int cur = 0;
    const int ntg = blockIdx.x * 4 + w;
    for (int kb = 0; kb < KB; ++kb) {
        __syncthreads();
        if (kb + 1 < KB) stage(kb + 1, cur ^ 1);
        bf16x8 a_h[4], a_l[4];
        #pragma unroll
        for (int mt = 0; mt < 4; ++mt) {
            a_h[mt] = *(const bf16x8*)&Ah[cur][mt * 16 + lm][lg * 8];
            a_l[mt] = *(const bf16x8*)&Al[cur][mt * 16 + lm][lg * 8];
        }
        const unsigned short* bp = wpk + ((size_t)kb * NTT + ntg) * 1024 + (size_t)l * 8;
        bf16x8 Bh = *(const bf16x8*)bp;
        bf16x8 Bl = *(const bf16x8*)(bp + 512);
        #pragma unroll
        for (int mt = 0; mt < 4; ++mt) {
            acc[mt] = __builtin_amdgcn_mfma_f32_16x16x32_bf16(a_h[mt], Bl, acc[mt], 0, 0, 0);
            acc[mt] = __builtin_amdgcn_mfma_f32_16x16x32_bf16(a_l[mt], Bh, acc[mt], 0, 0, 0);
            acc[mt] = __builtin_amdgcn_mfma_f32_16x16x32_bf16(a_h[mt], Bh, acc[mt], 0, 0, 0);
        }
        cur ^= 1;
    }

    const int col = o0 + w * 16 + lm;
    const bool cok = col < Nn;
    const float bv = (bias != nullptr && cok) ? bias[col] : 0.f;
    float s = 0.f, q = 0.f;
    #pragma unroll
    for (int mt = 0; mt < 4; ++mt) {
        #pragma unroll
        for (int r = 0; r < 4; ++r) {
            float v = acc[mt][r] + bv;
            if (STATS) { s += v; q = fmaf(v, v, q); }
            if (cok) Cc[(size_t)(m0 + mt * 16 + lg * 4 + r) * Nn + col] = v;
        }
    }
    if (STATS) {
        s += __shfl_xor(s, 16); q += __shfl_xor(q, 16);
        s += __shfl_xor(s, 32); q += __shfl_xor(q, 32);
        if (l < 16 && cok) {
            partS[(size_t)col * 2048 + blockIdx.y] = s;
            partQ[(size_t)col * 2048 + blockIdx.y] = q;
        }
    }
}

__global__ __launch_bounds__(256) void logsoftmax_kernel(float* __restrict__ out)
{
    const int n = blockIdx.x, t = threadIdx.x;
    float* row = out + (size_t)n * 800;
    __shared__ float red[256];
    float v[4];
    float mx = -INFINITY;
    #pragma unroll
    for (int j = 0; j < 4; ++j) {
        int i = t + j * 256;
        v[j] = (i < 800) ? row[i] : -INFINITY;
        mx = fmaxf(mx, v[j]);
    }
    red[t] = mx; __syncthreads();
    for (int w = 128; w > 0; w >>= 1) { if (t < w) red[t] = fmaxf(red[t], red[t + w]); __syncthreads(); }
    const float m = red[0]; __syncthreads();
    float s = 0.f;
    #pragma unroll
    for (int j = 0; j < 4; ++j) { int i = t + j * 256; if (i < 800) s += expf(v[j] - m); }
    red[t] = s; __syncthreads();
    for (int w = 128; w > 0; w >>= 1) { if (t < w) red[t] += red[t + w]; __syncthreads(); }
    const float lg = m + logf(red[0]);
    #pragma unroll
    for (int j = 0; j < 4; ++j) { int i = t + j * 256; if (i < 800) row[i] = v[j] - lg; }
}

extern "C" void kernel_launch(void* const* d_in, const int* in_sizes, int n_in,
                              void* d_out, int out_size, void* d_ws, size_t ws_size,
                              hipStream_t stream)
{
    (void)in_sizes; (void)n_in; (void)out_size; (void)ws_size;
    const float* x   = (const float*)d_in[0];
    const float* W1  = (const float*)d_in[2];
    const float* g1  = (const float*)d_in[3];
    const float* b1  = (const float*)d_in[4];
    const float* W2  = (const float*)d_in[5];
    const float* g2  = (const float*)d_in[6];
    const float* b2  = (const float*)d_in[7];
    const float* W3  = (const float*)d_in[8];
    const float* g3  = (const float*)d_in[9];
    const float* b3  = (const float*)d_in[10];
    const float* W4  = (const float*)d_in[11];
    const float* g4  = (const float*)d_in[12];
    const float* b4  = (const float*)d_in[13];
    const float* W5  = (const float*)d_in[14];
    const float* g5  = (const float*)d_in[15];
    const float* b5  = (const float*)d_in[16];
    const float* Wl1 = (const float*)d_in[17];
    const float* g6  = (const float*)d_in[18];
    const float* b6  = (const float*)d_in[19];
    const float* Wl2 = (const float*)d_in[20];
    const float* bl2 = (const float*)d_in[21];
    const float* g7  = (const float*)d_in[22];
    const float* b7  = (const float*)d_in[23];
    const float* Wl3 = (const float*)d_in[24];
    const float* bl3 = (const float*)d_in[25];

    char* ws = (char*)d_ws;
    size_t off = 0;
    auto alloc = [&](size_t bytes) -> void* {
        void* p = ws + off; off += (bytes + 255) & ~(size_t)255; return p;
    };
    float*          xc    = (float*)alloc((size_t)NPTS * 512 * P * 4);       // 134.2 MB
    unsigned char*  idx   = (unsigned char*)alloc((size_t)NPTS * P * KNN_K); // 0.98 MB
    float*          partS = (float*)alloc((size_t)1024 * 2048 * 4);          // 8.4 MB
    float*          partQ = (float*)alloc((size_t)1024 * 2048 * 4);          // 8.4 MB
    float*          st    = (float*)alloc(2048 * 4);
    float*          wt    = (float*)alloc((size_t)512 * 1024 * 4);           // 2 MB (f32 wcat blk1 / W5 pack)
    unsigned short* wpk   = (unsigned short*)alloc((size_t)128 * 512 * 2 * 2); // 256 KB edge pack
    unsigned short* fcpk  = (unsigned short*)alloc((size_t)512 * 2048 * 2 * 2); // 4.2 MB FC pack
    float*          h     = (float*)alloc((size_t)2048 * 2048 * 4);          // 16.8 MB
    float*          h1p   = (float*)alloc((size_t)2048 * 512 * 4);           // 4.2 MB
    unsigned short* y5 = (unsigned short*)xc;   // in-place
    float* h2p = h + 1048576;                   // h dead after FC1 gemm

    const float inv_edge = 1.f / (float)(NPTS * P * KNN_K);

    // ---- edge block 1: x(C=3) -> O=64 (xc ch 0..63), f32 path ----
    knn_kernel<3><<<NPTS, 64, 0, stream>>>(x, 3 * P, idx);
    build_wcat_kernel<<<(3 * 128 + 255) / 256, 256, 0, stream>>>(W1, wt, 3, 64, 1);
    edge_pass_kernel<3, 64, 1, false><<<NPTS, 256, 0, stream>>>(x, 3 * P, wt, idx, nullptr, nullptr, partS, partQ);
    reduce_stats_kernel<<<64, 256, 0, stream>>>(partS, partQ, g1, b1, st, 2048, inv_edge);
    edge_pass_kernel<3, 64, 1, true><<<NPTS, 256, 0, stream>>>(x, 3 * P, wt, idx, st, xc + 0 * P, nullptr, nullptr);

    // ---- edge block 2: xc ch 0..63 -> O=64 (ch 64..127), MFMA ----
    knn_kernel<64><<<NPTS, 64, 0, stream>>>(xc, 512 * P, idx);
    pack_wcat_direct<<<(64 * 128 + 255) / 256, 256, 0, stream>>>(W2, wpk, 64, 64, 1);
    edge_mfma_kernel<64, 64, false><<<NPTS, 256, 0, stream>>>(xc, 512 * P, wpk, idx, nullptr, nullptr, partS, partQ);
    reduce_stats_kernel<<<64, 256, 0, stream>>>(partS, partQ, g2, b2, st, 2048, inv_edge);
    edge_mfma_kernel<64, 64, true><<<NPTS, 256, 0, stream>>>(xc, 512 * P, wpk, idx, st, xc + 64 * P, nullptr, nullptr);

    // ---- edge block 3: xc ch 64..127 -> O=128 (ch 128..255), MFMA ----
    knn_kernel<64><<<NPTS, 64, 0, stream>>>(xc + 64 * P, 512 * P, idx);
    pack_wcat_direct<<<(64 * 256 + 255) / 256, 256, 0, stream>>>(W3, wpk, 64, 128, 1);
    edge_mfma_kernel<64, 128, false><<<NPTS, 256, 0, stream>>>(xc + 64 * P, 512 * P, wpk, idx, nullptr, nullptr, partS, partQ);
    reduce_stats_kernel<<<128, 256, 0, stream>>>(partS, partQ, g3, b3, st, 2048, inv_edge);
    edge_mfma_kernel<64, 128, true><<<NPTS, 256, 0, stream>>>(xc + 64 * P, 512 * P, wpk, idx, st, xc + 128 * P, nullptr, nullptr);

    // ---- edge block 4: xc ch 128..255 -> O=256 (ch 256..511), MFMA, 2 chunks ----
    knn_kernel<128><<<NPTS, 64, 0, stream>>>(xc + 128 * P, 512 * P, idx);
    pack_wcat_direct<<<(128 * 512 + 255) / 256, 256, 0, stream>>>(W4, wpk, 128, 256, 2);
    edge_mfma_kernel<128, 256, false><<<NPTS, 256, 0, stream>>>(xc + 128 * P, 512 * P, wpk, idx, nullptr, nullptr, partS, partQ);
    reduce_stats_kernel<<<256, 256, 0, stream>>>(partS, partQ, g4, b4, st, 2048, inv_edge);
    edge_mfma_kernel<128, 256, true><<<NPTS, 256, 0, stream>>>(xc + 128 * P, 512 * P, wpk, idx, st, xc + 256 * P, nullptr, nullptr);

    // ---- stage 5 via MFMA, single GEMM pass: stats + y5 in place; then BN+pool ----
    pack_w5_kernel<<<2048, 256, 0, stream>>>(W5, (unsigned short*)wt);
    conv5_store_kernel<<<1024, 512, 0, stream>>>(xc, (const unsigned short*)wt, y5, partS, partQ);
    reduce_stats_kernel<<<1024, 256, 0, stream>>>(partS, partQ, g5, b5, st, 1024, 1.f / 65536.f);
    conv5_finish_kernel<<<1024, 512, 0, stream>>>(y5, st, h);

    // ---- FC head (MFMA, fused colstats + BN-in-stage) ----
    // FC1: h[2048][2048] x Wl1[512][2048] -> h1p (raw), stats fused
    pack_wfc_kernel<<<4096, 256, 0, stream>>>(Wl1, fcpk, 2048, 512, 32);
    gemm_mfma_nt<false, true><<<dim3(8, 32), 256, 0, stream>>>(h, fcpk, nullptr, nullptr, h1p, partS, partQ, 512, 32, 2048);
    reduce_stats_kernel<<<512, 256, 0, stream>>>(partS, partQ, g6, b6, st, 32, 1.f / 2048.f);

    // FC2: BN(h1p)+lrelu staged in; x Wl2[256][512] + bl2 -> h2p (raw incl. bias), stats fused
    pack_wfc_kernel<<<512, 256, 0, stream>>>(Wl2, fcpk, 512, 256, 16);
    gemm_mfma_nt<true, true><<<dim3(4, 32), 256, 0, stream>>>(h1p, fcpk, st, bl2, h2p, partS, partQ, 256, 16, 512);
    reduce_stats_kernel<<<256, 256, 0, stream>>>(partS, partQ, g7, b7, st, 32, 1.f / 2048.f);

    // FC3: BN(h2p)+lrelu staged in; x Wl3[800][256] + bl3 -> d_out
    pack_wfc_kernel<<<832, 256, 0, stream>>>(Wl3, fcpk, 256, 800, 52);
    gemm_mfma_nt<true, false><<<dim3(13, 32), 256, 0, stream>>>(h2p, fcpk, st, bl3, (float*)d_out, nullptr, nullptr, 800, 52, 256);

    logsoftmax_kernel<<<NPTS, 256, 0, stream>>>((float*)d_out);
}

// Round 9
// 849.917 us; speedup vs baseline: 2.4621x; 1.0014x over previous
//
#include <hip/hip_runtime.h>
#include <hip/hip_bf16.h>
#include <cstdint>
#include <cstddef>

#define NPTS 2048
#define P 32
#define KNN_K 15
#define LRELU_NEG 0.2f
#define BN_EPS 1e-5f

__device__ __forceinline__ float lrelu(float x) { return x > 0.f ? x : LRELU_NEG * x; }

__device__ __forceinline__ unsigned short f2bf(float x) {      // RNE f32 -> bf16 bits
    union { float f; unsigned u; } uu; uu.f = x;
    unsigned r = uu.u + 0x7fffu + ((uu.u >> 16) & 1u);
    return (unsigned short)(r >> 16);
}
__device__ __forceinline__ float bf2f(unsigned short b) {
    union { unsigned u; float f; } uu; uu.u = ((unsigned)b) << 16;
    return uu.f;
}

typedef short bf16x8 __attribute__((ext_vector_type(8)));
typedef float f32x4  __attribute__((ext_vector_type(4)));

// ================= mega-pack: all weight transforms in one launch =================
__device__ __forceinline__ void edge_pack_body(int i, const float* __restrict__ W,
                                               unsigned short* __restrict__ wpk,
                                               int C, int O, int NCHUNK)
{
    const int TOTC = 2 * O, NTT = TOTC / 16;
    if (i >= C * TOTC) return;
    int j = i & 7, lane = (i >> 3) & 63, rest = i >> 9;
    int ntg = rest % NTT, kb = rest / NTT;
    int k = kb * 32 + (lane >> 4) * 8 + j;
    int col = ntg * 16 + (lane & 15);
    int O2C = TOTC / NCHUNK, OC = O / NCHUNK;
    int chunk = col / O2C, cl = col % O2C;
    float v;
    if (cl < OC) { int o = chunk * OC + cl; v = W[(size_t)o * 2 * C + k]; }
    else         { int o = chunk * OC + cl - OC; v = W[(size_t)o * 2 * C + C + k] - W[(size_t)o * 2 * C + k]; }
    unsigned short hi = f2bf(v);
    wpk[(size_t)rest * 1024 + lane * 8 + j] = hi;
    wpk[(size_t)rest * 1024 + 512 + lane * 8 + j] = f2bf(v - bf2f(hi));
}

__device__ __forceinline__ void wfc_pack_body(int i, const float* __restrict__ W,
                                              unsigned short* __restrict__ wpk,
                                              int Kk, int Nn, int NTT)
{
    if (i >= NTT * 16 * Kk) return;
    int j = i & 7, lane = (i >> 3) & 63, rest = i >> 9;
    int ntg = rest % NTT, kb = rest / NTT;
    int k = kb * 32 + (lane >> 4) * 8 + j;
    int col = ntg * 16 + (lane & 15);
    float v = (col < Nn) ? W[(size_t)col * Kk + k] : 0.f;
    unsigned short hi = f2bf(v);
    wpk[(size_t)rest * 1024 + lane * 8 + j] = hi;
    wpk[(size_t)rest * 1024 + 512 + lane * 8 + j] = f2bf(v - bf2f(hi));
}

__global__ __launch_bounds__(256) void pack_all_kernel(
    const float* __restrict__ W1, const float* __restrict__ W2,
    const float* __restrict__ W3, const float* __restrict__ W4,
    const float* __restrict__ W5, const float* __restrict__ Wl1,
    const float* __restrict__ Wl2, const float* __restrict__ Wl3,
    float* __restrict__ wt1,
    unsigned short* __restrict__ wpk2, unsigned short* __restrict__ wpk3,
    unsigned short* __restrict__ wpk4, unsigned short* __restrict__ w5pk,
    unsigned short* __restrict__ fc1pk, unsigned short* __restrict__ fc2pk,
    unsigned short* __restrict__ fc3pk)
{
    const int b = blockIdx.x, t = threadIdx.x;
    if (b < 2) {                               // W1 wcat f32: C=3, O=64
        int i = b * 256 + t;
        if (i < 3 * 128) {
            int c = i / 128, col = i % 128;
            float v;
            if (col < 64) v = W1[(size_t)col * 6 + c];
            else          v = W1[(size_t)(col - 64) * 6 + 3 + c] - W1[(size_t)(col - 64) * 6 + c];
            wt1[i] = v;
        }
    } else if (b < 34)   edge_pack_body((b - 2)    * 256 + t, W2, wpk2, 64, 64, 1);
    else if (b < 98)     edge_pack_body((b - 34)   * 256 + t, W3, wpk3, 64, 128, 1);
    else if (b < 354)    edge_pack_body((b - 98)   * 256 + t, W4, wpk4, 128, 256, 2);
    else if (b < 2402) {                       // W5: [1024][512] -> frag order
        int i = (b - 354) * 256 + t;
        if (i < (1 << 19)) {
            int j = i & 7, lane = (i >> 3) & 63, nt = (i >> 9) & 63, kb = i >> 15;
            int c = kb * 32 + (lane >> 4) * 8 + j;
            int o = nt * 16 + (lane & 15);
            float f = W5[(size_t)o * 512 + c];
            unsigned short hi = f2bf(f);
            size_t base = (size_t)(kb * 64 + nt) * 1024 + (size_t)lane * 8 + j;
            w5pk[base] = hi;
            w5pk[base + 512] = f2bf(f - bf2f(hi));
        }
    }
    else if (b < 6498)   wfc_pack_body((b - 2402) * 256 + t, Wl1, fc1pk, 2048, 512, 32);
    else if (b < 7010)   wfc_pack_body((b - 6498) * 256 + t, Wl2, fc2pk, 512, 256, 16);
    else                 wfc_pack_body((b - 7010) * 256 + t, Wl3, fc3pk, 256, 800, 52);
}

// ================= edge conv, f32 VALU path (block 1: C=3) — stats pass fuses KNN =================
template<int C, int O, int NCHUNK, bool OUT>
__global__ __launch_bounds__(256) void edge_pass_kernel(
    const float* __restrict__ xin, int cloudStride,
    const float* __restrict__ wt,
    unsigned char* idx,                            // written if !OUT, read if OUT
    const float* __restrict__ st,
    float* __restrict__ xcout,
    float* __restrict__ partS, float* __restrict__ partQ)
{
    constexpr int TOTC = 2 * O;
    constexpr int O2C = TOTC / NCHUNK;
    constexpr int OC  = O / NCHUNK;
    constexpr int TPC = (O2C >= 256) ? 1 : (256 / O2C);
    constexpr int CPT = (O2C > 256) ? (O2C / 256) : 1;
    constexpr int PP  = P / TPC;
    constexpr int TPO = 256 / OC;
    constexpr int PPo = P / TPO;
    const int n = blockIdx.x, t = threadIdx.x;

    __shared__ float xs[C][P];
    __shared__ float gh[P * O2C];
    __shared__ unsigned char idl[P * KNN_K];
    __shared__ float red[2][256];
    __shared__ float xx[P];

    const float* xp = xin + (size_t)n * cloudStride;
    for (int i = t; i < C * P; i += 256) xs[i / P][i % P] = xp[i];

    if constexpr (!OUT) {
        // fused KNN (bit-identical to the former knn_kernel): pd aliased on gh
        float* pd = gh;                            // [P][P+1]
        __syncthreads();
        if (t < P) { float s = 0.f; for (int c = 0; c < C; ++c) { float v = xs[c][t]; s = fmaf(v, v, s); } xx[t] = s; }
        __syncthreads();
        for (int i = t; i < P * P; i += 256) {
            int p = i >> 5, q = i & 31;
            float d = 0.f;
            for (int c = 0; c < C; ++c) d = fmaf(xs[c][p], xs[c][q], d);
            pd[p * (P + 1) + q] = 2.f * d - xx[p] - xx[q];   // diag exactly 0
        }
        __syncthreads();
        if (t < P) {
            for (int j = 0; j < KNN_K; ++j) {
                float best = -INFINITY; int bq = 0;
                for (int q = 0; q < P; ++q) { float v = pd[t * (P + 1) + q]; if (v > best) { best = v; bq = q; } }
                idl[t * KNN_K + j] = (unsigned char)bq;
                idx[(size_t)n * (P * KNN_K) + t * KNN_K + j] = (unsigned char)bq;
                pd[t * (P + 1) + bq] = -INFINITY;
            }
        }
    } else {
        for (int i = t; i < P * KNN_K; i += 256) idl[i] = idx[(size_t)n * (P * KNN_K) + i];
    }

    const int col = (O2C >= 256) ? t : (t % O2C);
    const int p0  = ((O2C >= 256) ? 0 : (t / O2C)) * PP;
    const int o   = t % OC;
    const int p0c = (t / OC) * PPo;

    for (int chunk = 0; chunk < NCHUNK; ++chunk) {
        __syncthreads();
        {
            float acc[CPT][PP];
            #pragma unroll
            for (int j = 0; j < CPT; ++j)
                #pragma unroll
                for (int p = 0; p < PP; ++p) acc[j][p] = 0.f;
            for (int c = 0; c < C; ++c) {
                float w[CPT];
                #pragma unroll
                for (int j = 0; j < CPT; ++j) w[j] = wt[(size_t)c * TOTC + chunk * O2C + col + j * 256];
                #pragma unroll
                for (int p = 0; p < PP; ++p) {
                    float xv = xs[c][p0 + p];
                    #pragma unroll
                    for (int j = 0; j < CPT; ++j) acc[j][p] = fmaf(w[j], xv, acc[j][p]);
                }
            }
            #pragma unroll
            for (int j = 0; j < CPT; ++j)
                #pragma unroll
                for (int p = 0; p < PP; ++p) gh[(p0 + p) * O2C + col + j * 256] = acc[j][p];
        }
        __syncthreads();

        if constexpr (!OUT) {
            float ssum = 0.f, ssq = 0.f;
            #pragma unroll
            for (int p = 0; p < PPo; ++p) {
                const int pp = p0c + p;
                const float g = gh[pp * O2C + OC + o];
                #pragma unroll
                for (int k = 0; k < KNN_K; ++k) {
                    const int q = idl[pp * KNN_K + k];
                    float yv = gh[q * O2C + o] + g;
                    ssum += yv; ssq += yv * yv;
                }
            }
            red[0][t] = ssum; red[1][t] = ssq;
            __syncthreads();
            if (t < OC) {
                float S = 0.f, Q = 0.f;
                #pragma unroll
                for (int j = 0; j < TPO; ++j) { S += red[0][t + j * OC]; Q += red[1][t + j * OC]; }
                partS[(size_t)(chunk * OC + t) * 2048 + n] = S;
                partQ[(size_t)(chunk * OC + t) * 2048 + n] = Q;
            }
        } else {
            const float s = st[chunk * OC + o], sh = st[1024 + chunk * OC + o];
            float rbuf[PPo];
            #pragma unroll
            for (int p = 0; p < PPo; ++p) {
                const int pp = p0c + p;
                const float g = gh[pp * O2C + OC + o];
                float mx = -INFINITY, mn = INFINITY;
                #pragma unroll
                for (int k = 0; k < KNN_K; ++k) {
                    const int q = idl[pp * KNN_K + k];
                    float yv = gh[q * O2C + o] + g;
                    mx = fmaxf(mx, yv); mn = fminf(mn, yv);
                }
                rbuf[p] = lrelu(fmaf(s, (s >= 0.f ? mx : mn), sh));
            }
            __syncthreads();
            #pragma unroll
            for (int p = 0; p < PPo; ++p) gh[o * (P + 1) + p0c + p] = rbuf[p];
            __syncthreads();
            for (int i = t; i < OC * P; i += 256)
                xcout[(size_t)n * (512 * P) + chunk * OC * P + i] = gh[(i / P) * (P + 1) + (i % P)];
        }
    }
}

// ================= edge conv via MFMA (blocks 2-4) — stats pass fuses KNN =================
template<int C, int O, bool OUT>
__global__ __launch_bounds__(256) void edge_mfma_kernel(
    const float* __restrict__ xin, int cloudStride,
    const unsigned short* __restrict__ wpk,
    unsigned char* idx,                            // written if !OUT, read if OUT
    const float* __restrict__ st,
    float* __restrict__ xcout,
    float* __restrict__ partS, float* __restrict__ partQ)
{
    constexpr int TOTC  = 2 * O;
    constexpr int O2C   = (TOTC > 256) ? 256 : TOTC;
    constexpr int NCHUNK= TOTC / O2C;
    constexpr int OC    = O2C / 2;
    constexpr int NTW   = O2C / 64;
    constexpr int KB    = C / 32;
    constexpr int NTT   = TOTC / 16;
    constexpr int AS    = C + 8;
    constexpr int GHS   = O2C + 4;
    constexpr int TPO   = 256 / OC;
    constexpr int PPo   = P / TPO;
    static_assert(P * GHS >= C * P + P * (P + 1), "pd+xs must fit in gh");

    const int n = blockIdx.x, t = threadIdx.x;
    const int w = t >> 6, l = t & 63;
    const int lg = l >> 4, lm = l & 15;

    __shared__ unsigned short Ah[P * AS];
    __shared__ unsigned short Al[P * AS];
    __shared__ float gh[P * GHS];
    __shared__ unsigned char idl[P * KNN_K];
    __shared__ float xx[P];

    const float* xp = xin + (size_t)n * cloudStride;
    if constexpr (!OUT) {
        float* xsf = gh;                 // [C*P] f32, alias
        float* pd  = gh + C * P;         // [P][P+1], alias
        for (int i = t; i < C * P; i += 256) {
            int c = i / P, p = i % P;
            float v = xp[i];
            unsigned short hi = f2bf(v);
            Ah[p * AS + c] = hi;
            Al[p * AS + c] = f2bf(v - bf2f(hi));
            xsf[i] = v;
        }
        __syncthreads();
        if (t < P) { float s = 0.f; for (int c = 0; c < C; ++c) { float v = xsf[c * P + t]; s = fmaf(v, v, s); } xx[t] = s; }
        __syncthreads();
        for (int i = t; i < P * P; i += 256) {
            int p = i >> 5, q = i & 31;
            float d = 0.f;
            for (int c = 0; c < C; ++c) d = fmaf(xsf[c * P + p], xsf[c * P + q], d);
            pd[p * (P + 1) + q] = 2.f * d - xx[p] - xx[q];
        }
        __syncthreads();
        if (t < P) {
            for (int j = 0; j < KNN_K; ++j) {
                float best = -INFINITY; int bq = 0;
                for (int q = 0; q < P; ++q) { float v = pd[t * (P + 1) + q]; if (v > best) { best = v; bq = q; } }
                idl[t * KNN_K + j] = (unsigned char)bq;
                idx[(size_t)n * (P * KNN_K) + t * KNN_K + j] = (unsigned char)bq;
                pd[t * (P + 1) + bq] = -INFINITY;
            }
        }
        __syncthreads();                 // idl visible; xsf/pd dead
    } else {
        for (int i = t; i < C * P; i += 256) {
            int c = i / P, p = i % P;
            float v = xp[i];
            unsigned short hi = f2bf(v);
            Ah[p * AS + c] = hi;
            Al[p * AS + c] = f2bf(v - bf2f(hi));
        }
        for (int i = t; i < P * KNN_K; i += 256) idl[i] = idx[(size_t)n * (P * KNN_K) + i];
        __syncthreads();
    }

    const int o = t % OC;
    const int p0c = (t / OC) * PPo;

    for (int chunk = 0; chunk < NCHUNK; ++chunk) {
        f32x4 acc[2][NTW];
        #pragma unroll
        for (int mt = 0; mt < 2; ++mt)
            #pragma unroll
            for (int nt = 0; nt < NTW; ++nt) acc[mt][nt] = (f32x4)0.f;

        #pragma unroll
        for (int kb = 0; kb < KB; ++kb) {
            bf16x8 a_h[2], a_l[2];
            #pragma unroll
            for (int mt = 0; mt < 2; ++mt) {
                int row = mt * 16 + lm;
                a_h[mt] = *(const bf16x8*)&Ah[row * AS + kb * 32 + lg * 8];
                a_l[mt] = *(const bf16x8*)&Al[row * AS + kb * 32 + lg * 8];
            }
            #pragma unroll
            for (int nt = 0; nt < NTW; ++nt) {
                int ntg = chunk * (O2C / 16) + w * NTW + nt;
                const unsigned short* bp = wpk + (size_t)(kb * NTT + ntg) * 1024 + (size_t)l * 8;
                bf16x8 Bh = *(const bf16x8*)bp;
                bf16x8 Bl = *(const bf16x8*)(bp + 512);
                #pragma unroll
                for (int mt = 0; mt < 2; ++mt) {
                    acc[mt][nt] = __builtin_amdgcn_mfma_f32_16x16x32_bf16(a_h[mt], Bl, acc[mt][nt], 0, 0, 0);
                    acc[mt][nt] = __builtin_amdgcn_mfma_f32_16x16x32_bf16(a_l[mt], Bh, acc[mt][nt], 0, 0, 0);
                    acc[mt][nt] = __builtin_amdgcn_mfma_f32_16x16x32_bf16(a_h[mt], Bh, acc[mt][nt], 0, 0, 0);
                }
            }
        }
        __syncthreads();
        #pragma unroll
        for (int mt = 0; mt < 2; ++mt)
            #pragma unroll
            for (int nt = 0; nt < NTW; ++nt) {
                int colb = (w * NTW + nt) * 16 + lm;
                #pragma unroll
                for (int r = 0; r < 4; ++r)
                    gh[(mt * 16 + lg * 4 + r) * GHS + colb] = acc[mt][nt][r];
            }
        __syncthreads();

        if constexpr (!OUT) {
            float ssum = 0.f, ssq = 0.f;
            #pragma unroll
            for (int p = 0; p < PPo; ++p) {
                const int pp = p0c + p;
                const float g = gh[pp * GHS + OC + o];
                #pragma unroll
                for (int k = 0; k < KNN_K; ++k) {
                    const int q = idl[pp * KNN_K + k];
                    float yv = gh[q * GHS + o] + g;
                    ssum += yv; ssq += yv * yv;
                }
            }
            __syncthreads();
            gh[t] = ssum; gh[256 + t] = ssq;
            __syncthreads();
            if (t < OC) {
                float S = 0.f, Q = 0.f;
                #pragma unroll
                for (int j = 0; j < TPO; ++j) { S += gh[t + j * OC]; Q += gh[256 + t + j * OC]; }
                partS[(size_t)(chunk * OC + t) * 2048 + n] = S;
                partQ[(size_t)(chunk * OC + t) * 2048 + n] = Q;
            }
        } else {
            const float s = st[chunk * OC + o], sh = st[1024 + chunk * OC + o];
            float rbuf[PPo];
            #pragma unroll
            for (int p = 0; p < PPo; ++p) {
                const int pp = p0c + p;
                const float g = gh[pp * GHS + OC + o];
                float mx = -INFINITY, mn = INFINITY;
                #pragma unroll
                for (int k = 0; k < KNN_K; ++k) {
                    const int q = idl[pp * KNN_K + k];
                    float yv = gh[q * GHS + o] + g;
                    mx = fmaxf(mx, yv); mn = fminf(mn, yv);
                }
                rbuf[p] = lrelu(fmaf(s, (s >= 0.f ? mx : mn), sh));
            }
            __syncthreads();
            #pragma unroll
            for (int p = 0; p < PPo; ++p) gh[o * (P + 1) + p0c + p] = rbuf[p];
            __syncthreads();
            for (int i = t; i < OC * P; i += 256)
                xcout[(size_t)n * (512 * P) + chunk * OC * P + i] = gh[(i / P) * (P + 1) + (i % P)];
        }
    }
}

// ================= reduce partials -> scale/shift per channel =================
__global__ __launch_bounds__(256) void reduce_stats_kernel(const float* __restrict__ partS,
                                                           const float* __restrict__ partQ,
                                                           const float* __restrict__ gamma,
                                                           const float* __restrict__ beta,
                                                           float* __restrict__ st, int nparts, float inv_count)
{
    const int o = blockIdx.x, t = threadIdx.x;
    __shared__ float rs[256], rq[256];
    float S = 0.f, Q = 0.f;
    for (int i = t; i < nparts; i += 256) { S += partS[(size_t)o * 2048 + i]; Q += partQ[(size_t)o * 2048 + i]; }
    rs[t] = S; rq[t] = Q; __syncthreads();
    for (int w = 128; w > 0; w >>= 1) { if (t < w) { rs[t] += rs[t + w]; rq[t] += rq[t + w]; } __syncthreads(); }
    if (t == 0) {
        float m = rs[0] * inv_count;
        float v = fmaxf(rq[0] * inv_count - m * m, 0.f);
        float s = gamma[o] * rsqrtf(v + BN_EPS);
        st[o] = s;
        st[1024 + o] = fmaf(-m, s, beta[o]);
    }
}

// ================= conv5 single pass, double-buffered staging =================
__global__ __launch_bounds__(512) void conv5_store_kernel(
    const float* xc, const unsigned short* __restrict__ wpack,
    unsigned short* y5,
    float* __restrict__ partS, float* __restrict__ partQ)
{
    const int b = blockIdx.x;
    const int t = threadIdx.x;
    const int w = t >> 6, l = t & 63;
    const int lg = l >> 4, lm = l & 15;

    __shared__ unsigned short Ah[2][64][40];
    __shared__ unsigned short Al[2][64][40];

    f32x4 acc[4][8];
    #pragma unroll
    for (int mt = 0; mt < 4; ++mt)
        #pragma unroll
        for (int nt = 0; nt < 8; ++nt) acc[mt][nt] = (f32x4)0.f;

    const float* xbase = xc + (size_t)(b * 2) * (512 * P);

    const int sp4    = t & 7;
    const int schalf = (t >> 3) & 15;
    const int scloud = (t >> 7) & 1;
    const bool sact  = t < 256;

    auto stage = [&](int kb, int buf) {
        if (sact) {
            const float* src = xbase + (size_t)scloud * (512 * P)
                             + (size_t)(kb * 32 + 2 * schalf) * P + sp4 * 4;
            const float4 v0 = *(const float4*)src;
            const float4 v1 = *(const float4*)(src + P);
            const int r0 = scloud * 32 + sp4 * 4;
            #pragma unroll
            for (int e = 0; e < 4; ++e) {
                float a0 = (&v0.x)[e], a1 = (&v1.x)[e];
                unsigned short h0 = f2bf(a0), h1 = f2bf(a1);
                unsigned short l0 = f2bf(a0 - bf2f(h0)), l1 = f2bf(a1 - bf2f(h1));
                *(unsigned*)&Ah[buf][r0 + e][2 * schalf] = (unsigned)h0 | ((unsigned)h1 << 16);
                *(unsigned*)&Al[buf][r0 + e][2 * schalf] = (unsigned)l0 | ((unsigned)l1 << 16);
            }
        }
    };

    stage(0, 0);
    int cur = 0;
    for (int kb = 0; kb < 16; ++kb) {
        __syncthreads();
        if (kb + 1 < 16) stage(kb + 1, cur ^ 1);

        bf16x8 a_h[4], a_l[4];
        #pragma unroll
        for (int mt = 0; mt < 4; ++mt) {
            int row = mt * 16 + lm;
            a_h[mt] = *(const bf16x8*)&Ah[cur][row][lg * 8];
            a_l[mt] = *(const bf16x8*)&Al[cur][row][lg * 8];
        }
        #pragma unroll
        for (int nt = 0; nt < 8; ++nt) {
            const int ntg = w * 8 + nt;
            const unsigned short* bp = wpack + (size_t)(kb * 64 + ntg) * 2 * 512 + (size_t)l * 8;
            bf16x8 Bh = *(const bf16x8*)bp;
            bf16x8 Bl = *(const bf16x8*)(bp + 512);
            #pragma unroll
            for (int mt = 0; mt < 4; ++mt) {
                acc[mt][nt] = __builtin_amdgcn_mfma_f32_16x16x32_bf16(a_h[mt], Bl, acc[mt][nt], 0, 0, 0);
                acc[mt][nt] = __builtin_amdgcn_mfma_f32_16x16x32_bf16(a_l[mt], Bh, acc[mt][nt], 0, 0, 0);
                acc[mt][nt] = __builtin_amdgcn_mfma_f32_16x16x32_bf16(a_h[mt], Bh, acc[mt][nt], 0, 0, 0);
            }
        }
        cur ^= 1;
    }
    __syncthreads();   // all xc reads complete before in-place overwrite

    #pragma unroll
    for (int nt = 0; nt < 8; ++nt) {
        float s = 0.f, q = 0.f;
        #pragma unroll
        for (int mt = 0; mt < 4; ++mt)
            #pragma unroll
            for (int r = 0; r < 4; ++r) { float v = acc[mt][nt][r]; s += v; q = fmaf(v, v, q); }
        s += __shfl_xor(s, 16); q += __shfl_xor(q, 16);
        s += __shfl_xor(s, 32); q += __shfl_xor(q, 32);
        if (l < 16) {
            int o = w * 128 + nt * 16 + lm;
            partS[(size_t)o * 2048 + b] = s;
            partQ[(size_t)o * 2048 + b] = q;
        }
        #pragma unroll
        for (int mt = 0; mt < 4; ++mt) {
            unsigned p0 = (unsigned)f2bf(acc[mt][nt][0]) | ((unsigned)f2bf(acc[mt][nt][1]) << 16);
            unsigned p1 = (unsigned)f2bf(acc[mt][nt][2]) | ((unsigned)f2bf(acc[mt][nt][3]) << 16);
            size_t off = ((((size_t)b * 8 + w) * 8 + nt) * 4 + mt) * 64 + l;
            ((uint2*)y5)[off] = make_uint2(p0, p1);
        }
    }
}

// ================= conv5 finish: BN+lrelu+max/mean pool -> h =================
__global__ __launch_bounds__(512) void conv5_finish_kernel(
    const unsigned short* __restrict__ y5, const float* __restrict__ st, float* __restrict__ h)
{
    const int b = blockIdx.x, t = threadIdx.x;
    const int w = t >> 6, l = t & 63, lm = l & 15;
    #pragma unroll
    for (int nt = 0; nt < 8; ++nt) {
        const int o = w * 128 + nt * 16 + lm;
        const float sc = st[o], sh = st[1024 + o];
        #pragma unroll
        for (int cloud = 0; cloud < 2; ++cloud) {
            float mx = -INFINITY, sm = 0.f;
            #pragma unroll
            for (int half = 0; half < 2; ++half) {
                const int mt = cloud * 2 + half;
                uint2 pk = ((const uint2*)y5)[((((size_t)b * 8 + w) * 8 + nt) * 4 + mt) * 64 + l];
                #pragma unroll
                for (int r = 0; r < 4; ++r) {
                    unsigned word = (r < 2) ? pk.x : pk.y;
                    unsigned short bits = (unsigned short)((r & 1) ? (word >> 16) : (word & 0xffff));
                    float v = lrelu(fmaf(sc, bf2f(bits), sh));
                    mx = fmaxf(mx, v); sm += v;
                }
            }
            mx = fmaxf(mx, __shfl_xor(mx, 16)); sm += __shfl_xor(sm, 16);
            mx = fmaxf(mx, __shfl_xor(mx, 32)); sm += __shfl_xor(sm, 32);
            if (l < 16) {
                const int n = b * 2 + cloud;
                h[(size_t)n * 2048 + o] = mx;
                h[(size_t)n * 2048 + 1024 + o] = sm * (1.f / 32.f);
            }
        }
    }
}

// ================= FC GEMM via MFMA (fused BN-in / colstats-out) =================
template<bool BNIN, bool STATS>
__global__ __launch_bounds__(256) void gemm_mfma_nt(
    const float* __restrict__ A, const unsigned short* __restrict__ wpk,
    const float* __restrict__ stbn, const float* __restrict__ bias,
    float* __restrict__ Cc, float* __restrict__ partS, float* __restrict__ partQ,
    int Nn, int NTT, int Kk)
{
    const int o0 = blockIdx.x * 64;
    const int m0 = blockIdx.y * 64;
    const int t = threadIdx.x;
    const int w = t >> 6, l = t & 63;
    const int lg = l >> 4, lm = l & 15;

    __shared__ unsigned short Ah[2][64][40];
    __shared__ unsigned short Al[2][64][40];

    f32x4 acc[4];
    #pragma unroll
    for (int mt = 0; mt < 4; ++mt) acc[mt] = (f32x4)0.f;

    const int srow = t >> 3;
    const int sk4  = (t & 7) * 4;

    auto stage = [&](int kb, int buf) {
        const float* src = A + (size_t)(m0 + srow) * Kk + kb * 32 + sk4;
        float4 v0 = *(const float4*)src;
        float4 v1 = *(const float4*)(src + (size_t)32 * Kk);
        if (BNIN) {
            const float4 s4 = *(const float4*)(stbn + kb * 32 + sk4);
            const float4 t4 = *(const float4*)(stbn + 1024 + kb * 32 + sk4);
            #pragma unroll
            for (int e = 0; e < 4; ++e) {
                (&v0.x)[e] = lrelu(fmaf((&s4.x)[e], (&v0.x)[e], (&t4.x)[e]));
                (&v1.x)[e] = lrelu(fmaf((&s4.x)[e], (&v1.x)[e], (&t4.x)[e]));
            }
        }
        #pragma unroll
        for (int e = 0; e < 4; e += 2) {
            float a0 = (&v0.x)[e], a1 = (&v0.x)[e + 1];
            unsigned short h0 = f2bf(a0), h1 = f2bf(a1);
            *(unsigned*)&Ah[buf][srow][sk4 + e] = (unsigned)h0 | ((unsigned)h1 << 16);
            *(unsigned*)&Al[buf][srow][sk4 + e] =
                (unsigned)f2bf(a0 - bf2f(h0)) | ((unsigned)f2bf(a1 - bf2f(h1)) << 16);
            float b0 = (&v1.x)[e], b1 = (&v1.x)[e + 1];
            unsigned short g0 = f2bf(b0), g1 = f2bf(b1);
            *(unsigned*)&Ah[buf][srow + 32][sk4 + e] = (unsigned)g0 | ((unsigned)g1 << 16);
            *(unsigned*)&Al[buf][srow + 32][sk4 + e] =
                (unsigned)f2bf(b0 - bf2f(g0)) | ((unsigned)f2bf(b1 - bf2f(g1)) << 16);
        }
    };

    const int KB = Kk >> 5;
    stage(0, 0);
    int cur = 0;
    const int ntg = blockIdx.x * 4 + w;
    for (int kb = 0; kb < KB; ++kb) {
        __syncthreads();
        if (kb + 1 < KB) stage(kb + 1, cur ^ 1);
        bf16x8 a_h[4], a_l[4];
        #pragma unroll
        for (int mt = 0; mt < 4; ++mt) {
            a_h[mt] = *(const bf16x8*)&Ah[cur][mt * 16 + lm][lg * 8];
            a_l[mt] = *(const bf16x8*)&Al[cur][mt * 16 + lm][lg * 8];
        }
        const unsigned short* bp = wpk + ((size_t)kb * NTT + ntg) * 1024 + (size_t)l * 8;
        bf16x8 Bh = *(const bf16x8*)bp;
        bf16x8 Bl = *(const bf16x8*)(bp + 512);
        #pragma unroll
        for (int mt = 0; mt < 4; ++mt) {
            acc[mt] = __builtin_amdgcn_mfma_f32_16x16x32_bf16(a_h[mt], Bl, acc[mt], 0, 0, 0);
            acc[mt] = __builtin_amdgcn_mfma_f32_16x16x32_bf16(a_l[mt], Bh, acc[mt], 0, 0, 0);
            acc[mt] = __builtin_amdgcn_mfma_f32_16x16x32_bf16(a_h[mt], Bh, acc[mt], 0, 0, 0);
        }
        cur ^= 1;
    }

    const int col = o0 + w * 16 + lm;
    const bool cok = col < Nn;
    const float bv = (bias != nullptr && cok) ? bias[col] : 0.f;
    float s = 0.f, q = 0.f;
    #pragma unroll
    for (int mt = 0; mt < 4; ++mt) {
        #pragma unroll
        for (int r = 0; r < 4; ++r) {
            float v = acc[mt][r] + bv;
            if (STATS) { s += v; q = fmaf(v, v, q); }
            if (cok) Cc[(size_t)(m0 + mt * 16 + lg * 4 + r) * Nn + col] = v;
        }
    }
    if (STATS) {
        s += __shfl_xor(s, 16); q += __shfl_xor(q, 16);
        s += __shfl_xor(s, 32); q += __shfl_xor(q, 32);
        if (l < 16 && cok) {
            partS[(size_t)col * 2048 + blockIdx.y] = s;
            partQ[(size_t)col * 2048 + blockIdx.y] = q;
        }
    }
}

__global__ __launch_bounds__(256) void logsoftmax_kernel(float* __restrict__ out)
{
    const int n = blockIdx.x, t = threadIdx.x;
    float* row = out + (size_t)n * 800;
    __shared__ float red[256];
    float v[4];
    float mx = -INFINITY;
    #pragma unroll
    for (int j = 0; j < 4; ++j) {
        int i = t + j * 256;
        v[j] = (i < 800) ? row[i] : -INFINITY;
        mx = fmaxf(mx, v[j]);
    }
    red[t] = mx; __syncthreads();
    for (int w = 128; w > 0; w >>= 1) { if (t < w) red[t] = fmaxf(red[t], red[t + w]); __syncthreads(); }
    const float m = red[0]; __syncthreads();
    float s = 0.f;
    #pragma unroll
    for (int j = 0; j < 4; ++j) { int i = t + j * 256; if (i < 800) s += expf(v[j] - m); }
    red[t] = s; __syncthreads();
    for (int w = 128; w > 0; w >>= 1) { if (t < w) red[t] += red[t + w]; __syncthreads(); }
    const float lg = m + logf(red[0]);
    #pragma unroll
    for (int j = 0; j < 4; ++j) { int i = t + j * 256; if (i < 800) row[i] = v[j] - lg; }
}

extern "C" void kernel_launch(void* const* d_in, const int* in_sizes, int n_in,
                              void* d_out, int out_size, void* d_ws, size_t ws_size,
                              hipStream_t stream)
{
    (void)in_sizes; (void)n_in; (void)out_size; (void)ws_size;
    const float* x   = (const float*)d_in[0];
    const float* W1  = (const float*)d_in[2];
    const float* g1  = (const float*)d_in[3];
    const float* b1  = (const float*)d_in[4];
    const float* W2  = (const float*)d_in[5];
    const float* g2  = (const float*)d_in[6];
    const float* b2  = (const float*)d_in[7];
    const float* W3  = (const float*)d_in[8];
    const float* g3  = (const float*)d_in[9];
    const float* b3  = (const float*)d_in[10];
    const float* W4  = (const float*)d_in[11];
    const float* g4  = (const float*)d_in[12];
    const float* b4  = (const float*)d_in[13];
    const float* W5  = (const float*)d_in[14];
    const float* g5  = (const float*)d_in[15];
    const float* b5  = (const float*)d_in[16];
    const float* Wl1 = (const float*)d_in[17];
    const float* g6  = (const float*)d_in[18];
    const float* b6  = (const float*)d_in[19];
    const float* Wl2 = (const float*)d_in[20];
    const float* bl2 = (const float*)d_in[21];
    const float* g7  = (const float*)d_in[22];
    const float* b7  = (const float*)d_in[23];
    const float* Wl3 = (const float*)d_in[24];
    const float* bl3 = (const float*)d_in[25];

    char* ws = (char*)d_ws;
    size_t off = 0;
    auto alloc = [&](size_t bytes) -> void* {
        void* p = ws + off; off += (bytes + 255) & ~(size_t)255; return p;
    };
    float*          xc    = (float*)alloc((size_t)NPTS * 512 * P * 4);        // 134.2 MB
    unsigned char*  idx   = (unsigned char*)alloc((size_t)NPTS * P * KNN_K);  // 0.98 MB
    float*          partS = (float*)alloc((size_t)1024 * 2048 * 4);           // 8.4 MB
    float*          partQ = (float*)alloc((size_t)1024 * 2048 * 4);           // 8.4 MB
    float*          st    = (float*)alloc(2048 * 4);
    float*          wt1   = (float*)alloc(3 * 128 * 4);                       // block-1 wcat f32
    unsigned short* wpk2  = (unsigned short*)alloc((size_t)2 * 64 * 128 * 2);  // 32 KB
    unsigned short* wpk3  = (unsigned short*)alloc((size_t)2 * 64 * 256 * 2);  // 64 KB
    unsigned short* wpk4  = (unsigned short*)alloc((size_t)2 * 128 * 512 * 2); // 256 KB
    unsigned short* w5pk  = (unsigned short*)alloc((size_t)2 * 512 * 1024 * 2);// 2 MB
    unsigned short* fc1pk = (unsigned short*)alloc((size_t)2 * 512 * 2048 * 2);// 4 MB
    unsigned short* fc2pk = (unsigned short*)alloc((size_t)2 * 256 * 512 * 2); // 0.5 MB
    unsigned short* fc3pk = (unsigned short*)alloc((size_t)2 * 832 * 256 * 2); // 0.83 MB
    float*          h     = (float*)alloc((size_t)2048 * 2048 * 4);           // 16.8 MB
    float*          h1p   = (float*)alloc((size_t)2048 * 512 * 4);            // 4.2 MB
    unsigned short* y5 = (unsigned short*)xc;   // in-place
    float* h2p = h + 1048576;                   // h dead after FC1 gemm

    const float inv_edge = 1.f / (float)(NPTS * P * KNN_K);

    // ---- all weight packs, one launch ----
    pack_all_kernel<<<7842, 256, 0, stream>>>(W1, W2, W3, W4, W5, Wl1, Wl2, Wl3,
                                              wt1, wpk2, wpk3, wpk4, w5pk, fc1pk, fc2pk, fc3pk);

    // ---- edge block 1: x(C=3) -> O=64 (xc ch 0..63), f32 path, knn fused in stats ----
    edge_pass_kernel<3, 64, 1, false><<<NPTS, 256, 0, stream>>>(x, 3 * P, wt1, idx, nullptr, nullptr, partS, partQ);
    reduce_stats_kernel<<<64, 256, 0, stream>>>(partS, partQ, g1, b1, st, 2048, inv_edge);
    edge_pass_kernel<3, 64, 1, true><<<NPTS, 256, 0, stream>>>(x, 3 * P, wt1, idx, st, xc + 0 * P, nullptr, nullptr);

    // ---- edge block 2: xc ch 0..63 -> O=64 (ch 64..127), MFMA, knn fused ----
    edge_mfma_kernel<64, 64, false><<<NPTS, 256, 0, stream>>>(xc, 512 * P, wpk2, idx, nullptr, nullptr, partS, partQ);
    reduce_stats_kernel<<<64, 256, 0, stream>>>(partS, partQ, g2, b2, st, 2048, inv_edge);
    edge_mfma_kernel<64, 64, true><<<NPTS, 256, 0, stream>>>(xc, 512 * P, wpk2, idx, st, xc + 64 * P, nullptr, nullptr);

    // ---- edge block 3: xc ch 64..127 -> O=128 (ch 128..255), MFMA, knn fused ----
    edge_mfma_kernel<64, 128, false><<<NPTS, 256, 0, stream>>>(xc + 64 * P, 512 * P, wpk3, idx, nullptr, nullptr, partS, partQ);
    reduce_stats_kernel<<<128, 256, 0, stream>>>(partS, partQ, g3, b3, st, 2048, inv_edge);
    edge_mfma_kernel<64, 128, true><<<NPTS, 256, 0, stream>>>(xc + 64 * P, 512 * P, wpk3, idx, st, xc + 128 * P, nullptr, nullptr);

    // ---- edge block 4: xc ch 128..255 -> O=256 (ch 256..511), MFMA, knn fused ----
    edge_mfma_kernel<128, 256, false><<<NPTS, 256, 0, stream>>>(xc + 128 * P, 512 * P, wpk4, idx, nullptr, nullptr, partS, partQ);
    reduce_stats_kernel<<<256, 256, 0, stream>>>(partS, partQ, g4, b4, st, 2048, inv_edge);
    edge_mfma_kernel<128, 256, true><<<NPTS, 256, 0, stream>>>(xc + 128 * P, 512 * P, wpk4, idx, st, xc + 256 * P, nullptr, nullptr);

    // ---- stage 5 via MFMA, single GEMM pass: stats + y5 in place; then BN+pool ----
    conv5_store_kernel<<<1024, 512, 0, stream>>>(xc, w5pk, y5, partS, partQ);
    reduce_stats_kernel<<<1024, 256, 0, stream>>>(partS, partQ, g5, b5, st, 1024, 1.f / 65536.f);
    conv5_finish_kernel<<<1024, 512, 0, stream>>>(y5, st, h);

    // ---- FC head (MFMA, fused colstats + BN-in-stage) ----
    gemm_mfma_nt<false, true><<<dim3(8, 32), 256, 0, stream>>>(h, fc1pk, nullptr, nullptr, h1p, partS, partQ, 512, 32, 2048);
    reduce_stats_kernel<<<512, 256, 0, stream>>>(partS, partQ, g6, b6, st, 32, 1.f / 2048.f);

    gemm_mfma_nt<true, true><<<dim3(4, 32), 256, 0, stream>>>(h1p, fc2pk, st, bl2, h2p, partS, partQ, 256, 16, 512);
    reduce_stats_kernel<<<256, 256, 0, stream>>>(partS, partQ, g7, b7, st, 32, 1.f / 2048.f);

    gemm_mfma_nt<true, false><<<dim3(13, 32), 256, 0, stream>>>(h2p, fc3pk, st, bl3, (float*)d_out, nullptr, nullptr, 800, 52, 256);

    logsoftmax_kernel<<<NPTS, 256, 0, stream>>>((float*)d_out);
}

// Round 10
// 787.048 us; speedup vs baseline: 2.6588x; 1.0799x over previous
//
#include <hip/hip_runtime.h>
#include <hip/hip_bf16.h>
#include <cstdint>
#include <cstddef>

#define NPTS 2048
#define P 32
#define KNN_K 15
#define LRELU_NEG 0.2f
#define BN_EPS 1e-5f

__device__ __forceinline__ float lrelu(float x) { return x > 0.f ? x : LRELU_NEG * x; }

__device__ __forceinline__ unsigned short f2bf(float x) {      // RNE f32 -> bf16 bits
    union { float f; unsigned u; } uu; uu.f = x;
    unsigned r = uu.u + 0x7fffu + ((uu.u >> 16) & 1u);
    return (unsigned short)(r >> 16);
}
__device__ __forceinline__ float bf2f(unsigned short b) {
    union { unsigned u; float f; } uu; uu.u = ((unsigned)b) << 16;
    return uu.f;
}

typedef short bf16x8 __attribute__((ext_vector_type(8)));
typedef float f32x4  __attribute__((ext_vector_type(4)));

// ================= mega-pack: all weight transforms in one launch =================
__device__ __forceinline__ void edge_pack_body(int i, const float* __restrict__ W,
                                               unsigned short* __restrict__ wpk,
                                               int C, int O, int NCHUNK)
{
    const int TOTC = 2 * O, NTT = TOTC / 16;
    if (i >= C * TOTC) return;
    int j = i & 7, lane = (i >> 3) & 63, rest = i >> 9;
    int ntg = rest % NTT, kb = rest / NTT;
    int k = kb * 32 + (lane >> 4) * 8 + j;
    int col = ntg * 16 + (lane & 15);
    int O2C = TOTC / NCHUNK, OC = O / NCHUNK;
    int chunk = col / O2C, cl = col % O2C;
    float v;
    if (cl < OC) { int o = chunk * OC + cl; v = W[(size_t)o * 2 * C + k]; }
    else         { int o = chunk * OC + cl - OC; v = W[(size_t)o * 2 * C + C + k] - W[(size_t)o * 2 * C + k]; }
    unsigned short hi = f2bf(v);
    wpk[(size_t)rest * 1024 + lane * 8 + j] = hi;
    wpk[(size_t)rest * 1024 + 512 + lane * 8 + j] = f2bf(v - bf2f(hi));
}

__device__ __forceinline__ void wfc_pack_body(int i, const float* __restrict__ W,
                                              unsigned short* __restrict__ wpk,
                                              int Kk, int Nn, int NTT)
{
    if (i >= NTT * 16 * Kk) return;
    int j = i & 7, lane = (i >> 3) & 63, rest = i >> 9;
    int ntg = rest % NTT, kb = rest / NTT;
    int k = kb * 32 + (lane >> 4) * 8 + j;
    int col = ntg * 16 + (lane & 15);
    float v = (col < Nn) ? W[(size_t)col * Kk + k] : 0.f;
    unsigned short hi = f2bf(v);
    wpk[(size_t)rest * 1024 + lane * 8 + j] = hi;
    wpk[(size_t)rest * 1024 + 512 + lane * 8 + j] = f2bf(v - bf2f(hi));
}

__global__ __launch_bounds__(256) void pack_all_kernel(
    const float* __restrict__ W1, const float* __restrict__ W2,
    const float* __restrict__ W3, const float* __restrict__ W4,
    const float* __restrict__ W5, const float* __restrict__ Wl1,
    const float* __restrict__ Wl2, const float* __restrict__ Wl3,
    float* __restrict__ wt1,
    unsigned short* __restrict__ wpk2, unsigned short* __restrict__ wpk3,
    unsigned short* __restrict__ wpk4, unsigned short* __restrict__ w5pk,
    unsigned short* __restrict__ fc1pk, unsigned short* __restrict__ fc2pk,
    unsigned short* __restrict__ fc3pk)
{
    const int b = blockIdx.x, t = threadIdx.x;
    if (b < 2) {                               // W1 wcat f32: C=3, O=64
        int i = b * 256 + t;
        if (i < 3 * 128) {
            int c = i / 128, col = i % 128;
            float v;
            if (col < 64) v = W1[(size_t)col * 6 + c];
            else          v = W1[(size_t)(col - 64) * 6 + 3 + c] - W1[(size_t)(col - 64) * 6 + c];
            wt1[i] = v;
        }
    } else if (b < 34)   edge_pack_body((b - 2)    * 256 + t, W2, wpk2, 64, 64, 1);
    else if (b < 98)     edge_pack_body((b - 34)   * 256 + t, W3, wpk3, 64, 128, 1);
    else if (b < 354)    edge_pack_body((b - 98)   * 256 + t, W4, wpk4, 128, 256, 2);
    else if (b < 2402) {                       // W5: [1024][512] -> frag order
        int i = (b - 354) * 256 + t;
        if (i < (1 << 19)) {
            int j = i & 7, lane = (i >> 3) & 63, nt = (i >> 9) & 63, kb = i >> 15;
            int c = kb * 32 + (lane >> 4) * 8 + j;
            int o = nt * 16 + (lane & 15);
            float f = W5[(size_t)o * 512 + c];
            unsigned short hi = f2bf(f);
            size_t base = (size_t)(kb * 64 + nt) * 1024 + (size_t)lane * 8 + j;
            w5pk[base] = hi;
            w5pk[base + 512] = f2bf(f - bf2f(hi));
        }
    }
    else if (b < 6498)   wfc_pack_body((b - 2402) * 256 + t, Wl1, fc1pk, 2048, 512, 32);
    else if (b < 7010)   wfc_pack_body((b - 6498) * 256 + t, Wl2, fc2pk, 512, 256, 16);
    else                 wfc_pack_body((b - 7010) * 256 + t, Wl3, fc3pk, 256, 800, 52);
}

// ================= edge conv, f32 VALU path (block 1: C=3) — stats pass fuses KNN =================
template<int C, int O, int NCHUNK, bool OUT>
__global__ __launch_bounds__(256) void edge_pass_kernel(
    const float* __restrict__ xin, int cloudStride,
    const float* __restrict__ wt,
    unsigned char* idx,                            // written if !OUT, read if OUT
    const float* __restrict__ st,
    float* __restrict__ xcout,
    float* __restrict__ partS, float* __restrict__ partQ)
{
    constexpr int TOTC = 2 * O;
    constexpr int O2C = TOTC / NCHUNK;
    constexpr int OC  = O / NCHUNK;
    constexpr int TPC = (O2C >= 256) ? 1 : (256 / O2C);
    constexpr int CPT = (O2C > 256) ? (O2C / 256) : 1;
    constexpr int PP  = P / TPC;
    constexpr int QUADS = OC / 4;
    constexpr int PG    = 256 / QUADS;
    constexpr int PPq   = P / PG;
    const int n = blockIdx.x, t = threadIdx.x;

    __shared__ float xs[C][P];
    __shared__ alignas(16) float gh[P * O2C];
    __shared__ unsigned char idl[P * KNN_K];
    __shared__ float xx[P];

    const float* xp = xin + (size_t)n * cloudStride;
    for (int i = t; i < C * P; i += 256) xs[i / P][i % P] = xp[i];

    if constexpr (!OUT) {
        // fused KNN (bit-identical to the standalone knn kernel): pd aliased on gh
        float* pd = gh;                            // [P][P+1]
        __syncthreads();
        if (t < P) { float s = 0.f; for (int c = 0; c < C; ++c) { float v = xs[c][t]; s = fmaf(v, v, s); } xx[t] = s; }
        __syncthreads();
        for (int i = t; i < P * P; i += 256) {
            int p = i >> 5, q = i & 31;
            float d = 0.f;
            for (int c = 0; c < C; ++c) d = fmaf(xs[c][p], xs[c][q], d);
            pd[p * (P + 1) + q] = 2.f * d - xx[p] - xx[q];   // diag exactly 0
        }
        __syncthreads();
        if (t < P) {
            for (int j = 0; j < KNN_K; ++j) {
                float best = -INFINITY; int bq = 0;
                for (int q = 0; q < P; ++q) { float v = pd[t * (P + 1) + q]; if (v > best) { best = v; bq = q; } }
                idl[t * KNN_K + j] = (unsigned char)bq;
                idx[(size_t)n * (P * KNN_K) + t * KNN_K + j] = (unsigned char)bq;
                pd[t * (P + 1) + bq] = -INFINITY;
            }
        }
    } else {
        for (int i = t; i < P * KNN_K; i += 256) idl[i] = idx[(size_t)n * (P * KNN_K) + i];
    }

    const int col = (O2C >= 256) ? t : (t % O2C);
    const int p0  = ((O2C >= 256) ? 0 : (t / O2C)) * PP;
    const int q4  = t % QUADS;
    const int pg  = t / QUADS;
    const int p0q = pg * PPq;

    for (int chunk = 0; chunk < NCHUNK; ++chunk) {
        __syncthreads();
        {
            float acc[CPT][PP];
            #pragma unroll
            for (int j = 0; j < CPT; ++j)
                #pragma unroll
                for (int p = 0; p < PP; ++p) acc[j][p] = 0.f;
            for (int c = 0; c < C; ++c) {
                float w[CPT];
                #pragma unroll
                for (int j = 0; j < CPT; ++j) w[j] = wt[(size_t)c * TOTC + chunk * O2C + col + j * 256];
                #pragma unroll
                for (int p = 0; p < PP; ++p) {
                    float xv = xs[c][p0 + p];
                    #pragma unroll
                    for (int j = 0; j < CPT; ++j) acc[j][p] = fmaf(w[j], xv, acc[j][p]);
                }
            }
            #pragma unroll
            for (int j = 0; j < CPT; ++j)
                #pragma unroll
                for (int p = 0; p < PP; ++p) gh[(p0 + p) * O2C + col + j * 256] = acc[j][p];
        }
        __syncthreads();

        if constexpr (!OUT) {
            f32x4 ssum4 = (f32x4)0.f, ssq4 = (f32x4)0.f;
            #pragma unroll
            for (int p = 0; p < PPq; ++p) {
                const int pp = p0q + p;
                const f32x4 gv = *(const f32x4*)&gh[pp * O2C + OC + q4 * 4];
                #pragma unroll
                for (int k = 0; k < KNN_K; ++k) {
                    const int q = idl[pp * KNN_K + k];
                    f32x4 yv = *(const f32x4*)&gh[q * O2C + q4 * 4] + gv;
                    ssum4 += yv; ssq4 += yv * yv;
                }
            }
            __syncthreads();           // all gathers done; reuse gh as reduction scratch
            #pragma unroll
            for (int e = 0; e < 4; ++e) {
                gh[(q4 * 4 + e) * PG + pg] = ssum4[e];
                gh[OC * PG + (q4 * 4 + e) * PG + pg] = ssq4[e];
            }
            __syncthreads();
            if (t < OC) {
                float S = 0.f, Q = 0.f;
                #pragma unroll
                for (int j = 0; j < PG; ++j) { S += gh[t * PG + j]; Q += gh[OC * PG + t * PG + j]; }
                partS[(size_t)(chunk * OC + t) * 2048 + n] = S;
                partQ[(size_t)(chunk * OC + t) * 2048 + n] = Q;
            }
        } else {
            const f32x4 s4  = *(const f32x4*)&st[chunk * OC + q4 * 4];
            const f32x4 sh4 = *(const f32x4*)&st[1024 + chunk * OC + q4 * 4];
            f32x4 res[PPq];
            #pragma unroll
            for (int p = 0; p < PPq; ++p) {
                const int pp = p0q + p;
                const f32x4 gv = *(const f32x4*)&gh[pp * O2C + OC + q4 * 4];
                f32x4 mx = (f32x4)(-INFINITY), mn = (f32x4)(INFINITY);
                #pragma unroll
                for (int k = 0; k < KNN_K; ++k) {
                    const int q = idl[pp * KNN_K + k];
                    f32x4 yv = *(const f32x4*)&gh[q * O2C + q4 * 4] + gv;
                    #pragma unroll
                    for (int e = 0; e < 4; ++e) { mx[e] = fmaxf(mx[e], yv[e]); mn[e] = fminf(mn[e], yv[e]); }
                }
                #pragma unroll
                for (int e = 0; e < 4; ++e)
                    res[p][e] = lrelu(fmaf(s4[e], (s4[e] >= 0.f ? mx[e] : mn[e]), sh4[e]));
            }
            __syncthreads();           // all gh reads done
            #pragma unroll
            for (int p = 0; p < PPq; ++p)
                #pragma unroll
                for (int e = 0; e < 4; ++e)
                    gh[(q4 * 4 + e) * (P + 1) + p0q + p] = res[p][e];
            __syncthreads();
            for (int i = t; i < OC * P; i += 256)
                xcout[(size_t)n * (512 * P) + chunk * OC * P + i] = gh[(i / P) * (P + 1) + (i % P)];
        }
    }
}

// ================= edge conv via MFMA (blocks 2-4) — stats pass fuses KNN =================
template<int C, int O, bool OUT>
__global__ __launch_bounds__(256) void edge_mfma_kernel(
    const float* __restrict__ xin, int cloudStride,
    const unsigned short* __restrict__ wpk,
    unsigned char* idx,                            // written if !OUT, read if OUT
    const float* __restrict__ st,
    float* __restrict__ xcout,
    float* __restrict__ partS, float* __restrict__ partQ)
{
    constexpr int TOTC  = 2 * O;
    constexpr int O2C   = (TOTC > 256) ? 256 : TOTC;
    constexpr int NCHUNK= TOTC / O2C;
    constexpr int OC    = O2C / 2;
    constexpr int NTW   = O2C / 64;
    constexpr int KB    = C / 32;
    constexpr int NTT   = TOTC / 16;
    constexpr int AS    = C + 8;
    constexpr int GHS   = O2C + 4;
    constexpr int QUADS = OC / 4;
    constexpr int PG    = 256 / QUADS;
    constexpr int PPq   = P / PG;
    static_assert(P * GHS >= C * P + P * (P + 1), "pd+xs must fit in gh");
    static_assert(P * GHS >= 2 * OC * PG, "stats scratch must fit in gh");

    const int n = blockIdx.x, t = threadIdx.x;
    const int w = t >> 6, l = t & 63;
    const int lg = l >> 4, lm = l & 15;

    __shared__ unsigned short Ah[P * AS];
    __shared__ unsigned short Al[P * AS];
    __shared__ alignas(16) float gh[P * GHS];
    __shared__ unsigned char idl[P * KNN_K];
    __shared__ float xx[P];

    const float* xp = xin + (size_t)n * cloudStride;
    if constexpr (!OUT) {
        float* xsf = gh;                 // [C*P] f32, alias
        float* pd  = gh + C * P;         // [P][P+1], alias
        for (int i = t; i < C * P; i += 256) {
            int c = i / P, p = i % P;
            float v = xp[i];
            unsigned short hi = f2bf(v);
            Ah[p * AS + c] = hi;
            Al[p * AS + c] = f2bf(v - bf2f(hi));
            xsf[i] = v;
        }
        __syncthreads();
        if (t < P) { float s = 0.f; for (int c = 0; c < C; ++c) { float v = xsf[c * P + t]; s = fmaf(v, v, s); } xx[t] = s; }
        __syncthreads();
        for (int i = t; i < P * P; i += 256) {
            int p = i >> 5, q = i & 31;
            float d = 0.f;
            for (int c = 0; c < C; ++c) d = fmaf(xsf[c * P + p], xsf[c * P + q], d);
            pd[p * (P + 1) + q] = 2.f * d - xx[p] - xx[q];
        }
        __syncthreads();
        if (t < P) {
            for (int j = 0; j < KNN_K; ++j) {
                float best = -INFINITY; int bq = 0;
                for (int q = 0; q < P; ++q) { float v = pd[t * (P + 1) + q]; if (v > best) { best = v; bq = q; } }
                idl[t * KNN_K + j] = (unsigned char)bq;
                idx[(size_t)n * (P * KNN_K) + t * KNN_K + j] = (unsigned char)bq;
                pd[t * (P + 1) + bq] = -INFINITY;
            }
        }
        __syncthreads();                 // idl visible; xsf/pd dead
    } else {
        for (int i = t; i < C * P; i += 256) {
            int c = i / P, p = i % P;
            float v = xp[i];
            unsigned short hi = f2bf(v);
            Ah[p * AS + c] = hi;
            Al[p * AS + c] = f2bf(v - bf2f(hi));
        }
        for (int i = t; i < P * KNN_K; i += 256) idl[i] = idx[(size_t)n * (P * KNN_K) + i];
        __syncthreads();
    }

    const int q4  = t % QUADS;
    const int pg  = t / QUADS;
    const int p0q = pg * PPq;

    for (int chunk = 0; chunk < NCHUNK; ++chunk) {
        f32x4 acc[2][NTW];
        #pragma unroll
        for (int mt = 0; mt < 2; ++mt)
            #pragma unroll
            for (int nt = 0; nt < NTW; ++nt) acc[mt][nt] = (f32x4)0.f;

        #pragma unroll
        for (int kb = 0; kb < KB; ++kb) {
            bf16x8 a_h[2], a_l[2];
            #pragma unroll
            for (int mt = 0; mt < 2; ++mt) {
                int row = mt * 16 + lm;
                a_h[mt] = *(const bf16x8*)&Ah[row * AS + kb * 32 + lg * 8];
                a_l[mt] = *(const bf16x8*)&Al[row * AS + kb * 32 + lg * 8];
            }
            #pragma unroll
            for (int nt = 0; nt < NTW; ++nt) {
                int ntg = chunk * (O2C / 16) + w * NTW + nt;
                const unsigned short* bp = wpk + (size_t)(kb * NTT + ntg) * 1024 + (size_t)l * 8;
                bf16x8 Bh = *(const bf16x8*)bp;
                bf16x8 Bl = *(const bf16x8*)(bp + 512);
                #pragma unroll
                for (int mt = 0; mt < 2; ++mt) {
                    acc[mt][nt] = __builtin_amdgcn_mfma_f32_16x16x32_bf16(a_h[mt], Bl, acc[mt][nt], 0, 0, 0);
                    acc[mt][nt] = __builtin_amdgcn_mfma_f32_16x16x32_bf16(a_l[mt], Bh, acc[mt][nt], 0, 0, 0);
                    acc[mt][nt] = __builtin_amdgcn_mfma_f32_16x16x32_bf16(a_h[mt], Bh, acc[mt][nt], 0, 0, 0);
                }
            }
        }
        __syncthreads();   // prev chunk's gh consumers done
        // scatter C frags: row = mt*16 + lg*4 + r, col = (w*NTW+nt)*16 + lm  [m89 mapping]
        #pragma unroll
        for (int mt = 0; mt < 2; ++mt)
            #pragma unroll
            for (int nt = 0; nt < NTW; ++nt) {
                int colb = (w * NTW + nt) * 16 + lm;
                #pragma unroll
                for (int r = 0; r < 4; ++r)
                    gh[(mt * 16 + lg * 4 + r) * GHS + colb] = acc[mt][nt][r];
            }
        __syncthreads();

        if constexpr (!OUT) {
            f32x4 ssum4 = (f32x4)0.f, ssq4 = (f32x4)0.f;
            #pragma unroll
            for (int p = 0; p < PPq; ++p) {
                const int pp = p0q + p;
                const f32x4 gv = *(const f32x4*)&gh[pp * GHS + OC + q4 * 4];
                #pragma unroll
                for (int k = 0; k < KNN_K; ++k) {
                    const int q = idl[pp * KNN_K + k];
                    f32x4 yv = *(const f32x4*)&gh[q * GHS + q4 * 4] + gv;
                    ssum4 += yv; ssq4 += yv * yv;
                }
            }
            __syncthreads();           // all gathers done; reuse gh as reduction scratch
            #pragma unroll
            for (int e = 0; e < 4; ++e) {
                gh[(q4 * 4 + e) * PG + pg] = ssum4[e];
                gh[OC * PG + (q4 * 4 + e) * PG + pg] = ssq4[e];
            }
            __syncthreads();
            if (t < OC) {
                float S = 0.f, Q = 0.f;
                #pragma unroll
                for (int j = 0; j < PG; ++j) { S += gh[t * PG + j]; Q += gh[OC * PG + t * PG + j]; }
                partS[(size_t)(chunk * OC + t) * 2048 + n] = S;
                partQ[(size_t)(chunk * OC + t) * 2048 + n] = Q;
            }
        } else {
            const f32x4 s4  = *(const f32x4*)&st[chunk * OC + q4 * 4];
            const f32x4 sh4 = *(const f32x4*)&st[1024 + chunk * OC + q4 * 4];
            f32x4 res[PPq];
            #pragma unroll
            for (int p = 0; p < PPq; ++p) {
                const int pp = p0q + p;
                const f32x4 gv = *(const f32x4*)&gh[pp * GHS + OC + q4 * 4];
                f32x4 mx = (f32x4)(-INFINITY), mn = (f32x4)(INFINITY);
                #pragma unroll
                for (int k = 0; k < KNN_K; ++k) {
                    const int q = idl[pp * KNN_K + k];
                    f32x4 yv = *(const f32x4*)&gh[q * GHS + q4 * 4] + gv;
                    #pragma unroll
                    for (int e = 0; e < 4; ++e) { mx[e] = fmaxf(mx[e], yv[e]); mn[e] = fminf(mn[e], yv[e]); }
                }
                #pragma unroll
                for (int e = 0; e < 4; ++e)
                    res[p][e] = lrelu(fmaf(s4[e], (s4[e] >= 0.f ? mx[e] : mn[e]), sh4[e]));
            }
            __syncthreads();           // all gh reads done
            #pragma unroll
            for (int p = 0; p < PPq; ++p)
                #pragma unroll
                for (int e = 0; e < 4; ++e)
                    gh[(q4 * 4 + e) * (P + 1) + p0q + p] = res[p][e];
            __syncthreads();
            for (int i = t; i < OC * P; i += 256)
                xcout[(size_t)n * (512 * P) + chunk * OC * P + i] = gh[(i / P) * (P + 1) + (i % P)];
        }
    }
}

// ================= reduce partials -> scale/shift per channel =================
__global__ __launch_bounds__(256) void reduce_stats_kernel(const float* __restrict__ partS,
                                                           const float* __restrict__ partQ,
                                                           const float* __restrict__ gamma,
                                                           const float* __restrict__ beta,
                                                           float* __restrict__ st, int nparts, float inv_count)
{
    const int o = blockIdx.x, t = threadIdx.x;
    __shared__ float rs[256], rq[256];
    float S = 0.f, Q = 0.f;
    for (int i = t; i < nparts; i += 256) { S += partS[(size_t)o * 2048 + i]; Q += partQ[(size_t)o * 2048 + i]; }
    rs[t] = S; rq[t] = Q; __syncthreads();
    for (int w = 128; w > 0; w >>= 1) { if (t < w) { rs[t] += rs[t + w]; rq[t] += rq[t + w]; } __syncthreads(); }
    if (t == 0) {
        float m = rs[0] * inv_count;
        float v = fmaxf(rq[0] * inv_count - m * m, 0.f);
        float s = gamma[o] * rsqrtf(v + BN_EPS);
        st[o] = s;
        st[1024 + o] = fmaf(-m, s, beta[o]);
    }
}

// ================= conv5 single pass, double-buffered staging =================
__global__ __launch_bounds__(512) void conv5_store_kernel(
    const float* xc, const unsigned short* __restrict__ wpack,
    unsigned short* y5,
    float* __restrict__ partS, float* __restrict__ partQ)
{
    const int b = blockIdx.x;
    const int t = threadIdx.x;
    const int w = t >> 6, l = t & 63;
    const int lg = l >> 4, lm = l & 15;

    __shared__ unsigned short Ah[2][64][40];
    __shared__ unsigned short Al[2][64][40];

    f32x4 acc[4][8];
    #pragma unroll
    for (int mt = 0; mt < 4; ++mt)
        #pragma unroll
        for (int nt = 0; nt < 8; ++nt) acc[mt][nt] = (f32x4)0.f;

    const float* xbase = xc + (size_t)(b * 2) * (512 * P);

    const int sp4    = t & 7;
    const int schalf = (t >> 3) & 15;
    const int scloud = (t >> 7) & 1;
    const bool sact  = t < 256;

    auto stage = [&](int kb, int buf) {
        if (sact) {
            const float* src = xbase + (size_t)scloud * (512 * P)
                             + (size_t)(kb * 32 + 2 * schalf) * P + sp4 * 4;
            const float4 v0 = *(const float4*)src;
            const float4 v1 = *(const float4*)(src + P);
            const int r0 = scloud * 32 + sp4 * 4;
            #pragma unroll
            for (int e = 0; e < 4; ++e) {
                float a0 = (&v0.x)[e], a1 = (&v1.x)[e];
                unsigned short h0 = f2bf(a0), h1 = f2bf(a1);
                unsigned short l0 = f2bf(a0 - bf2f(h0)), l1 = f2bf(a1 - bf2f(h1));
                *(unsigned*)&Ah[buf][r0 + e][2 * schalf] = (unsigned)h0 | ((unsigned)h1 << 16);
                *(unsigned*)&Al[buf][r0 + e][2 * schalf] = (unsigned)l0 | ((unsigned)l1 << 16);
            }
        }
    };

    stage(0, 0);
    int cur = 0;
    for (int kb = 0; kb < 16; ++kb) {
        __syncthreads();
        if (kb + 1 < 16) stage(kb + 1, cur ^ 1);

        bf16x8 a_h[4], a_l[4];
        #pragma unroll
        for (int mt = 0; mt < 4; ++mt) {
            int row = mt * 16 + lm;
            a_h[mt] = *(const bf16x8*)&Ah[cur][row][lg * 8];
            a_l[mt] = *(const bf16x8*)&Al[cur][row][lg * 8];
        }
        #pragma unroll
        for (int nt = 0; nt < 8; ++nt) {
            const int ntg = w * 8 + nt;
            const unsigned short* bp = wpack + (size_t)(kb * 64 + ntg) * 2 * 512 + (size_t)l * 8;
            bf16x8 Bh = *(const bf16x8*)bp;
            bf16x8 Bl = *(const bf16x8*)(bp + 512);
            #pragma unroll
            for (int mt = 0; mt < 4; ++mt) {
                acc[mt][nt] = __builtin_amdgcn_mfma_f32_16x16x32_bf16(a_h[mt], Bl, acc[mt][nt], 0, 0, 0);
                acc[mt][nt] = __builtin_amdgcn_mfma_f32_16x16x32_bf16(a_l[mt], Bh, acc[mt][nt], 0, 0, 0);
                acc[mt][nt] = __builtin_amdgcn_mfma_f32_16x16x32_bf16(a_h[mt], Bh, acc[mt][nt], 0, 0, 0);
            }
        }
        cur ^= 1;
    }
    __syncthreads();   // all xc reads complete before in-place overwrite

    #pragma unroll
    for (int nt = 0; nt < 8; ++nt) {
        float s = 0.f, q = 0.f;
        #pragma unroll
        for (int mt = 0; mt < 4; ++mt)
            #pragma unroll
            for (int r = 0; r < 4; ++r) { float v = acc[mt][nt][r]; s += v; q = fmaf(v, v, q); }
        s += __shfl_xor(s, 16); q += __shfl_xor(q, 16);
        s += __shfl_xor(s, 32); q += __shfl_xor(q, 32);
        if (l < 16) {
            int o = w * 128 + nt * 16 + lm;
            partS[(size_t)o * 2048 + b] = s;
            partQ[(size_t)o * 2048 + b] = q;
        }
        #pragma unroll
        for (int mt = 0; mt < 4; ++mt) {
            unsigned p0 = (unsigned)f2bf(acc[mt][nt][0]) | ((unsigned)f2bf(acc[mt][nt][1]) << 16);
            unsigned p1 = (unsigned)f2bf(acc[mt][nt][2]) | ((unsigned)f2bf(acc[mt][nt][3]) << 16);
            size_t off = ((((size_t)b * 8 + w) * 8 + nt) * 4 + mt) * 64 + l;
            ((uint2*)y5)[off] = make_uint2(p0, p1);
        }
    }
}

// ================= conv5 finish: BN+lrelu+max/mean pool -> h =================
__global__ __launch_bounds__(512) void conv5_finish_kernel(
    const unsigned short* __restrict__ y5, const float* __restrict__ st, float* __restrict__ h)
{
    const int b = blockIdx.x, t = threadIdx.x;
    const int w = t >> 6, l = t & 63, lm = l & 15;
    #pragma unroll
    for (int nt = 0; nt < 8; ++nt) {
        const int o = w * 128 + nt * 16 + lm;
        const float sc = st[o], sh = st[1024 + o];
        #pragma unroll
        for (int cloud = 0; cloud < 2; ++cloud) {
            float mx = -INFINITY, sm = 0.f;
            #pragma unroll
            for (int half = 0; half < 2; ++half) {
                const int mt = cloud * 2 + half;
                uint2 pk = ((const uint2*)y5)[((((size_t)b * 8 + w) * 8 + nt) * 4 + mt) * 64 + l];
                #pragma unroll
                for (int r = 0; r < 4; ++r) {
                    unsigned word = (r < 2) ? pk.x : pk.y;
                    unsigned short bits = (unsigned short)((r & 1) ? (word >> 16) : (word & 0xffff));
                    float v = lrelu(fmaf(sc, bf2f(bits), sh));
                    mx = fmaxf(mx, v); sm += v;
                }
            }
            mx = fmaxf(mx, __shfl_xor(mx, 16)); sm += __shfl_xor(sm, 16);
            mx = fmaxf(mx, __shfl_xor(mx, 32)); sm += __shfl_xor(sm, 32);
            if (l < 16) {
                const int n = b * 2 + cloud;
                h[(size_t)n * 2048 + o] = mx;
                h[(size_t)n * 2048 + 1024 + o] = sm * (1.f / 32.f);
            }
        }
    }
}

// ================= FC GEMM via MFMA (fused BN-in / colstats-out) =================
template<bool BNIN, bool STATS>
__global__ __launch_bounds__(256) void gemm_mfma_nt(
    const float* __restrict__ A, const unsigned short* __restrict__ wpk,
    const float* __restrict__ stbn, const float* __restrict__ bias,
    float* __restrict__ Cc, float* __restrict__ partS, float* __restrict__ partQ,
    int Nn, int NTT, int Kk)
{
    const int o0 = blockIdx.x * 64;
    const int m0 = blockIdx.y * 64;
    const int t = threadIdx.x;
    const int w = t >> 6, l = t & 63;
    const int lg = l >> 4, lm = l & 15;

    __shared__ unsigned short Ah[2][64][40];
    __shared__ unsigned short Al[2][64][40];

    f32x4 acc[4];
    #pragma unroll
    for (int mt = 0; mt < 4; ++mt) acc[mt] = (f32x4)0.f;

    const int srow = t >> 3;
    const int sk4  = (t & 7) * 4;

    auto stage = [&](int kb, int buf) {
        const float* src = A + (size_t)(m0 + srow) * Kk + kb * 32 + sk4;
        float4 v0 = *(const float4*)src;
        float4 v1 = *(const float4*)(src + (size_t)32 * Kk);
        if (BNIN) {
            const float4 s4 = *(const float4*)(stbn + kb * 32 + sk4);
            const float4 t4 = *(const float4*)(stbn + 1024 + kb * 32 + sk4);
            #pragma unroll
            for (int e = 0; e < 4; ++e) {
                (&v0.x)[e] = lrelu(fmaf((&s4.x)[e], (&v0.x)[e], (&t4.x)[e]));
                (&v1.x)[e] = lrelu(fmaf((&s4.x)[e], (&v1.x)[e], (&t4.x)[e]));
            }
        }
        #pragma unroll
        for (int e = 0; e < 4; e += 2) {
            float a0 = (&v0.x)[e], a1 = (&v0.x)[e + 1];
            unsigned short h0 = f2bf(a0), h1 = f2bf(a1);
            *(unsigned*)&Ah[buf][srow][sk4 + e] = (unsigned)h0 | ((unsigned)h1 << 16);
            *(unsigned*)&Al[buf][srow][sk4 + e] =
                (unsigned)f2bf(a0 - bf2f(h0)) | ((unsigned)f2bf(a1 - bf2f(h1)) << 16);
            float b0 = (&v1.x)[e], b1 = (&v1.x)[e + 1];
            unsigned short g0 = f2bf(b0), g1 = f2bf(b1);
            *(unsigned*)&Ah[buf][srow + 32][sk4 + e] = (unsigned)g0 | ((unsigned)g1 << 16);
            *(unsigned*)&Al[buf][srow + 32][sk4 + e] =
                (unsigned)f2bf(b0 - bf2f(g0)) | ((unsigned)f2bf(b1 - bf2f(g1)) << 16);
        }
    };

    const int KB = Kk >> 5;
    stage(0, 0);
    int cur = 0;
    const int ntg = blockIdx.x * 4 + w;
    for (int kb = 0; kb < KB; ++kb) {
        __syncthreads();
        if (kb + 1 < KB) stage(kb + 1, cur ^ 1);
        bf16x8 a_h[4], a_l[4];
        #pragma unroll
        for (int mt = 0; mt < 4; ++mt) {
            a_h[mt] = *(const bf16x8*)&Ah[cur][mt * 16 + lm][lg * 8];
            a_l[mt] = *(const bf16x8*)&Al[cur][mt * 16 + lm][lg * 8];
        }
        const unsigned short* bp = wpk + ((size_t)kb * NTT + ntg) * 1024 + (size_t)l * 8;
        bf16x8 Bh = *(const bf16x8*)bp;
        bf16x8 Bl = *(const bf16x8*)(bp + 512);
        #pragma unroll
        for (int mt = 0; mt < 4; ++mt) {
            acc[mt] = __builtin_amdgcn_mfma_f32_16x16x32_bf16(a_h[mt], Bl, acc[mt], 0, 0, 0);
            acc[mt] = __builtin_amdgcn_mfma_f32_16x16x32_bf16(a_l[mt], Bh, acc[mt], 0, 0, 0);
            acc[mt] = __builtin_amdgcn_mfma_f32_16x16x32_bf16(a_h[mt], Bh, acc[mt], 0, 0, 0);
        }
        cur ^= 1;
    }

    const int col = o0 + w * 16 + lm;
    const bool cok = col < Nn;
    const float bv = (bias != nullptr && cok) ? bias[col] : 0.f;
    float s = 0.f, q = 0.f;
    #pragma unroll
    for (int mt = 0; mt < 4; ++mt) {
        #pragma unroll
        for (int r = 0; r < 4; ++r) {
            float v = acc[mt][r] + bv;
            if (STATS) { s += v; q = fmaf(v, v, q); }
            if (cok) Cc[(size_t)(m0 + mt * 16 + lg * 4 + r) * Nn + col] = v;
        }
    }
    if (STATS) {
        s += __shfl_xor(s, 16); q += __shfl_xor(q, 16);
        s += __shfl_xor(s, 32); q += __shfl_xor(q, 32);
        if (l < 16 && cok) {
            partS[(size_t)col * 2048 + blockIdx.y] = s;
            partQ[(size_t)col * 2048 + blockIdx.y] = q;
        }
    }
}

__global__ __launch_bounds__(256) void logsoftmax_kernel(float* __restrict__ out)
{
    const int n = blockIdx.x, t = threadIdx.x;
    float* row = out + (size_t)n * 800;
    __shared__ float red[256];
    float v[4];
    float mx = -INFINITY;
    #pragma unroll
    for (int j = 0; j < 4; ++j) {
        int i = t + j * 256;
        v[j] = (i < 800) ? row[i] : -INFINITY;
        mx = fmaxf(mx, v[j]);
    }
    red[t] = mx; __syncthreads();
    for (int w = 128; w > 0; w >>= 1) { if (t < w) red[t] = fmaxf(red[t], red[t + w]); __syncthreads(); }
    const float m = red[0]; __syncthreads();
    float s = 0.f;
    #pragma unroll
    for (int j = 0; j < 4; ++j) { int i = t + j * 256; if (i < 800) s += expf(v[j] - m); }
    red[t] = s; __syncthreads();
    for (int w = 128; w > 0; w >>= 1) { if (t < w) red[t] += red[t + w]; __syncthreads(); }
    const float lg = m + logf(red[0]);
    #pragma unroll
    for (int j = 0; j < 4; ++j) { int i = t + j * 256; if (i < 800) row[i] = v[j] - lg; }
}

extern "C" void kernel_launch(void* const* d_in, const int* in_sizes, int n_in,
                              void* d_out, int out_size, void* d_ws, size_t ws_size,
                              hipStream_t stream)
{
    (void)in_sizes; (void)n_in; (void)out_size; (void)ws_size;
    const float* x   = (const float*)d_in[0];
    const float* W1  = (const float*)d_in[2];
    const float* g1  = (const float*)d_in[3];
    const float* b1  = (const float*)d_in[4];
    const float* W2  = (const float*)d_in[5];
    const float* g2  = (const float*)d_in[6];
    const float* b2  = (const float*)d_in[7];
    const float* W3  = (const float*)d_in[8];
    const float* g3  = (const float*)d_in[9];
    const float* b3  = (const float*)d_in[10];
    const float* W4  = (const float*)d_in[11];
    const float* g4  = (const float*)d_in[12];
    const float* b4  = (const float*)d_in[13];
    const float* W5  = (const float*)d_in[14];
    const float* g5  = (const float*)d_in[15];
    const float* b5  = (const float*)d_in[16];
    const float* Wl1 = (const float*)d_in[17];
    const float* g6  = (const float*)d_in[18];
    const float* b6  = (const float*)d_in[19];
    const float* Wl2 = (const float*)d_in[20];
    const float* bl2 = (const float*)d_in[21];
    const float* g7  = (const float*)d_in[22];
    const float* b7  = (const float*)d_in[23];
    const float* Wl3 = (const float*)d_in[24];
    const float* bl3 = (const float*)d_in[25];

    char* ws = (char*)d_ws;
    size_t off = 0;
    auto alloc = [&](size_t bytes) -> void* {
        void* p = ws + off; off += (bytes + 255) & ~(size_t)255; return p;
    };
    float*          xc    = (float*)alloc((size_t)NPTS * 512 * P * 4);        // 134.2 MB
    unsigned char*  idx   = (unsigned char*)alloc((size_t)NPTS * P * KNN_K);  // 0.98 MB
    float*          partS = (float*)alloc((size_t)1024 * 2048 * 4);           // 8.4 MB
    float*          partQ = (float*)alloc((size_t)1024 * 2048 * 4);           // 8.4 MB
    float*          st    = (float*)alloc(2048 * 4);
    float*          wt1   = (float*)alloc(3 * 128 * 4);                       // block-1 wcat f32
    unsigned short* wpk2  = (unsigned short*)alloc((size_t)2 * 64 * 128 * 2);  // 32 KB
    unsigned short* wpk3  = (unsigned short*)alloc((size_t)2 * 64 * 256 * 2);  // 64 KB
    unsigned short* wpk4  = (unsigned short*)alloc((size_t)2 * 128 * 512 * 2); // 256 KB
    unsigned short* w5pk  = (unsigned short*)alloc((size_t)2 * 512 * 1024 * 2);// 2 MB
    unsigned short* fc1pk = (unsigned short*)alloc((size_t)2 * 512 * 2048 * 2);// 4 MB
    unsigned short* fc2pk = (unsigned short*)alloc((size_t)2 * 256 * 512 * 2); // 0.5 MB
    unsigned short* fc3pk = (unsigned short*)alloc((size_t)2 * 832 * 256 * 2); // 0.83 MB
    float*          h     = (float*)alloc((size_t)2048 * 2048 * 4);           // 16.8 MB
    float*          h1p   = (float*)alloc((size_t)2048 * 512 * 4);            // 4.2 MB
    unsigned short* y5 = (unsigned short*)xc;   // in-place
    float* h2p = h + 1048576;                   // h dead after FC1 gemm

    const float inv_edge = 1.f / (float)(NPTS * P * KNN_K);

    // ---- all weight packs, one launch ----
    pack_all_kernel<<<7842, 256, 0, stream>>>(W1, W2, W3, W4, W5, Wl1, Wl2, Wl3,
                                              wt1, wpk2, wpk3, wpk4, w5pk, fc1pk, fc2pk, fc3pk);

    // ---- edge block 1: x(C=3) -> O=64 (xc ch 0..63), f32 path, knn fused in stats ----
    edge_pass_kernel<3, 64, 1, false><<<NPTS, 256, 0, stream>>>(x, 3 * P, wt1, idx, nullptr, nullptr, partS, partQ);
    reduce_stats_kernel<<<64, 256, 0, stream>>>(partS, partQ, g1, b1, st, 2048, inv_edge);
    edge_pass_kernel<3, 64, 1, true><<<NPTS, 256, 0, stream>>>(x, 3 * P, wt1, idx, st, xc + 0 * P, nullptr, nullptr);

    // ---- edge block 2: xc ch 0..63 -> O=64 (ch 64..127), MFMA, knn fused ----
    edge_mfma_kernel<64, 64, false><<<NPTS, 256, 0, stream>>>(xc, 512 * P, wpk2, idx, nullptr, nullptr, partS, partQ);
    reduce_stats_kernel<<<64, 256, 0, stream>>>(partS, partQ, g2, b2, st, 2048, inv_edge);
    edge_mfma_kernel<64, 64, true><<<NPTS, 256, 0, stream>>>(xc, 512 * P, wpk2, idx, st, xc + 64 * P, nullptr, nullptr);

    // ---- edge block 3: xc ch 64..127 -> O=128 (ch 128..255), MFMA, knn fused ----
    edge_mfma_kernel<64, 128, false><<<NPTS, 256, 0, stream>>>(xc + 64 * P, 512 * P, wpk3, idx, nullptr, nullptr, partS, partQ);
    reduce_stats_kernel<<<128, 256, 0, stream>>>(partS, partQ, g3, b3, st, 2048, inv_edge);
    edge_mfma_kernel<64, 128, true><<<NPTS, 256, 0, stream>>>(xc + 64 * P, 512 * P, wpk3, idx, st, xc + 128 * P, nullptr, nullptr);

    // ---- edge block 4: xc ch 128..255 -> O=256 (ch 256..511), MFMA, knn fused ----
    edge_mfma_kernel<128, 256, false><<<NPTS, 256, 0, stream>>>(xc + 128 * P, 512 * P, wpk4, idx, nullptr, nullptr, partS, partQ);
    reduce_stats_kernel<<<256, 256, 0, stream>>>(partS, partQ, g4, b4, st, 2048, inv_edge);
    edge_mfma_kernel<128, 256, true><<<NPTS, 256, 0, stream>>>(xc + 128 * P, 512 * P, wpk4, idx, st, xc + 256 * P, nullptr, nullptr);

    // ---- stage 5 via MFMA, single GEMM pass: stats + y5 in place; then BN+pool ----
    conv5_store_kernel<<<1024, 512, 0, stream>>>(xc, w5pk, y5, partS, partQ);
    reduce_stats_kernel<<<1024, 256, 0, stream>>>(partS, partQ, g5, b5, st, 1024, 1.f / 65536.f);
    conv5_finish_kernel<<<1024, 512, 0, stream>>>(y5, st, h);

    // ---- FC head (MFMA, fused colstats + BN-in-stage) ----
    gemm_mfma_nt<false, true><<<dim3(8, 32), 256, 0, stream>>>(h, fc1pk, nullptr, nullptr, h1p, partS, partQ, 512, 32, 2048);
    reduce_stats_kernel<<<512, 256, 0, stream>>>(partS, partQ, g6, b6, st, 32, 1.f / 2048.f);

    gemm_mfma_nt<true, true><<<dim3(4, 32), 256, 0, stream>>>(h1p, fc2pk, st, bl2, h2p, partS, partQ, 256, 16, 512);
    reduce_stats_kernel<<<256, 256, 0, stream>>>(partS, partQ, g7, b7, st, 32, 1.f / 2048.f);

    gemm_mfma_nt<true, false><<<dim3(13, 32), 256, 0, stream>>>(h2p, fc3pk, st, bl3, (float*)d_out, nullptr, nullptr, 800, 52, 256);

    logsoftmax_kernel<<<NPTS, 256, 0, stream>>>((float*)d_out);
}

// Round 11
// 776.054 us; speedup vs baseline: 2.6965x; 1.0142x over previous
//
#include <hip/hip_runtime.h>
#include <hip/hip_bf16.h>
#include <cstdint>
#include <cstddef>

#define NPTS 2048
#define P 32
#define KNN_K 15
#define LRELU_NEG 0.2f
#define BN_EPS 1e-5f

__device__ __forceinline__ float lrelu(float x) { return x > 0.f ? x : LRELU_NEG * x; }

__device__ __forceinline__ unsigned short f2bf(float x) {      // RNE f32 -> bf16 bits
    union { float f; unsigned u; } uu; uu.f = x;
    unsigned r = uu.u + 0x7fffu + ((uu.u >> 16) & 1u);
    return (unsigned short)(r >> 16);
}
__device__ __forceinline__ float bf2f(unsigned short b) {
    union { unsigned u; float f; } uu; uu.u = ((unsigned)b) << 16;
    return uu.f;
}

typedef short bf16x8 __attribute__((ext_vector_type(8)));
typedef float f32x4  __attribute__((ext_vector_type(4)));

// ================= mega-pack: all weight transforms in one launch =================
__device__ __forceinline__ void edge_pack_body(int i, const float* __restrict__ W,
                                               unsigned short* __restrict__ wpk,
                                               int C, int O, int NCHUNK)
{
    const int TOTC = 2 * O, NTT = TOTC / 16;
    if (i >= C * TOTC) return;
    int j = i & 7, lane = (i >> 3) & 63, rest = i >> 9;
    int ntg = rest % NTT, kb = rest / NTT;
    int k = kb * 32 + (lane >> 4) * 8 + j;
    int col = ntg * 16 + (lane & 15);
    int O2C = TOTC / NCHUNK, OC = O / NCHUNK;
    int chunk = col / O2C, cl = col % O2C;
    float v;
    if (cl < OC) { int o = chunk * OC + cl; v = W[(size_t)o * 2 * C + k]; }
    else         { int o = chunk * OC + cl - OC; v = W[(size_t)o * 2 * C + C + k] - W[(size_t)o * 2 * C + k]; }
    unsigned short hi = f2bf(v);
    wpk[(size_t)rest * 1024 + lane * 8 + j] = hi;
    wpk[(size_t)rest * 1024 + 512 + lane * 8 + j] = f2bf(v - bf2f(hi));
}

__device__ __forceinline__ void wfc_pack_body(int i, const float* __restrict__ W,
                                              unsigned short* __restrict__ wpk,
                                              int Kk, int Nn, int NTT)
{
    if (i >= NTT * 16 * Kk) return;
    int j = i & 7, lane = (i >> 3) & 63, rest = i >> 9;
    int ntg = rest % NTT, kb = rest / NTT;
    int k = kb * 32 + (lane >> 4) * 8 + j;
    int col = ntg * 16 + (lane & 15);
    float v = (col < Nn) ? W[(size_t)col * Kk + k] : 0.f;
    unsigned short hi = f2bf(v);
    wpk[(size_t)rest * 1024 + lane * 8 + j] = hi;
    wpk[(size_t)rest * 1024 + 512 + lane * 8 + j] = f2bf(v - bf2f(hi));
}

__global__ __launch_bounds__(256) void pack_all_kernel(
    const float* __restrict__ W1, const float* __restrict__ W2,
    const float* __restrict__ W3, const float* __restrict__ W4,
    const float* __restrict__ W5, const float* __restrict__ Wl1,
    const float* __restrict__ Wl2, const float* __restrict__ Wl3,
    float* __restrict__ wt1,
    unsigned short* __restrict__ wpk2, unsigned short* __restrict__ wpk3,
    unsigned short* __restrict__ wpk4, unsigned short* __restrict__ w5pk,
    unsigned short* __restrict__ fc1pk, unsigned short* __restrict__ fc2pk,
    unsigned short* __restrict__ fc3pk)
{
    const int b = blockIdx.x, t = threadIdx.x;
    if (b < 2) {                               // W1 wcat f32: C=3, O=64
        int i = b * 256 + t;
        if (i < 3 * 128) {
            int c = i / 128, col = i % 128;
            float v;
            if (col < 64) v = W1[(size_t)col * 6 + c];
            else          v = W1[(size_t)(col - 64) * 6 + 3 + c] - W1[(size_t)(col - 64) * 6 + c];
            wt1[i] = v;
        }
    } else if (b < 34)   edge_pack_body((b - 2)    * 256 + t, W2, wpk2, 64, 64, 1);
    else if (b < 98)     edge_pack_body((b - 34)   * 256 + t, W3, wpk3, 64, 128, 1);
    else if (b < 354)    edge_pack_body((b - 98)   * 256 + t, W4, wpk4, 128, 256, 2);
    else if (b < 2402) {                       // W5: [1024][512] -> frag order
        int i = (b - 354) * 256 + t;
        if (i < (1 << 19)) {
            int j = i & 7, lane = (i >> 3) & 63, nt = (i >> 9) & 63, kb = i >> 15;
            int c = kb * 32 + (lane >> 4) * 8 + j;
            int o = nt * 16 + (lane & 15);
            float f = W5[(size_t)o * 512 + c];
            unsigned short hi = f2bf(f);
            size_t base = (size_t)(kb * 64 + nt) * 1024 + (size_t)lane * 8 + j;
            w5pk[base] = hi;
            w5pk[base + 512] = f2bf(f - bf2f(hi));
        }
    }
    else if (b < 6498)   wfc_pack_body((b - 2402) * 256 + t, Wl1, fc1pk, 2048, 512, 32);
    else if (b < 7010)   wfc_pack_body((b - 6498) * 256 + t, Wl2, fc2pk, 512, 256, 16);
    else                 wfc_pack_body((b - 7010) * 256 + t, Wl3, fc3pk, 256, 800, 52);
}

// ================= edge conv, f32 VALU path (block 1: C=3) — stats pass fuses KNN =================
template<int C, int O, int NCHUNK, bool OUT>
__global__ __launch_bounds__(256) void edge_pass_kernel(
    const float* __restrict__ xin, int cloudStride,
    const float* __restrict__ wt,
    unsigned char* idx,                            // written if !OUT, read if OUT
    const float* __restrict__ st,
    float* __restrict__ xcout,
    float* __restrict__ partS, float* __restrict__ partQ)
{
    constexpr int TOTC = 2 * O;
    constexpr int O2C = TOTC / NCHUNK;
    constexpr int OC  = O / NCHUNK;
    constexpr int TPC = (O2C >= 256) ? 1 : (256 / O2C);
    constexpr int CPT = (O2C > 256) ? (O2C / 256) : 1;
    constexpr int PP  = P / TPC;
    constexpr int QUADS = OC / 4;
    constexpr int PG    = 256 / QUADS;
    constexpr int PPq   = P / PG;
    const int n = blockIdx.x, t = threadIdx.x;

    __shared__ float xs[C][P];
    __shared__ alignas(16) float gh[P * O2C];
    __shared__ unsigned char idl[P * KNN_K];
    __shared__ float xx[P];

    const float* xp = xin + (size_t)n * cloudStride;
    for (int i = t; i < C * P; i += 256) xs[i / P][i % P] = xp[i];

    if constexpr (!OUT) {
        // fused KNN (bit-identical to the standalone knn kernel): pd aliased on gh
        float* pd = gh;                            // [P][P+1]
        __syncthreads();
        if (t < P) { float s = 0.f; for (int c = 0; c < C; ++c) { float v = xs[c][t]; s = fmaf(v, v, s); } xx[t] = s; }
        __syncthreads();
        for (int i = t; i < P * P; i += 256) {
            int p = i >> 5, q = i & 31;
            float d = 0.f;
            for (int c = 0; c < C; ++c) d = fmaf(xs[c][p], xs[c][q], d);
            pd[p * (P + 1) + q] = 2.f * d - xx[p] - xx[q];   // diag exactly 0
        }
        __syncthreads();
        if (t < P) {
            for (int j = 0; j < KNN_K; ++j) {
                float best = -INFINITY; int bq = 0;
                for (int q = 0; q < P; ++q) { float v = pd[t * (P + 1) + q]; if (v > best) { best = v; bq = q; } }
                idl[t * KNN_K + j] = (unsigned char)bq;
                idx[(size_t)n * (P * KNN_K) + t * KNN_K + j] = (unsigned char)bq;
                pd[t * (P + 1) + bq] = -INFINITY;
            }
        }
    } else {
        for (int i = t; i < P * KNN_K; i += 256) idl[i] = idx[(size_t)n * (P * KNN_K) + i];
    }

    const int col = (O2C >= 256) ? t : (t % O2C);
    const int p0  = ((O2C >= 256) ? 0 : (t / O2C)) * PP;
    const int q4  = t % QUADS;
    const int pg  = t / QUADS;
    const int p0q = pg * PPq;

    for (int chunk = 0; chunk < NCHUNK; ++chunk) {
        __syncthreads();
        {
            float acc[CPT][PP];
            #pragma unroll
            for (int j = 0; j < CPT; ++j)
                #pragma unroll
                for (int p = 0; p < PP; ++p) acc[j][p] = 0.f;
            for (int c = 0; c < C; ++c) {
                float w[CPT];
                #pragma unroll
                for (int j = 0; j < CPT; ++j) w[j] = wt[(size_t)c * TOTC + chunk * O2C + col + j * 256];
                #pragma unroll
                for (int p = 0; p < PP; ++p) {
                    float xv = xs[c][p0 + p];
                    #pragma unroll
                    for (int j = 0; j < CPT; ++j) acc[j][p] = fmaf(w[j], xv, acc[j][p]);
                }
            }
            #pragma unroll
            for (int j = 0; j < CPT; ++j)
                #pragma unroll
                for (int p = 0; p < PP; ++p) gh[(p0 + p) * O2C + col + j * 256] = acc[j][p];
        }
        __syncthreads();

        if constexpr (!OUT) {
            f32x4 ssum4 = (f32x4)0.f, ssq4 = (f32x4)0.f;
            #pragma unroll
            for (int p = 0; p < PPq; ++p) {
                const int pp = p0q + p;
                const f32x4 gv = *(const f32x4*)&gh[pp * O2C + OC + q4 * 4];
                #pragma unroll
                for (int k = 0; k < KNN_K; ++k) {
                    const int q = idl[pp * KNN_K + k];
                    f32x4 yv = *(const f32x4*)&gh[q * O2C + q4 * 4] + gv;
                    ssum4 += yv; ssq4 += yv * yv;
                }
            }
            __syncthreads();           // all gathers done; reuse gh as reduction scratch
            #pragma unroll
            for (int e = 0; e < 4; ++e) {
                gh[(q4 * 4 + e) * PG + pg] = ssum4[e];
                gh[OC * PG + (q4 * 4 + e) * PG + pg] = ssq4[e];
            }
            __syncthreads();
            if (t < OC) {
                float S = 0.f, Q = 0.f;
                #pragma unroll
                for (int j = 0; j < PG; ++j) { S += gh[t * PG + j]; Q += gh[OC * PG + t * PG + j]; }
                partS[(size_t)(chunk * OC + t) * 2048 + n] = S;
                partQ[(size_t)(chunk * OC + t) * 2048 + n] = Q;
            }
        } else {
            const f32x4 s4  = *(const f32x4*)&st[chunk * OC + q4 * 4];
            const f32x4 sh4 = *(const f32x4*)&st[1024 + chunk * OC + q4 * 4];
            f32x4 res[PPq];
            #pragma unroll
            for (int p = 0; p < PPq; ++p) {
                const int pp = p0q + p;
                const f32x4 gv = *(const f32x4*)&gh[pp * O2C + OC + q4 * 4];
                f32x4 mx = (f32x4)(-INFINITY), mn = (f32x4)(INFINITY);
                #pragma unroll
                for (int k = 0; k < KNN_K; ++k) {
                    const int q = idl[pp * KNN_K + k];
                    f32x4 yv = *(const f32x4*)&gh[q * O2C + q4 * 4] + gv;
                    #pragma unroll
                    for (int e = 0; e < 4; ++e) { mx[e] = fmaxf(mx[e], yv[e]); mn[e] = fminf(mn[e], yv[e]); }
                }
                #pragma unroll
                for (int e = 0; e < 4; ++e)
                    res[p][e] = lrelu(fmaf(s4[e], (s4[e] >= 0.f ? mx[e] : mn[e]), sh4[e]));
            }
            __syncthreads();           // all gh reads done
            #pragma unroll
            for (int p = 0; p < PPq; ++p)
                #pragma unroll
                for (int e = 0; e < 4; ++e)
                    gh[(q4 * 4 + e) * (P + 1) + p0q + p] = res[p][e];
            __syncthreads();
            for (int i = t; i < OC * P; i += 256)
                xcout[(size_t)n * (512 * P) + chunk * OC * P + i] = gh[(i / P) * (P + 1) + (i % P)];
        }
    }
}

// ================= edge conv via MFMA (blocks 2-4) — stats pass fuses KNN =================
template<int C, int O, bool OUT>
__global__ __launch_bounds__(256) void edge_mfma_kernel(
    const float* __restrict__ xin, int cloudStride,
    const unsigned short* __restrict__ wpk,
    unsigned char* idx,                            // written if !OUT, read if OUT
    const float* __restrict__ st,
    float* __restrict__ xcout,
    float* __restrict__ partS, float* __restrict__ partQ)
{
    constexpr int TOTC  = 2 * O;
    constexpr int O2C   = (TOTC > 256) ? 256 : TOTC;
    constexpr int NCHUNK= TOTC / O2C;
    constexpr int OC    = O2C / 2;
    constexpr int NTW   = O2C / 64;
    constexpr int KB    = C / 32;
    constexpr int NTT   = TOTC / 16;
    constexpr int AS    = C + 8;
    constexpr int GHS   = O2C + 4;
    constexpr int QUADS = OC / 4;
    constexpr int PG    = 256 / QUADS;
    constexpr int PPq   = P / PG;
    static_assert(P * GHS >= C * P + P * (P + 1), "pd+xs must fit in gh");
    static_assert(P * GHS >= 2 * OC * PG, "stats scratch must fit in gh");

    const int n = blockIdx.x, t = threadIdx.x;
    const int w = t >> 6, l = t & 63;
    const int lg = l >> 4, lm = l & 15;

    __shared__ unsigned short Ah[P * AS];
    __shared__ unsigned short Al[P * AS];
    __shared__ alignas(16) float gh[P * GHS];
    __shared__ unsigned char idl[P * KNN_K];
    __shared__ float xx[P];

    const float* xp = xin + (size_t)n * cloudStride;
    if constexpr (!OUT) {
        float* xsf = gh;                 // [C*P] f32, alias
        float* pd  = gh + C * P;         // [P][P+1], alias
        for (int i = t; i < C * P; i += 256) {
            int c = i / P, p = i % P;
            float v = xp[i];
            unsigned short hi = f2bf(v);
            Ah[p * AS + c] = hi;
            Al[p * AS + c] = f2bf(v - bf2f(hi));
            xsf[i] = v;
        }
        __syncthreads();
        if (t < P) { float s = 0.f; for (int c = 0; c < C; ++c) { float v = xsf[c * P + t]; s = fmaf(v, v, s); } xx[t] = s; }
        __syncthreads();
        for (int i = t; i < P * P; i += 256) {
            int p = i >> 5, q = i & 31;
            float d = 0.f;
            for (int c = 0; c < C; ++c) d = fmaf(xsf[c * P + p], xsf[c * P + q], d);
            pd[p * (P + 1) + q] = 2.f * d - xx[p] - xx[q];
        }
        __syncthreads();
        if (t < P) {
            for (int j = 0; j < KNN_K; ++j) {
                float best = -INFINITY; int bq = 0;
                for (int q = 0; q < P; ++q) { float v = pd[t * (P + 1) + q]; if (v > best) { best = v; bq = q; } }
                idl[t * KNN_K + j] = (unsigned char)bq;
                idx[(size_t)n * (P * KNN_K) + t * KNN_K + j] = (unsigned char)bq;
                pd[t * (P + 1) + bq] = -INFINITY;
            }
        }
        __syncthreads();                 // idl visible; xsf/pd dead
    } else {
        for (int i = t; i < C * P; i += 256) {
            int c = i / P, p = i % P;
            float v = xp[i];
            unsigned short hi = f2bf(v);
            Ah[p * AS + c] = hi;
            Al[p * AS + c] = f2bf(v - bf2f(hi));
        }
        for (int i = t; i < P * KNN_K; i += 256) idl[i] = idx[(size_t)n * (P * KNN_K) + i];
        __syncthreads();
    }

    const int q4  = t % QUADS;
    const int pg  = t / QUADS;
    const int p0q = pg * PPq;

    for (int chunk = 0; chunk < NCHUNK; ++chunk) {
        f32x4 acc[2][NTW];
        #pragma unroll
        for (int mt = 0; mt < 2; ++mt)
            #pragma unroll
            for (int nt = 0; nt < NTW; ++nt) acc[mt][nt] = (f32x4)0.f;

        #pragma unroll
        for (int kb = 0; kb < KB; ++kb) {
            bf16x8 a_h[2], a_l[2];
            #pragma unroll
            for (int mt = 0; mt < 2; ++mt) {
                int row = mt * 16 + lm;
                a_h[mt] = *(const bf16x8*)&Ah[row * AS + kb * 32 + lg * 8];
                a_l[mt] = *(const bf16x8*)&Al[row * AS + kb * 32 + lg * 8];
            }
            #pragma unroll
            for (int nt = 0; nt < NTW; ++nt) {
                int ntg = chunk * (O2C / 16) + w * NTW + nt;
                const unsigned short* bp = wpk + (size_t)(kb * NTT + ntg) * 1024 + (size_t)l * 8;
                bf16x8 Bh = *(const bf16x8*)bp;
                bf16x8 Bl = *(const bf16x8*)(bp + 512);
                #pragma unroll
                for (int mt = 0; mt < 2; ++mt) {
                    acc[mt][nt] = __builtin_amdgcn_mfma_f32_16x16x32_bf16(a_h[mt], Bl, acc[mt][nt], 0, 0, 0);
                    acc[mt][nt] = __builtin_amdgcn_mfma_f32_16x16x32_bf16(a_l[mt], Bh, acc[mt][nt], 0, 0, 0);
                    acc[mt][nt] = __builtin_amdgcn_mfma_f32_16x16x32_bf16(a_h[mt], Bh, acc[mt][nt], 0, 0, 0);
                }
            }
        }
        __syncthreads();   // prev chunk's gh consumers done
        // scatter C frags: row = mt*16 + lg*4 + r, col = (w*NTW+nt)*16 + lm  [m89 mapping]
        #pragma unroll
        for (int mt = 0; mt < 2; ++mt)
            #pragma unroll
            for (int nt = 0; nt < NTW; ++nt) {
                int colb = (w * NTW + nt) * 16 + lm;
                #pragma unroll
                for (int r = 0; r < 4; ++r)
                    gh[(mt * 16 + lg * 4 + r) * GHS + colb] = acc[mt][nt][r];
            }
        __syncthreads();

        if constexpr (!OUT) {
            f32x4 ssum4 = (f32x4)0.f, ssq4 = (f32x4)0.f;
            #pragma unroll
            for (int p = 0; p < PPq; ++p) {
                const int pp = p0q + p;
                const f32x4 gv = *(const f32x4*)&gh[pp * GHS + OC + q4 * 4];
                #pragma unroll
                for (int k = 0; k < KNN_K; ++k) {
                    const int q = idl[pp * KNN_K + k];
                    f32x4 yv = *(const f32x4*)&gh[q * GHS + q4 * 4] + gv;
                    ssum4 += yv; ssq4 += yv * yv;
                }
            }
            __syncthreads();           // all gathers done; reuse gh as reduction scratch
            #pragma unroll
            for (int e = 0; e < 4; ++e) {
                gh[(q4 * 4 + e) * PG + pg] = ssum4[e];
                gh[OC * PG + (q4 * 4 + e) * PG + pg] = ssq4[e];
            }
            __syncthreads();
            if (t < OC) {
                float S = 0.f, Q = 0.f;
                #pragma unroll
                for (int j = 0; j < PG; ++j) { S += gh[t * PG + j]; Q += gh[OC * PG + t * PG + j]; }
                partS[(size_t)(chunk * OC + t) * 2048 + n] = S;
                partQ[(size_t)(chunk * OC + t) * 2048 + n] = Q;
            }
        } else {
            const f32x4 s4  = *(const f32x4*)&st[chunk * OC + q4 * 4];
            const f32x4 sh4 = *(const f32x4*)&st[1024 + chunk * OC + q4 * 4];
            f32x4 res[PPq];
            #pragma unroll
            for (int p = 0; p < PPq; ++p) {
                const int pp = p0q + p;
                const f32x4 gv = *(const f32x4*)&gh[pp * GHS + OC + q4 * 4];
                f32x4 mx = (f32x4)(-INFINITY), mn = (f32x4)(INFINITY);
                #pragma unroll
                for (int k = 0; k < KNN_K; ++k) {
                    const int q = idl[pp * KNN_K + k];
                    f32x4 yv = *(const f32x4*)&gh[q * GHS + q4 * 4] + gv;
                    #pragma unroll
                    for (int e = 0; e < 4; ++e) { mx[e] = fmaxf(mx[e], yv[e]); mn[e] = fminf(mn[e], yv[e]); }
                }
                #pragma unroll
                for (int e = 0; e < 4; ++e)
                    res[p][e] = lrelu(fmaf(s4[e], (s4[e] >= 0.f ? mx[e] : mn[e]), sh4[e]));
            }
            __syncthreads();           // all gh reads done
            #pragma unroll
            for (int p = 0; p < PPq; ++p)
                #pragma unroll
                for (int e = 0; e < 4; ++e)
                    gh[(q4 * 4 + e) * (P + 1) + p0q + p] = res[p][e];
            __syncthreads();
            for (int i = t; i < OC * P; i += 256)
                xcout[(size_t)n * (512 * P) + chunk * OC * P + i] = gh[(i / P) * (P + 1) + (i % P)];
        }
    }
}

// ================= reduce partials -> scale/shift per channel =================
__global__ __launch_bounds__(256) void reduce_stats_kernel(const float* __restrict__ partS,
                                                           const float* __restrict__ partQ,
                                                           const float* __restrict__ gamma,
                                                           const float* __restrict__ beta,
                                                           float* __restrict__ st, int nparts, float inv_count)
{
    const int o = blockIdx.x, t = threadIdx.x;
    __shared__ float rs[256], rq[256];
    float S = 0.f, Q = 0.f;
    for (int i = t; i < nparts; i += 256) { S += partS[(size_t)o * 2048 + i]; Q += partQ[(size_t)o * 2048 + i]; }
    rs[t] = S; rq[t] = Q; __syncthreads();
    for (int w = 128; w > 0; w >>= 1) { if (t < w) { rs[t] += rs[t + w]; rq[t] += rq[t + w]; } __syncthreads(); }
    if (t == 0) {
        float m = rs[0] * inv_count;
        float v = fmaxf(rq[0] * inv_count - m * m, 0.f);
        float s = gamma[o] * rsqrtf(v + BN_EPS);
        st[o] = s;
        st[1024 + o] = fmaf(-m, s, beta[o]);
    }
}

// ================= conv5 single pass: A single-bf16, B hi/lo 2-term; T14 load/MFMA/commit order =================
// y5 rounding (2^-9|y|) already dominates; A-rounding adds ~0.12%|y| in quadrature — below threshold.
__global__ __launch_bounds__(512) void conv5_store_kernel(
    const float* xc, const unsigned short* __restrict__ wpack,
    unsigned short* y5,
    float* __restrict__ partS, float* __restrict__ partQ)
{
    const int b = blockIdx.x;
    const int t = threadIdx.x;
    const int w = t >> 6, l = t & 63;
    const int lg = l >> 4, lm = l & 15;

    __shared__ unsigned short Ah[2][64][40];

    f32x4 acc[4][8];
    #pragma unroll
    for (int mt = 0; mt < 4; ++mt)
        #pragma unroll
        for (int nt = 0; nt < 8; ++nt) acc[mt][nt] = (f32x4)0.f;

    const float* xbase = xc + (size_t)(b * 2) * (512 * P);

    const int sp4    = t & 7;
    const int schalf = (t >> 3) & 15;
    const int scloud = (t >> 7) & 1;
    const bool sact  = t < 256;

    float4 v0, v1;                       // staging registers (T14: load early, commit late)
    auto loadv = [&](int kb) {
        if (sact) {
            const float* src = xbase + (size_t)scloud * (512 * P)
                             + (size_t)(kb * 32 + 2 * schalf) * P + sp4 * 4;
            v0 = *(const float4*)src;
            v1 = *(const float4*)(src + P);
        }
    };
    auto commit = [&](int buf) {
        if (sact) {
            const int r0 = scloud * 32 + sp4 * 4;
            #pragma unroll
            for (int e = 0; e < 4; ++e) {
                unsigned short h0 = f2bf((&v0.x)[e]), h1 = f2bf((&v1.x)[e]);
                *(unsigned*)&Ah[buf][r0 + e][2 * schalf] = (unsigned)h0 | ((unsigned)h1 << 16);
            }
        }
    };

    loadv(0); commit(0);
    int cur = 0;
    for (int kb = 0; kb < 16; ++kb) {
        __syncthreads();                     // buf[cur] visible; prev reads of buf[cur^1] done
        if (kb + 1 < 16) loadv(kb + 1);      // issue global loads; latency hides under MFMA

        bf16x8 a_h[4];
        #pragma unroll
        for (int mt = 0; mt < 4; ++mt)
            a_h[mt] = *(const bf16x8*)&Ah[cur][mt * 16 + lm][lg * 8];
        #pragma unroll
        for (int nt = 0; nt < 8; ++nt) {
            const int ntg = w * 8 + nt;
            const unsigned short* bp = wpack + (size_t)(kb * 64 + ntg) * 2 * 512 + (size_t)l * 8;
            bf16x8 Bh = *(const bf16x8*)bp;
            bf16x8 Bl = *(const bf16x8*)(bp + 512);
            #pragma unroll
            for (int mt = 0; mt < 4; ++mt) {
                acc[mt][nt] = __builtin_amdgcn_mfma_f32_16x16x32_bf16(a_h[mt], Bl, acc[mt][nt], 0, 0, 0);
                acc[mt][nt] = __builtin_amdgcn_mfma_f32_16x16x32_bf16(a_h[mt], Bh, acc[mt][nt], 0, 0, 0);
            }
        }
        if (kb + 1 < 16) commit(cur ^ 1);    // convert + ds_write after MFMA (writes to other buffer)
        cur ^= 1;
    }
    __syncthreads();   // all xc reads complete before in-place overwrite

    #pragma unroll
    for (int nt = 0; nt < 8; ++nt) {
        float s = 0.f, q = 0.f;
        #pragma unroll
        for (int mt = 0; mt < 4; ++mt)
            #pragma unroll
            for (int r = 0; r < 4; ++r) { float v = acc[mt][nt][r]; s += v; q = fmaf(v, v, q); }
        s += __shfl_xor(s, 16); q += __shfl_xor(q, 16);
        s += __shfl_xor(s, 32); q += __shfl_xor(q, 32);
        if (l < 16) {
            int o = w * 128 + nt * 16 + lm;
            partS[(size_t)o * 2048 + b] = s;
            partQ[(size_t)o * 2048 + b] = q;
        }
        #pragma unroll
        for (int mt = 0; mt < 4; ++mt) {
            unsigned p0 = (unsigned)f2bf(acc[mt][nt][0]) | ((unsigned)f2bf(acc[mt][nt][1]) << 16);
            unsigned p1 = (unsigned)f2bf(acc[mt][nt][2]) | ((unsigned)f2bf(acc[mt][nt][3]) << 16);
            size_t off = ((((size_t)b * 8 + w) * 8 + nt) * 4 + mt) * 64 + l;
            ((uint2*)y5)[off] = make_uint2(p0, p1);
        }
    }
}

// ================= conv5 finish: BN+lrelu+max/mean pool -> h =================
__global__ __launch_bounds__(512) void conv5_finish_kernel(
    const unsigned short* __restrict__ y5, const float* __restrict__ st, float* __restrict__ h)
{
    const int b = blockIdx.x, t = threadIdx.x;
    const int w = t >> 6, l = t & 63, lm = l & 15;
    #pragma unroll
    for (int nt = 0; nt < 8; ++nt) {
        const int o = w * 128 + nt * 16 + lm;
        const float sc = st[o], sh = st[1024 + o];
        #pragma unroll
        for (int cloud = 0; cloud < 2; ++cloud) {
            float mx = -INFINITY, sm = 0.f;
            #pragma unroll
            for (int half = 0; half < 2; ++half) {
                const int mt = cloud * 2 + half;
                uint2 pk = ((const uint2*)y5)[((((size_t)b * 8 + w) * 8 + nt) * 4 + mt) * 64 + l];
                #pragma unroll
                for (int r = 0; r < 4; ++r) {
                    unsigned word = (r < 2) ? pk.x : pk.y;
                    unsigned short bits = (unsigned short)((r & 1) ? (word >> 16) : (word & 0xffff));
                    float v = lrelu(fmaf(sc, bf2f(bits), sh));
                    mx = fmaxf(mx, v); sm += v;
                }
            }
            mx = fmaxf(mx, __shfl_xor(mx, 16)); sm += __shfl_xor(sm, 16);
            mx = fmaxf(mx, __shfl_xor(mx, 32)); sm += __shfl_xor(sm, 32);
            if (l < 16) {
                const int n = b * 2 + cloud;
                h[(size_t)n * 2048 + o] = mx;
                h[(size_t)n * 2048 + 1024 + o] = sm * (1.f / 32.f);
            }
        }
    }
}

// ================= FC GEMM via MFMA (fused BN-in / colstats-out) =================
template<bool BNIN, bool STATS>
__global__ __launch_bounds__(256) void gemm_mfma_nt(
    const float* __restrict__ A, const unsigned short* __restrict__ wpk,
    const float* __restrict__ stbn, const float* __restrict__ bias,
    float* __restrict__ Cc, float* __restrict__ partS, float* __restrict__ partQ,
    int Nn, int NTT, int Kk)
{
    const int o0 = blockIdx.x * 64;
    const int m0 = blockIdx.y * 64;
    const int t = threadIdx.x;
    const int w = t >> 6, l = t & 63;
    const int lg = l >> 4, lm = l & 15;

    __shared__ unsigned short Ah[2][64][40];
    __shared__ unsigned short Al[2][64][40];

    f32x4 acc[4];
    #pragma unroll
    for (int mt = 0; mt < 4; ++mt) acc[mt] = (f32x4)0.f;

    const int srow = t >> 3;
    const int sk4  = (t & 7) * 4;

    auto stage = [&](int kb, int buf) {
        const float* src = A + (size_t)(m0 + srow) * Kk + kb * 32 + sk4;
        float4 v0 = *(const float4*)src;
        float4 v1 = *(const float4*)(src + (size_t)32 * Kk);
        if (BNIN) {
            const float4 s4 = *(const float4*)(stbn + kb * 32 + sk4);
            const float4 t4 = *(const float4*)(stbn + 1024 + kb * 32 + sk4);
            #pragma unroll
            for (int e = 0; e < 4; ++e) {
                (&v0.x)[e] = lrelu(fmaf((&s4.x)[e], (&v0.x)[e], (&t4.x)[e]));
                (&v1.x)[e] = lrelu(fmaf((&s4.x)[e], (&v1.x)[e], (&t4.x)[e]));
            }
        }
        #pragma unroll
        for (int e = 0; e < 4; e += 2) {
            float a0 = (&v0.x)[e], a1 = (&v0.x)[e + 1];
            unsigned short h0 = f2bf(a0), h1 = f2bf(a1);
            *(unsigned*)&Ah[buf][srow][sk4 + e] = (unsigned)h0 | ((unsigned)h1 << 16);
            *(unsigned*)&Al[buf][srow][sk4 + e] =
                (unsigned)f2bf(a0 - bf2f(h0)) | ((unsigned)f2bf(a1 - bf2f(h1)) << 16);
            float b0 = (&v1.x)[e], b1 = (&v1.x)[e + 1];
            unsigned short g0 = f2bf(b0), g1 = f2bf(b1);
            *(unsigned*)&Ah[buf][srow + 32][sk4 + e] = (unsigned)g0 | ((unsigned)g1 << 16);
            *(unsigned*)&Al[buf][srow + 32][sk4 + e] =
                (unsigned)f2bf(b0 - bf2f(g0)) | ((unsigned)f2bf(b1 - bf2f(g1)) << 16);
        }
    };

    const int KB = Kk >> 5;
    stage(0, 0);
    int cur = 0;
    const int ntg = blockIdx.x * 4 + w;
    for (int kb = 0; kb < KB; ++kb) {
        __syncthreads();
        if (kb + 1 < KB) stage(kb + 1, cur ^ 1);
        bf16x8 a_h[4], a_l[4];
        #pragma unroll
        for (int mt = 0; mt < 4; ++mt) {
            a_h[mt] = *(const bf16x8*)&Ah[cur][mt * 16 + lm][lg * 8];
            a_l[mt] = *(const bf16x8*)&Al[cur][mt * 16 + lm][lg * 8];
        }
        const unsigned short* bp = wpk + ((size_t)kb * NTT + ntg) * 1024 + (size_t)l * 8;
        bf16x8 Bh = *(const bf16x8*)bp;
        bf16x8 Bl = *(const bf16x8*)(bp + 512);
        #pragma unroll
        for (int mt = 0; mt < 4; ++mt) {
            acc[mt] = __builtin_amdgcn_mfma_f32_16x16x32_bf16(a_h[mt], Bl, acc[mt], 0, 0, 0);
            acc[mt] = __builtin_amdgcn_mfma_f32_16x16x32_bf16(a_l[mt], Bh, acc[mt], 0, 0, 0);
            acc[mt] = __builtin_amdgcn_mfma_f32_16x16x32_bf16(a_h[mt], Bh, acc[mt], 0, 0, 0);
        }
        cur ^= 1;
    }

    const int col = o0 + w * 16 + lm;
    const bool cok = col < Nn;
    const float bv = (bias != nullptr && cok) ? bias[col] : 0.f;
    float s = 0.f, q = 0.f;
    #pragma unroll
    for (int mt = 0; mt < 4; ++mt) {
        #pragma unroll
        for (int r = 0; r < 4; ++r) {
            float v = acc[mt][r] + bv;
            if (STATS) { s += v; q = fmaf(v, v, q); }
            if (cok) Cc[(size_t)(m0 + mt * 16 + lg * 4 + r) * Nn + col] = v;
        }
    }
    if (STATS) {
        s += __shfl_xor(s, 16); q += __shfl_xor(q, 16);
        s += __shfl_xor(s, 32); q += __shfl_xor(q, 32);
        if (l < 16 && cok) {
            partS[(size_t)col * 2048 + blockIdx.y] = s;
            partQ[(size_t)col * 2048 + blockIdx.y] = q;
        }
    }
}

__global__ __launch_bounds__(256) void logsoftmax_kernel(float* __restrict__ out)
{
    const int n = blockIdx.x, t = threadIdx.x;
    float* row = out + (size_t)n * 800;
    __shared__ float red[256];
    float v[4];
    float mx = -INFINITY;
    #pragma unroll
    for (int j = 0; j < 4; ++j) {
        int i = t + j * 256;
        v[j] = (i < 800) ? row[i] : -INFINITY;
        mx = fmaxf(mx, v[j]);
    }
    red[t] = mx; __syncthreads();
    for (int w = 128; w > 0; w >>= 1) { if (t < w) red[t] = fmaxf(red[t], red[t + w]); __syncthreads(); }
    const float m = red[0]; __syncthreads();
    float s = 0.f;
    #pragma unroll
    for (int j = 0; j < 4; ++j) { int i = t + j * 256; if (i < 800) s += expf(v[j] - m); }
    red[t] = s; __syncthreads();
    for (int w = 128; w > 0; w >>= 1) { if (t < w) red[t] += red[t + w]; __syncthreads(); }
    const float lg = m + logf(red[0]);
    #pragma unroll
    for (int j = 0; j < 4; ++j) { int i = t + j * 256; if (i < 800) row[i] = v[j] - lg; }
}

extern "C" void kernel_launch(void* const* d_in, const int* in_sizes, int n_in,
                              void* d_out, int out_size, void* d_ws, size_t ws_size,
                              hipStream_t stream)
{
    (void)in_sizes; (void)n_in; (void)out_size; (void)ws_size;
    const float* x   = (const float*)d_in[0];
    const float* W1  = (const float*)d_in[2];
    const float* g1  = (const float*)d_in[3];
    const float* b1  = (const float*)d_in[4];
    const float* W2  = (const float*)d_in[5];
    const float* g2  = (const float*)d_in[6];
    const float* b2  = (const float*)d_in[7];
    const float* W3  = (const float*)d_in[8];
    const float* g3  = (const float*)d_in[9];
    const float* b3  = (const float*)d_in[10];
    const float* W4  = (const float*)d_in[11];
    const float* g4  = (const float*)d_in[12];
    const float* b4  = (const float*)d_in[13];
    const float* W5  = (const float*)d_in[14];
    const float* g5  = (const float*)d_in[15];
    const float* b5  = (const float*)d_in[16];
    const float* Wl1 = (const float*)d_in[17];
    const float* g6  = (const float*)d_in[18];
    const float* b6  = (const float*)d_in[19];
    const float* Wl2 = (const float*)d_in[20];
    const float* bl2 = (const float*)d_in[21];
    const float* g7  = (const float*)d_in[22];
    const float* b7  = (const float*)d_in[23];
    const float* Wl3 = (const float*)d_in[24];
    const float* bl3 = (const float*)d_in[25];

    char* ws = (char*)d_ws;
    size_t off = 0;
    auto alloc = [&](size_t bytes) -> void* {
        void* p = ws + off; off += (bytes + 255) & ~(size_t)255; return p;
    };
    float*          xc    = (float*)alloc((size_t)NPTS * 512 * P * 4);        // 134.2 MB
    unsigned char*  idx   = (unsigned char*)alloc((size_t)NPTS * P * KNN_K);  // 0.98 MB
    float*          partS = (float*)alloc((size_t)1024 * 2048 * 4);           // 8.4 MB
    float*          partQ = (float*)alloc((size_t)1024 * 2048 * 4);           // 8.4 MB
    float*          st    = (float*)alloc(2048 * 4);
    float*          wt1   = (float*)alloc(3 * 128 * 4);                       // block-1 wcat f32
    unsigned short* wpk2  = (unsigned short*)alloc((size_t)2 * 64 * 128 * 2);  // 32 KB
    unsigned short* wpk3  = (unsigned short*)alloc((size_t)2 * 64 * 256 * 2);  // 64 KB
    unsigned short* wpk4  = (unsigned short*)alloc((size_t)2 * 128 * 512 * 2); // 256 KB
    unsigned short* w5pk  = (unsigned short*)alloc((size_t)2 * 512 * 1024 * 2);// 2 MB
    unsigned short* fc1pk = (unsigned short*)alloc((size_t)2 * 512 * 2048 * 2);// 4 MB
    unsigned short* fc2pk = (unsigned short*)alloc((size_t)2 * 256 * 512 * 2); // 0.5 MB
    unsigned short* fc3pk = (unsigned short*)alloc((size_t)2 * 832 * 256 * 2); // 0.83 MB
    float*          h     = (float*)alloc((size_t)2048 * 2048 * 4);           // 16.8 MB
    float*          h1p   = (float*)alloc((size_t)2048 * 512 * 4);            // 4.2 MB
    unsigned short* y5 = (unsigned short*)xc;   // in-place
    float* h2p = h + 1048576;                   // h dead after FC1 gemm

    const float inv_edge = 1.f / (float)(NPTS * P * KNN_K);

    // ---- all weight packs, one launch ----
    pack_all_kernel<<<7842, 256, 0, stream>>>(W1, W2, W3, W4, W5, Wl1, Wl2, Wl3,
                                              wt1, wpk2, wpk3, wpk4, w5pk, fc1pk, fc2pk, fc3pk);

    // ---- edge block 1: x(C=3) -> O=64 (xc ch 0..63), f32 path, knn fused in stats ----
    edge_pass_kernel<3, 64, 1, false><<<NPTS, 256, 0, stream>>>(x, 3 * P, wt1, idx, nullptr, nullptr, partS, partQ);
    reduce_stats_kernel<<<64, 256, 0, stream>>>(partS, partQ, g1, b1, st, 2048, inv_edge);
    edge_pass_kernel<3, 64, 1, true><<<NPTS, 256, 0, stream>>>(x, 3 * P, wt1, idx, st, xc + 0 * P, nullptr, nullptr);

    // ---- edge block 2: xc ch 0..63 -> O=64 (ch 64..127), MFMA, knn fused ----
    edge_mfma_kernel<64, 64, false><<<NPTS, 256, 0, stream>>>(xc, 512 * P, wpk2, idx, nullptr, nullptr, partS, partQ);
    reduce_stats_kernel<<<64, 256, 0, stream>>>(partS, partQ, g2, b2, st, 2048, inv_edge);
    edge_mfma_kernel<64, 64, true><<<NPTS, 256, 0, stream>>>(xc, 512 * P, wpk2, idx, st, xc + 64 * P, nullptr, nullptr);

    // ---- edge block 3: xc ch 64..127 -> O=128 (ch 128..255), MFMA, knn fused ----
    edge_mfma_kernel<64, 128, false><<<NPTS, 256, 0, stream>>>(xc + 64 * P, 512 * P, wpk3, idx, nullptr, nullptr, partS, partQ);
    reduce_stats_kernel<<<128, 256, 0, stream>>>(partS, partQ, g3, b3, st, 2048, inv_edge);
    edge_mfma_kernel<64, 128, true><<<NPTS, 256, 0, stream>>>(xc + 64 * P, 512 * P, wpk3, idx, st, xc + 128 * P, nullptr, nullptr);

    // ---- edge block 4: xc ch 128..255 -> O=256 (ch 256..511), MFMA, knn fused ----
    edge_mfma_kernel<128, 256, false><<<NPTS, 256, 0, stream>>>(xc + 128 * P, 512 * P, wpk4, idx, nullptr, nullptr, partS, partQ);
    reduce_stats_kernel<<<256, 256, 0, stream>>>(partS, partQ, g4, b4, st, 2048, inv_edge);
    edge_mfma_kernel<128, 256, true><<<NPTS, 256, 0, stream>>>(xc + 128 * P, 512 * P, wpk4, idx, st, xc + 256 * P, nullptr, nullptr);

    // ---- stage 5 via MFMA, single GEMM pass: stats + y5 in place; then BN+pool ----
    conv5_store_kernel<<<1024, 512, 0, stream>>>(xc, w5pk, y5, partS, partQ);
    reduce_stats_kernel<<<1024, 256, 0, stream>>>(partS, partQ, g5, b5, st, 1024, 1.f / 65536.f);
    conv5_finish_kernel<<<1024, 512, 0, stream>>>(y5, st, h);

    // ---- FC head (MFMA, fused colstats + BN-in-stage) ----
    gemm_mfma_nt<false, true><<<dim3(8, 32), 256, 0, stream>>>(h, fc1pk, nullptr, nullptr, h1p, partS, partQ, 512, 32, 2048);
    reduce_stats_kernel<<<512, 256, 0, stream>>>(partS, partQ, g6, b6, st, 32, 1.f / 2048.f);

    gemm_mfma_nt<true, true><<<dim3(4, 32), 256, 0, stream>>>(h1p, fc2pk, st, bl2, h2p, partS, partQ, 256, 16, 512);
    reduce_stats_kernel<<<256, 256, 0, stream>>>(partS, partQ, g7, b7, st, 32, 1.f / 2048.f);

    gemm_mfma_nt<true, false><<<dim3(13, 32), 256, 0, stream>>>(h2p, fc3pk, st, bl3, (float*)d_out, nullptr, nullptr, 800, 52, 256);

    logsoftmax_kernel<<<NPTS, 256, 0, stream>>>((float*)d_out);
}